// Round 10
// baseline (2199.050 us; speedup 1.0000x reference)
//
#include <hip/hip_runtime.h>

typedef unsigned short u16;
typedef unsigned int u32;
typedef __attribute__((ext_vector_type(8))) short bf16x8_t;
typedef __attribute__((ext_vector_type(4))) float f32x4_t;

// problem constants
#define kN 65536
#define kE 262144
#define kG 2048
#define kH 300
#define kH2 600
#define kL 5
#define kF 32
#define kDG 1523
// padded dims
#define KP_H 320     // K pad of H
#define KP_H2 640    // K pad of 2H
#define KP_DG 1536   // K pad of DG
#define NP_H2 640    // N pad of 2H (128-tiled)
#define NP_H 320     // N pad of H (64-tiled)
// hvbf row stride (u16 / u32)
#define HVS 320
#define HVS32 160
// fragment-packed weight size per layer: 5*4*2*10*64*8 == 5*4*5*4*64*8 == 204800 u16
#define WFRAG_PER_L 204800

__device__ __forceinline__ float bf2f(u16 x) {
    union { u32 u; float f; } v; v.u = ((u32)x) << 16; return v.f;
}
__device__ __forceinline__ u16 f2bf(float f) {
    union { float f; u32 u; } v; v.f = f;
    u32 u = v.u;
    u32 r = (u + 0x7fffu + ((u >> 16) & 1u)) >> 16;  // RNE
    return (u16)r;
}
__device__ __forceinline__ float blo(u32 v) { return bf2f((u16)(v & 0xffffu)); }
__device__ __forceinline__ float bhi(u32 v) { return bf2f((u16)(v >> 16)); }
__device__ __forceinline__ u32 pack2(float lo, float hi) {
    return (u32)f2bf(lo) | ((u32)f2bf(hi) << 16);
}

// async 16B global -> LDS
__device__ __forceinline__ void gld16(const u16* g, u16* l) {
    __builtin_amdgcn_global_load_lds(
        (const __attribute__((address_space(1))) u32*)g,
        (__attribute__((address_space(3))) u32*)l, 16, 0, 0);
}

// counted vmcnt waits + raw barrier
__device__ __forceinline__ void vwait6() { asm volatile("s_waitcnt vmcnt(6)" ::: "memory"); }
__device__ __forceinline__ void vwait8() { asm volatile("s_waitcnt vmcnt(8)" ::: "memory"); }
__device__ __forceinline__ void vwait0() { asm volatile("s_waitcnt vmcnt(0)" ::: "memory"); }
__device__ __forceinline__ void lwait0() { asm volatile("s_waitcnt lgkmcnt(0)" ::: "memory"); }
__device__ __forceinline__ void rbar() {
    __builtin_amdgcn_sched_barrier(0);
    __builtin_amdgcn_s_barrier();
    __builtin_amdgcn_sched_barrier(0);
}

// XCD-bijective tile swizzle (requires gridDim.x % 8 == 0; holds: 16).
__device__ __forceinline__ void swz_tile(int& m, int& n) {
    int p = blockIdx.x + gridDim.x * blockIdx.y;
    int xcd = p & 7;
    int q = p >> 3;
    int NB = gridDim.y;
    int mb8 = gridDim.x >> 3;
    m = xcd * mb8 + q / NB;
    n = q % NB;
}

// ---------------- weight transpose: W[b][k][n] (f32) -> Wt[b][n][k] (bf16), zero-padded ----------------
__global__ void transpose_k(const float* __restrict__ W, u16* __restrict__ Wt,
                            int K, int NN, int NP, int KP, long total) {
    long idx = (long)blockIdx.x * 256 + threadIdx.x;
    if (idx >= total) return;
    int per = NP * KP;
    int b = (int)(idx / per);
    int r = (int)(idx % per);
    int n = r / KP;
    int k = r % KP;
    u16 v = 0;
    if (n < NN && k < K) v = f2bf(W[(long)b * K * NN + (long)k * NN + n]);
    Wt[idx] = v;
}

// ---------------- fragment-pack W1 (gin_W1 [L][300][600]) -> W1f [L][c][w][nt][tk][lane][8] ----------------
__global__ void pack_w1_k(const float* __restrict__ W, u16* __restrict__ Wf, long total) {
    long idx = (long)blockIdx.x * 256 + threadIdx.x;
    if (idx >= total) return;
    int l = (int)(idx / WFRAG_PER_L);
    long r = idx % WFRAG_PER_L;
    int e = (int)(r & 7);
    long r1 = r >> 3;
    int ln = (int)(r1 & 63);
    int l16 = ln & 15, quad = ln >> 4;
    long s = r1 >> 6;
    int tk = (int)(s % 10);
    long s2 = s / 10;
    int nt = (int)(s2 & 1);
    long s3 = s2 >> 1;
    int w = (int)(s3 & 3);
    int c = (int)(s3 >> 2);
    int n = c * 128 + w * 32 + nt * 16 + l16;
    int k = tk * 32 + quad * 8 + e;
    u16 v = 0;
    if (n < kH2 && k < kH) v = f2bf(W[(long)l * kH * kH2 + (long)k * kH2 + n]);
    Wf[idx] = v;
}

// ---------------- fragment-pack W2 (gin_W2 [L][600][300]) -> W2f [L][c][w][nt][ks][lane][8] ----------------
__global__ void pack_w2_k(const float* __restrict__ W, u16* __restrict__ Wf, long total) {
    long idx = (long)blockIdx.x * 256 + threadIdx.x;
    if (idx >= total) return;
    int l = (int)(idx / WFRAG_PER_L);
    long r = idx % WFRAG_PER_L;
    int e = (int)(r & 7);
    long r1 = r >> 3;
    int ln = (int)(r1 & 63);
    int l16 = ln & 15, quad = ln >> 4;
    long s = r1 >> 6;
    int ks = (int)(s & 3);
    long s2 = s >> 2;
    int nt = (int)(s2 % 5);
    long s3 = s2 / 5;
    int w = (int)(s3 & 3);
    int c = (int)(s3 >> 2);
    int n = w * 80 + nt * 16 + l16;
    int k = c * 128 + ks * 32 + quad * 8 + e;
    u16 v = 0;
    if (n < kH && k < kH2) v = f2bf(W[(long)l * kH2 * kH + (long)k * kH + n]);
    Wf[idx] = v;
}

// ---------------- graph histogram + scan ----------------
__global__ void hist_g_k(const int* __restrict__ batch, int* __restrict__ counts) {
    int n = blockIdx.x * 256 + threadIdx.x;
    if (n < kN) atomicAdd(&counts[batch[n]], 1);
}

__global__ void scan_g_k(const int* __restrict__ counts, int* __restrict__ starts) {
    __shared__ int s[1024];
    int t = threadIdx.x;
    int c0 = counts[2 * t], c1 = counts[2 * t + 1];
    s[t] = c0 + c1;
    __syncthreads();
    for (int off = 1; off < 1024; off <<= 1) {
        int v = (t >= off) ? s[t - off] : 0;
        __syncthreads();
        s[t] += v;
        __syncthreads();
    }
    int excl = (t > 0) ? s[t - 1] : 0;
    starts[2 * t] = excl;
    starts[2 * t + 1] = excl + c0;
}

// ---------------- node CSR build ----------------
__global__ void hist_n_k(const int* __restrict__ ei, int* __restrict__ cnt) {
    int e = blockIdx.x * 256 + threadIdx.x;
    if (e < kE) atomicAdd(&cnt[ei[kE + e]], 1);
}

__global__ void scanA_k(const int* __restrict__ cnt, int* __restrict__ start, int* __restrict__ bsum) {
    __shared__ int s[1024];
    int b = blockIdx.x, t = threadIdx.x;
    int v = cnt[b * 1024 + t];
    s[t] = v;
    __syncthreads();
    for (int off = 1; off < 1024; off <<= 1) {
        int u = (t >= off) ? s[t - off] : 0;
        __syncthreads();
        s[t] += u;
        __syncthreads();
    }
    start[b * 1024 + t] = s[t] - v;
    if (t == 1023) bsum[b] = s[1023];
}

__global__ void scanB_k(int* __restrict__ bsum) {
    if (threadIdx.x == 0) {
        int s = 0;
        for (int i = 0; i < kN / 1024; i++) { s += bsum[i]; bsum[i] = s; }
    }
}

__global__ void scanC_k(int* __restrict__ start, const int* __restrict__ bsum) {
    int b = blockIdx.x, t = threadIdx.x;
    int add = (b > 0) ? bsum[b - 1] : 0;
    start[b * 1024 + t] += add;
    if (b == kN / 1024 - 1 && t == 1023) start[kN] = bsum[kN / 1024 - 1];
}

__global__ void fill_n_k(const int* __restrict__ ei, const int* __restrict__ start,
                         int* __restrict__ fill, int* __restrict__ perm) {
    int e = blockIdx.x * 256 + threadIdx.x;
    if (e >= kE) return;
    int s = ei[e], d = ei[kE + e];
    int pos = start[d] + atomicAdd(&fill[d], 1);
    perm[pos] = s;
}

// ---------------- node embedding: hvbf = bf16(x@W+b + vn0) ----------------
__global__ __launch_bounds__(256) void embed_k(
    const float* __restrict__ x, const float* __restrict__ W,
    const float* __restrict__ b, const float* __restrict__ vn0,
    u32* __restrict__ hv32) {
    __shared__ float sW[9 * kH];
    __shared__ float sBV[kH];
    int tid = threadIdx.x;
    for (int i = tid; i < 9 * kH; i += 256) sW[i] = W[i];
    for (int i = tid; i < kH; i += 256) sBV[i] = b[i] + vn0[i];
    __syncthreads();
    int wave = tid >> 6, lane = tid & 63;
    int n = blockIdx.x * 4 + wave;
    float xv[9];
    #pragma unroll
    for (int d = 0; d < 9; d++) xv[d] = x[n * 9 + d];
    #pragma unroll
    for (int p = 0; p < 3; p++) {
        int ii = lane + p * 64;
        if (ii < 150) {
            int c0 = 2 * ii;
            float a0 = sBV[c0], a1 = sBV[c0 + 1];
            #pragma unroll
            for (int d = 0; d < 9; d++) {
                a0 += xv[d] * sW[d * kH + c0];
                a1 += xv[d] * sW[d * kH + c0 + 1];
            }
            hv32[(long)n * HVS32 + ii] = pack2(a0, a1);
        } else if (ii < HVS32) {
            hv32[(long)n * HVS32 + ii] = 0u;
        }
    }
}

__global__ void vninit_k(const float* __restrict__ vn0, float* __restrict__ vn) {
    int g = blockIdx.x, c = threadIdx.x;
    if (c < kH) vn[g * kH + c] = vn0[c];
}

// ---------------- gather + combine ----------------
__global__ __launch_bounds__(256) void gather_combine_k(
    const u32* __restrict__ hv32, const int* __restrict__ start_n,
    const int* __restrict__ perm, const float* __restrict__ eps, int l,
    u32* __restrict__ out32, float* __restrict__ stats) {
    int tid = threadIdx.x;
    int wave = tid >> 6, lane = tid & 63;
    int n = blockIdx.x * 4 + wave;
    int st = start_n[n], en = start_n[n + 1];
    int i0 = lane, i1 = lane + 64, i2 = lane + 128;
    bool p2 = (i2 < 150);
    float a0 = 0.f, b0 = 0.f, a1 = 0.f, b1 = 0.f, a2 = 0.f, b2 = 0.f;
    int e = st;
    for (; e + 4 <= en; e += 4) {
        const u32* rA = hv32 + (long)perm[e] * HVS32;
        const u32* rB = hv32 + (long)perm[e + 1] * HVS32;
        const u32* rC = hv32 + (long)perm[e + 2] * HVS32;
        const u32* rD = hv32 + (long)perm[e + 3] * HVS32;
        u32 vA0 = rA[i0], vA1 = rA[i1], vA2 = p2 ? rA[i2] : 0u;
        u32 vB0 = rB[i0], vB1 = rB[i1], vB2 = p2 ? rB[i2] : 0u;
        u32 vC0 = rC[i0], vC1 = rC[i1], vC2 = p2 ? rC[i2] : 0u;
        u32 vD0 = rD[i0], vD1 = rD[i1], vD2 = p2 ? rD[i2] : 0u;
        a0 += (blo(vA0) + blo(vB0)) + (blo(vC0) + blo(vD0));
        b0 += (bhi(vA0) + bhi(vB0)) + (bhi(vC0) + bhi(vD0));
        a1 += (blo(vA1) + blo(vB1)) + (blo(vC1) + blo(vD1));
        b1 += (bhi(vA1) + bhi(vB1)) + (bhi(vC1) + bhi(vD1));
        a2 += (blo(vA2) + blo(vB2)) + (blo(vC2) + blo(vD2));
        b2 += (bhi(vA2) + bhi(vB2)) + (bhi(vC2) + bhi(vD2));
    }
    for (; e + 2 <= en; e += 2) {
        const u32* rA = hv32 + (long)perm[e] * HVS32;
        const u32* rB = hv32 + (long)perm[e + 1] * HVS32;
        u32 vA0 = rA[i0], vA1 = rA[i1], vA2 = p2 ? rA[i2] : 0u;
        u32 vB0 = rB[i0], vB1 = rB[i1], vB2 = p2 ? rB[i2] : 0u;
        a0 += blo(vA0) + blo(vB0); b0 += bhi(vA0) + bhi(vB0);
        a1 += blo(vA1) + blo(vB1); b1 += bhi(vA1) + bhi(vB1);
        a2 += blo(vA2) + blo(vB2); b2 += bhi(vA2) + bhi(vB2);
    }
    if (e < en) {
        const u32* rA = hv32 + (long)perm[e] * HVS32;
        u32 vA0 = rA[i0], vA1 = rA[i1], vA2 = p2 ? rA[i2] : 0u;
        a0 += blo(vA0); b0 += bhi(vA0);
        a1 += blo(vA1); b1 += bhi(vA1);
        a2 += blo(vA2); b2 += bhi(vA2);
    }
    const u32* self = hv32 + (long)n * HVS32;
    float ep = 1.f + eps[l];
    u32 s0 = self[i0], s1 = self[i1];
    u32* o = out32 + (long)n * HVS32;
    o[i0] = pack2(ep * blo(s0) + a0, ep * bhi(s0) + b0);
    o[i1] = pack2(ep * blo(s1) + a1, ep * bhi(s1) + b1);
    if (p2) {
        u32 s2 = self[i2];
        o[i2] = pack2(ep * blo(s2) + a2, ep * bhi(s2) + b2);
    } else if (i2 < HVS32) {
        o[i2] = 0u;
    }
    int gz = blockIdx.x * 256 + tid;
    if (gz < 2 * kH) stats[gz] = 0.f;
}

// ---------------- vt (wave per graph): vt[g] = sum_rows hvbf + vn_cur[g] ----------------
__global__ __launch_bounds__(256) void vt_fin_k(
    const u32* __restrict__ hv32, const float* __restrict__ vncur,
    const int* __restrict__ counts, const int* __restrict__ starts,
    u32* __restrict__ vt32) {
    int tid = threadIdx.x, wave = tid >> 6, lane = tid & 63;
    int g = blockIdx.x * 4 + wave;
    int cnt = counts[g], st = starts[g];
    int i0 = lane, i1 = lane + 64, i2 = lane + 128;
    bool p2 = (i2 < 150);
    float a0 = 0.f, b0 = 0.f, a1 = 0.f, b1 = 0.f, a2 = 0.f, b2 = 0.f;
    int i = 0;
    for (; i + 4 <= cnt; i += 4) {
        const u32* rA = hv32 + (long)(st + i) * HVS32;
        const u32* rB = hv32 + (long)(st + i + 1) * HVS32;
        const u32* rC = hv32 + (long)(st + i + 2) * HVS32;
        const u32* rD = hv32 + (long)(st + i + 3) * HVS32;
        u32 vA0 = rA[i0], vA1 = rA[i1], vA2 = p2 ? rA[i2] : 0u;
        u32 vB0 = rB[i0], vB1 = rB[i1], vB2 = p2 ? rB[i2] : 0u;
        u32 vC0 = rC[i0], vC1 = rC[i1], vC2 = p2 ? rC[i2] : 0u;
        u32 vD0 = rD[i0], vD1 = rD[i1], vD2 = p2 ? rD[i2] : 0u;
        a0 += (blo(vA0) + blo(vB0)) + (blo(vC0) + blo(vD0));
        b0 += (bhi(vA0) + bhi(vB0)) + (bhi(vC0) + bhi(vD0));
        a1 += (blo(vA1) + blo(vB1)) + (blo(vC1) + blo(vD1));
        b1 += (bhi(vA1) + bhi(vB1)) + (bhi(vC1) + bhi(vD1));
        a2 += (blo(vA2) + blo(vB2)) + (blo(vC2) + blo(vD2));
        b2 += (bhi(vA2) + bhi(vB2)) + (bhi(vC2) + bhi(vD2));
    }
    for (; i < cnt; i++) {
        const u32* rA = hv32 + (long)(st + i) * HVS32;
        u32 vA0 = rA[i0], vA1 = rA[i1], vA2 = p2 ? rA[i2] : 0u;
        a0 += blo(vA0); b0 += bhi(vA0);
        a1 += blo(vA1); b1 += bhi(vA1);
        a2 += blo(vA2); b2 += bhi(vA2);
    }
    const float* vg = vncur + g * kH;
    vt32[(long)g * HVS32 + i0] = pack2(a0 + vg[2 * i0], b0 + vg[2 * i0 + 1]);
    vt32[(long)g * HVS32 + i1] = pack2(a1 + vg[2 * i1], b1 + vg[2 * i1 + 1]);
    if (p2) vt32[(long)g * HVS32 + i2] = pack2(a2 + vg[2 * i2], b2 + vg[2 * i2 + 1]);
    else if (i2 < HVS32) vt32[(long)g * HVS32 + i2] = 0u;
}

// ---------------- FUSED node MLP v5: 8 KB z1c (half-chunk handoff) -> 3 blocks/CU ----------------
// 256 thr / 64-row strip. A strip persisted in LDS; W1/W2 fragment-packed global->register
// (full-chunk register cache, r8-verified); z1 handoff done in two 64-col halves through an
// 8 KB XOR-swizzled buffer so total LDS = 50.5 KB -> 3 blocks/CU (was 2).
__global__ __launch_bounds__(256, 3) void fused_mlp_k(
    const u16* __restrict__ A,      // hv [kN x 320] bf16
    const u16* __restrict__ W1f,    // fragment-packed [5][4][2][10][64][8]
    const float* __restrict__ b1,   // [600]
    const u16* __restrict__ W2f,    // fragment-packed [5][4][5][4][64][8]
    const float* __restrict__ b2,   // [300]
    u16* __restrict__ outp,         // hv (in-place)
    float* __restrict__ stats) {
    __shared__ __align__(16) u16 lA[5][64 * 64];   // 40 KB persistent A strip
    __shared__ __align__(16) u16 z1c[64 * 64];     // 8 KB z1 half-chunk, XOR swizzle (8 groups)
    __shared__ float sred[320][2];                 // 2.5 KB BN partial sums

    const int tid = threadIdx.x;
    const int lane = tid & 63;
    const int wave = tid >> 6;      // 0..3
    const int l16 = lane & 15;
    const int quad = lane >> 4;
    const long tm = (long)blockIdx.x * 64;
    const int srow = lane >> 3;
    const int sch = (lane & 7) ^ srow;

    for (int i = tid; i < 320; i += 256) { sred[i][0] = 0.f; sred[i][1] = 0.f; }

    // stage the whole A strip once (5 k-tiles x 64 rows)
    #pragma unroll
    for (int t = 0; t < 5; t++) {
        #pragma unroll
        for (int j = 0; j < 2; j++) {
            int rb = wave * 16 + j * 8;
            gld16(A + (tm + rb + srow) * KP_H + t * 64 + sch * 8, &lA[t][rb * 64]);
        }
    }

    // preload biases (compile-time indexed after full unroll)
    float rb1[5][2];
    #pragma unroll
    for (int c = 0; c < 5; c++)
        #pragma unroll
        for (int nt = 0; nt < 2; nt++) {
            int gc = c * 128 + wave * 32 + nt * 16 + l16;
            rb1[c][nt] = (gc < kH2) ? b1[gc] : 0.f;
        }
    float rb2[5];
    #pragma unroll
    for (int nt = 0; nt < 5; nt++) {
        int col = wave * 80 + nt * 16 + l16;
        rb2[nt] = (col < kH) ? b2[col] : 0.f;
    }

    f32x4_t acc2[4][5];
    #pragma unroll
    for (int i = 0; i < 4; i++)
        #pragma unroll
        for (int j = 0; j < 5; j++) acc2[i][j] = (f32x4_t){0.f, 0.f, 0.f, 0.f};

    vwait0();
    rbar();  // A strip staged; sred zeroed

    #pragma unroll
    for (int c = 0; c < 5; c++) {
        // ---------- phase A: full W1 chunk in regs, stall-free MFMA loop ----------
        const u16* w1p = W1f + ((long)((c * 4 + wave) * 2) * 10) * 512 + lane * 8;
        bf16x8_t wA[2][10];
        #pragma unroll
        for (int tk = 0; tk < 10; tk++) {
            wA[0][tk] = *(const bf16x8_t*)(w1p + tk * 512);
            wA[1][tk] = *(const bf16x8_t*)(w1p + (10 + tk) * 512);
        }
        f32x4_t acc1[4][2];
        #pragma unroll
        for (int i = 0; i < 4; i++) {
            acc1[i][0] = (f32x4_t){0.f, 0.f, 0.f, 0.f};
            acc1[i][1] = (f32x4_t){0.f, 0.f, 0.f, 0.f};
        }
        #pragma unroll
        for (int tk = 0; tk < 10; tk++) {
            const int t = tk >> 1, ks = tk & 1;
            bf16x8_t af[4];
            #pragma unroll
            for (int mt = 0; mt < 4; mt++) {
                int row = mt * 16 + l16;
                int phys = (ks * 4 + quad) ^ (l16 & 7);
                af[mt] = *(const bf16x8_t*)&lA[t][row * 64 + phys * 8];
            }
            #pragma unroll
            for (int mt = 0; mt < 4; mt++) {
                acc1[mt][0] = __builtin_amdgcn_mfma_f32_16x16x32_bf16(af[mt], wA[0][tk], acc1[mt][0], 0, 0, 0);
                acc1[mt][1] = __builtin_amdgcn_mfma_f32_16x16x32_bf16(af[mt], wA[1][tk], acc1[mt][1], 0, 0, 0);
            }
        }

        // issue FULL W2 chunk now — latency hides under the first half's handoff
        const u16* w2p = W2f + ((long)((c * 4 + wave) * 5) * 4) * 512 + lane * 8;
        bf16x8_t wB[5][4];
        #pragma unroll
        for (int nt = 0; nt < 5; nt++)
            #pragma unroll
            for (int ks = 0; ks < 4; ks++)
                wB[nt][ks] = *(const bf16x8_t*)(w2p + (nt * 4 + ks) * 512);

        // ---------- handoff + phase B in two 64-col halves (z1c = 8 KB) ----------
        #pragma unroll
        for (int h = 0; h < 2; h++) {
            rbar();  // previous half's readers done with z1c
            if ((wave >> 1) == h) {
                int wl = wave & 1;  // wave index within this half (0..1)
                #pragma unroll
                for (int nt = 0; nt < 2; nt++) {
                    int col = wl * 32 + nt * 16 + l16;   // local col 0..63
                    #pragma unroll
                    for (int mt = 0; mt < 4; mt++) {
                        #pragma unroll
                        for (int r = 0; r < 4; r++) {
                            int row = mt * 16 + quad * 4 + r;
                            float v = fmaxf(acc1[mt][nt][r] + rb1[c][nt], 0.f);
                            int phys = ((col >> 3) & 7) ^ (row & 7);
                            z1c[row * 64 + phys * 8 + (col & 7)] = f2bf(v);
                        }
                    }
                }
            }
            lwait0();
            rbar();  // half visible to all waves
            #pragma unroll
            for (int ks2 = 0; ks2 < 2; ks2++) {
                const int ks = h * 2 + ks2;
                bf16x8_t af[4];
                #pragma unroll
                for (int mt = 0; mt < 4; mt++) {
                    int row = mt * 16 + l16;
                    int phys = (ks2 * 4 + quad) ^ (row & 7);
                    af[mt] = *(const bf16x8_t*)&z1c[row * 64 + phys * 8];
                }
                #pragma unroll
                for (int mt = 0; mt < 4; mt++)
                    #pragma unroll
                    for (int nt = 0; nt < 5; nt++)
                        acc2[mt][nt] = __builtin_amdgcn_mfma_f32_16x16x32_bf16(af[mt], wB[nt][ks], acc2[mt][nt], 0, 0, 0);
            }
        }
    }

    // ---------- epilogue: bias, bf16 store (in-place), BN stats ----------
    #pragma unroll
    for (int nt = 0; nt < 5; nt++) {
        int col = wave * 80 + nt * 16 + l16;
        float s = 0.f, s2 = 0.f;
        #pragma unroll
        for (int mt = 0; mt < 4; mt++) {
            #pragma unroll
            for (int r = 0; r < 4; r++) {
                long row = tm + mt * 16 + quad * 4 + r;
                float v = acc2[mt][nt][r] + rb2[nt];
                float sv = (col < kH) ? v : 0.f;
                outp[row * KP_H + col] = f2bf(sv);
                s += sv; s2 += sv * sv;
            }
        }
        atomicAdd(&sred[col][0], s);
        atomicAdd(&sred[col][1], s2);
    }
    __syncthreads();
    for (int i = tid; i < kH; i += 256) {
        atomicAdd(&stats[i], sred[i][0]);
        atomicAdd(&stats[kH + i], sred[i][1]);
    }
}

// ---------------- GEMM: 128x128 tile, BK=64, counted-vmcnt double-buffered pipeline ----------------
template<int ACT, int OUT_BF16, int BN_STATS>
__global__ __launch_bounds__(256) void gemm_k(
    const u16* __restrict__ A, const u16* __restrict__ Wt,
    const float* __restrict__ bias, void* __restrict__ out,
    float* __restrict__ stats,
    int KP, int NN, int out_stride, int store_cols) {
    __shared__ __align__(16) u16 lA[2][128 * 64];
    __shared__ __align__(16) u16 lB[2][128 * 64];
    __shared__ float sred[128][2];

    const int tid = threadIdx.x;
    const int lane = tid & 63;
    const int wave = tid >> 6;
    const int l16 = lane & 15;
    const int quad = lane >> 4;
    const int wm = (wave & 1) * 64;
    const int wn = (wave >> 1) * 64;
    int sm, sn;
    swz_tile(sm, sn);
    const long tm = (long)sm * 128;
    const int tn = sn * 128;

    const int srow = lane >> 3;
    const int sch = (lane & 7) ^ srow;

    f32x4_t acc[4][4];
    #pragma unroll
    for (int i = 0; i < 4; i++)
        #pragma unroll
        for (int j = 0; j < 4; j++) acc[i][j] = (f32x4_t){0.f, 0.f, 0.f, 0.f};

    auto stage = [&](int bb, int k0) {  // 8 VMEM per wave
        #pragma unroll
        for (int j = 0; j < 4; j++) {
            int rb = wave * 32 + j * 8;
            int r = rb + srow;
            gld16(A + (tm + r) * KP + k0 + sch * 8, &lA[bb][rb * 64]);
            gld16(Wt + (long)(tn + r) * KP + k0 + sch * 8, &lB[bb][rb * 64]);
        }
    };

    const int nk = KP >> 6;
    stage(0, 0);
    if (nk > 1) stage(1, 64);
    for (int t = 0; t < nk; t++) {
        if (t < nk - 1) vwait8(); else vwait0();
        rbar();
        const u16* la = lA[t & 1];
        const u16* lb = lB[t & 1];
        #pragma unroll
        for (int ks = 0; ks < 2; ks++) {
            bf16x8_t af[4], bfr[4];
            #pragma unroll
            for (int mt = 0; mt < 4; mt++) {
                int row = wm + mt * 16 + l16;
                int phys = (ks * 4 + quad) ^ (l16 & 7);
                af[mt] = *(const bf16x8_t*)&la[row * 64 + phys * 8];
            }
            #pragma unroll
            for (int nt = 0; nt < 4; nt++) {
                int row = wn + nt * 16 + l16;
                int phys = (ks * 4 + quad) ^ (l16 & 7);
                bfr[nt] = *(const bf16x8_t*)&lb[row * 64 + phys * 8];
            }
            #pragma unroll
            for (int mt = 0; mt < 4; mt++)
                #pragma unroll
                for (int nt = 0; nt < 4; nt++)
                    acc[mt][nt] = __builtin_amdgcn_mfma_f32_16x16x32_bf16(af[mt], bfr[nt], acc[mt][nt], 0, 0, 0);
        }
        rbar();
        if (t + 2 < nk) stage(t & 1, (t + 2) * 64);
    }

    if (BN_STATS) {
        if (tid < 128) { sred[tid][0] = 0.f; sred[tid][1] = 0.f; }
    }
    __syncthreads();

    #pragma unroll
    for (int nt = 0; nt < 4; nt++) {
        int col = tn + wn + nt * 16 + l16;
        float bv = (col < NN) ? bias[col] : 0.f;
        float s = 0.f, s2 = 0.f;
        #pragma unroll
        for (int mt = 0; mt < 4; mt++) {
            #pragma unroll
            for (int r = 0; r < 4; r++) {
                long row = tm + wm + mt * 16 + quad * 4 + r;
                float v = acc[mt][nt][r] + bv;
                if (ACT) v = fmaxf(v, 0.f);
                float sv = (col < NN) ? v : 0.f;
                if (col < store_cols) {
                    if (OUT_BF16) ((u16*)out)[row * out_stride + col] = f2bf(sv);
                    else          ((float*)out)[row * out_stride + col] = sv;
                }
                s += sv; s2 += sv * sv;
            }
        }
        if (BN_STATS) {
            atomicAdd(&sred[wn + nt * 16 + l16][0], s);
            atomicAdd(&sred[wn + nt * 16 + l16][1], s2);
        }
    }
    if (BN_STATS) {
        __syncthreads();
        if (tid < 128) {
            int col = tn + tid;
            if (col < NN) {
                atomicAdd(&stats[col], sred[tid][0]);
                atomicAdd(&stats[NN + col], sred[tid][1]);
            }
        }
    }
}

// ---------------- GEMM64: 128x64 tile; OUT_MODE: 0=f32, 1=bf16, 2=vn_nxt = vn_cur + relu(v) ----------------
template<int ACT, int OUT_MODE, int BN_STATS>
__global__ __launch_bounds__(256) void gemm64_k(
    const u16* __restrict__ A, const u16* __restrict__ Wt,
    const float* __restrict__ bias, void* __restrict__ out,
    float* __restrict__ stats, const float* __restrict__ vnacc,
    int KP, int NN, int out_stride, int store_cols) {
    __shared__ __align__(16) u16 lA[2][128 * 64];
    __shared__ __align__(16) u16 lB[2][64 * 64];
    __shared__ float sred[64][2];

    const int tid = threadIdx.x;
    const int lane = tid & 63;
    const int wave = tid >> 6;
    const int l16 = lane & 15;
    const int quad = lane >> 4;
    const int wm = (wave & 1) * 64;
    const int wn = (wave >> 1) * 32;
    int sm, sn;
    swz_tile(sm, sn);
    const long tm = (long)sm * 128;
    const int tn = sn * 64;

    const int srow = lane >> 3;
    const int sch = (lane & 7) ^ srow;

    f32x4_t acc[4][2];
    #pragma unroll
    for (int i = 0; i < 4; i++)
        #pragma unroll
        for (int j = 0; j < 2; j++) acc[i][j] = (f32x4_t){0.f, 0.f, 0.f, 0.f};

    auto stage = [&](int bb, int k0) {  // 6 VMEM per wave
        #pragma unroll
        for (int j = 0; j < 4; j++) {
            int rb = wave * 32 + j * 8;
            gld16(A + (tm + rb + srow) * KP + k0 + sch * 8, &lA[bb][rb * 64]);
        }
        #pragma unroll
        for (int j = 0; j < 2; j++) {
            int rb = wave * 16 + j * 8;
            gld16(Wt + (long)(tn + rb + srow) * KP + k0 + sch * 8, &lB[bb][rb * 64]);
        }
    };

    const int nk = KP >> 6;
    stage(0, 0);
    if (nk > 1) stage(1, 64);
    for (int t = 0; t < nk; t++) {
        if (t < nk - 1) vwait6(); else vwait0();
        rbar();
        const u16* la = lA[t & 1];
        const u16* lb = lB[t & 1];
        #pragma unroll
        for (int ks = 0; ks < 2; ks++) {
            bf16x8_t af[4], bfr[2];
            #pragma unroll
            for (int mt = 0; mt < 4; mt++) {
                int row = wm + mt * 16 + l16;
                int phys = (ks * 4 + quad) ^ (l16 & 7);
                af[mt] = *(const bf16x8_t*)&la[row * 64 + phys * 8];
            }
            #pragma unroll
            for (int nt = 0; nt < 2; nt++) {
                int row = wn + nt * 16 + l16;
                int phys = (ks * 4 + quad) ^ (l16 & 7);
                bfr[nt] = *(const bf16x8_t*)&lb[row * 64 + phys * 8];
            }
            #pragma unroll
            for (int mt = 0; mt < 4; mt++)
                #pragma unroll
                for (int nt = 0; nt < 2; nt++)
                    acc[mt][nt] = __builtin_amdgcn_mfma_f32_16x16x32_bf16(af[mt], bfr[nt], acc[mt][nt], 0, 0, 0);
        }
        rbar();
        if (t + 2 < nk) stage(t & 1, (t + 2) * 64);
    }

    if (BN_STATS) {
        if (tid < 64) { sred[tid][0] = 0.f; sred[tid][1] = 0.f; }
    }
    __syncthreads();

    #pragma unroll
    for (int nt = 0; nt < 2; nt++) {
        int col = tn + wn + nt * 16 + l16;
        float bv = (col < NN) ? bias[col] : 0.f;
        float s = 0.f, s2 = 0.f;
        #pragma unroll
        for (int mt = 0; mt < 4; mt++) {
            #pragma unroll
            for (int r = 0; r < 4; r++) {
                long row = tm + wm + mt * 16 + quad * 4 + r;
                float v = acc[mt][nt][r] + bv;
                if (ACT) v = fmaxf(v, 0.f);
                float sv = (col < NN) ? v : 0.f;
                if (col < store_cols) {
                    if (OUT_MODE == 1) ((u16*)out)[row * out_stride + col] = f2bf(sv);
                    else if (OUT_MODE == 2)
                        ((float*)out)[row * out_stride + col] =
                            vnacc[row * out_stride + col] + fmaxf(v, 0.f);
                    else ((float*)out)[row * out_stride + col] = sv;
                }
                s += sv; s2 += sv * sv;
            }
        }
        if (BN_STATS) {
            atomicAdd(&sred[wn + nt * 16 + l16][0], s);
            atomicAdd(&sred[wn + nt * 16 + l16][1], s2);
        }
    }
    if (BN_STATS) {
        __syncthreads();
        if (tid < 64) {
            int col = tn + tid;
            if (col < NN) {
                atomicAdd(&stats[col], sred[tid][0]);
                atomicAdd(&stats[NN + col], sred[tid][1]);
            }
        }
    }
}

// ---------------- BN-apply + (relu) + residual ----------------
template<int RELU>
__global__ __launch_bounds__(256) void resid_k(
    u32* __restrict__ hvb32, const u32* __restrict__ z32,
    const float* __restrict__ stats,
    const float* __restrict__ scale, const float* __restrict__ bias, int l,
    const int* __restrict__ batch,
    const float* __restrict__ vncur, const float* __restrict__ vnnxt) {
    int tid = threadIdx.x;
    int wave = tid >> 6, lane = tid & 63;
    int n = blockIdx.x * 4 + wave;
    int g = batch[n];
    #pragma unroll
    for (int p = 0; p < 3; p++) {
        int ii = lane + p * 64;
        if (ii >= 150) break;
        int c0 = 2 * ii;
        float m0 = stats[c0] * (1.f / (float)kN), m1 = stats[c0 + 1] * (1.f / (float)kN);
        float v0 = fmaxf(stats[kH + c0] * (1.f / (float)kN) - m0 * m0, 0.f);
        float v1 = fmaxf(stats[kH + c0 + 1] * (1.f / (float)kN) - m1 * m1, 0.f);
        float a0 = scale[l * kH + c0] * rsqrtf(v0 + 1e-5f);
        float a1 = scale[l * kH + c0 + 1] * rsqrtf(v1 + 1e-5f);
        float d0 = bias[l * kH + c0] - m0 * a0;
        float d1 = bias[l * kH + c0 + 1] - m1 * a1;
        u32 zz = z32[(long)n * HVS32 + ii];
        u32 ho = hvb32[(long)n * HVS32 + ii];
        float2 vc = *(const float2*)(vncur + g * kH + c0);
        float2 vx = *(const float2*)(vnnxt + g * kH + c0);
        float t0 = blo(zz) * a0 + d0;
        float t1 = bhi(zz) * a1 + d1;
        if (RELU) { t0 = fmaxf(t0, 0.f); t1 = fmaxf(t1, 0.f); }
        float h0 = (blo(ho) - vc.x) + t0;
        float h1 = (bhi(ho) - vc.y) + t1;
        hvb32[(long)n * HVS32 + ii] = pack2(h0 + vx.x, h1 + vx.y);
    }
}

// ---------------- pooled mean (wave per graph) ----------------
__global__ __launch_bounds__(256) void pooled_k(
    const u32* __restrict__ hv32, const float* __restrict__ vnlast,
    const int* __restrict__ counts, const int* __restrict__ starts,
    u32* __restrict__ hrep32) {
    int tid = threadIdx.x, wave = tid >> 6, lane = tid & 63;
    int g = blockIdx.x * 4 + wave;
    int cnt = counts[g], st = starts[g];
    int i0 = lane, i1 = lane + 64, i2 = lane + 128;
    bool p2 = (i2 < 150);
    float a0 = 0.f, b0 = 0.f, a1 = 0.f, b1 = 0.f, a2 = 0.f, b2 = 0.f;
    int i = 0;
    for (; i + 4 <= cnt; i += 4) {
        const u32* rA = hv32 + (long)(st + i) * HVS32;
        const u32* rB = hv32 + (long)(st + i + 1) * HVS32;
        const u32* rC = hv32 + (long)(st + i + 2) * HVS32;
        const u32* rD = hv32 + (long)(st + i + 3) * HVS32;
        u32 vA0 = rA[i0], vA1 = rA[i1], vA2 = p2 ? rA[i2] : 0u;
        u32 vB0 = rB[i0], vB1 = rB[i1], vB2 = p2 ? rB[i2] : 0u;
        u32 vC0 = rC[i0], vC1 = rC[i1], vC2 = p2 ? rC[i2] : 0u;
        u32 vD0 = rD[i0], vD1 = rD[i1], vD2 = p2 ? rD[i2] : 0u;
        a0 += (blo(vA0) + blo(vB0)) + (blo(vC0) + blo(vD0));
        b0 += (bhi(vA0) + bhi(vB0)) + (bhi(vC0) + bhi(vD0));
        a1 += (blo(vA1) + blo(vB1)) + (blo(vC1) + blo(vD1));
        b1 += (bhi(vA1) + bhi(vB1)) + (bhi(vC1) + bhi(vD1));
        a2 += (blo(vA2) + blo(vB2)) + (blo(vC2) + blo(vD2));
        b2 += (bhi(vA2) + bhi(vB2)) + (bhi(vC2) + bhi(vD2));
    }
    for (; i < cnt; i++) {
        const u32* rA = hv32 + (long)(st + i) * HVS32;
        u32 vA0 = rA[i0], vA1 = rA[i1], vA2 = p2 ? rA[i2] : 0u;
        a0 += blo(vA0); b0 += bhi(vA0);
        a1 += blo(vA1); b1 += bhi(vA1);
        a2 += blo(vA2); b2 += bhi(vA2);
    }
    float fc = (float)cnt;
    float inv = 1.f / (float)(cnt > 0 ? cnt : 1);
    const float* vg = vnlast + g * kH;
    hrep32[(long)g * 768 + i0] = pack2((a0 - fc * vg[2 * i0]) * inv, (b0 - fc * vg[2 * i0 + 1]) * inv);
    hrep32[(long)g * 768 + i1] = pack2((a1 - fc * vg[2 * i1]) * inv, (b1 - fc * vg[2 * i1 + 1]) * inv);
    if (p2)
        hrep32[(long)g * 768 + i2] = pack2((a2 - fc * vg[2 * i2]) * inv, (b2 - fc * vg[2 * i2 + 1]) * inv);
}

// ---------------- h_rep cols [300,1536) ----------------
__global__ void hrep_rest_k(const float* __restrict__ morgan, const float* __restrict__ maccs,
                            const int* __restrict__ counts, u16* __restrict__ hrep) {
    long idx = (long)blockIdx.x * 256 + threadIdx.x;
    if (idx >= (long)kG * (KP_DG - kH)) return;
    int g = (int)(idx / (KP_DG - kH));
    int j = (int)(idx % (KP_DG - kH));
    int col = kH + j;
    u16 v;
    if (j < kF) {
        int c = counts[g];
        int q = (j < c) ? ((c - 1 - j) / kF + 1) : 0;
        v = f2bf((float)q / (float)(c > 0 ? c : 1));
    } else if (j < kF + 1024) {
        v = f2bf(morgan[(long)g * 1024 + (j - kF)]);
    } else if (j < kF + 1024 + 167) {
        v = f2bf(maccs[(long)g * 167 + (j - kF - 1024)]);
    } else {
        v = 0;
    }
    hrep[(long)g * KP_DG + col] = v;
}

// ---------------- final ----------------
__global__ void final_k(const u16* __restrict__ zp, const float* __restrict__ Wp2,
                        const float* __restrict__ bp2, float* __restrict__ out) {
    int wave = threadIdx.x >> 6, lane = threadIdx.x & 63;
    int g = blockIdx.x * 4 + wave;
    float acc = 0.f;
    for (int c = lane; c < kH2; c += 64) acc += bf2f(zp[(long)g * KP_H2 + c]) * Wp2[c];
    #pragma unroll
    for (int off = 32; off; off >>= 1) acc += __shfl_down(acc, off);
    if (lane == 0) out[g] = acc + bp2[0];
}

extern "C" void kernel_launch(void* const* d_in, const int* in_sizes, int n_in,
                              void* d_out, int out_size, void* d_ws, size_t ws_size,
                              hipStream_t stream) {
    const float* x      = (const float*)d_in[0];
    const float* morgan = (const float*)d_in[1];
    const float* maccs  = (const float*)d_in[2];
    const int*   ei     = (const int*)d_in[3];
    const int*   batch  = (const int*)d_in[4];
    const float* W_emb  = (const float*)d_in[5];
    const float* b_emb  = (const float*)d_in[6];
    const float* gin_W1 = (const float*)d_in[7];
    const float* gin_b1 = (const float*)d_in[8];
    const float* gin_W2 = (const float*)d_in[9];
    const float* gin_b2 = (const float*)d_in[10];
    const float* bn_scale = (const float*)d_in[11];
    const float* bn_bias  = (const float*)d_in[12];
    const float* eps    = (const float*)d_in[13];
    const float* vn0    = (const float*)d_in[14];
    const float* vn_W1  = (const float*)d_in[15];
    const float* vn_b1  = (const float*)d_in[16];
    const float* vn_W2  = (const float*)d_in[17];
    const float* vn_b2  = (const float*)d_in[18];
    const float* Wp1    = (const float*)d_in[19];
    const float* bp1    = (const float*)d_in[20];
    const float* Wp2    = (const float*)d_in[21];
    const float* bp2    = (const float*)d_in[22];
    float* out = (float*)d_out;

    char* ws = (char*)d_ws;
    size_t off = 0;
    auto alloc = [&](size_t bytes) -> char* {
        char* p = ws + off;
        off += (bytes + 255) & ~(size_t)255;
        return p;
    };
    u16*   hvbf = (u16*)alloc((size_t)kN * HVS * 2);        // 41.9 MB
    u16*   hv   = (u16*)alloc((size_t)kN * KP_H * 2);       // 41.9 MB
    u16*   z1   = (u16*)alloc((size_t)kN * KP_H2 * 2);      // 83.9 MB (vn/pred overlays)
    float* vnA  = (float*)alloc((size_t)kG * kH * 4);
    float* vnB  = (float*)alloc((size_t)kG * kH * 4);
    int* counts = (int*)alloc(kG * 4);
    int* starts = (int*)alloc(kG * 4);
    float* stats = (float*)alloc(2 * kH * 4);
    int* cnt_n  = (int*)alloc((size_t)kN * 4);
    int* start_n = (int*)alloc((size_t)(kN + 1) * 4);
    int* fill_n = (int*)alloc((size_t)kN * 4);
    int* bsum   = (int*)alloc((kN / 1024) * 4);
    int* perm   = (int*)alloc((size_t)kE * 4);
    u16* W1f   = (u16*)alloc((size_t)kL * WFRAG_PER_L * 2);   // 2.05 MB fragment-packed gin_W1
    u16* W2f   = (u16*)alloc((size_t)kL * WFRAG_PER_L * 2);   // 2.05 MB fragment-packed gin_W2
    u16* Wt_v1 = (u16*)alloc((size_t)(kL - 1) * NP_H2 * KP_H * 2);
    u16* Wt_v2 = (u16*)alloc((size_t)(kL - 1) * NP_H * KP_H2 * 2);
    u16* Wt_p1 = (u16*)alloc((size_t)NP_H2 * KP_DG * 2);
    if (off > ws_size) return;

    // z1-region overlays (disjoint lifetimes):
    u16* vt_in = z1;                                   // [2048,320] bf16 (pre vn-G1)
    u16* z1v   = z1 + (size_t)4 * 1024 * 1024;         // [2048,640] bf16 (pre vn-G1)
    u16* hrep  = z1;                                   // [2048,1536] bf16 (post layers)
    u16* zp    = z1 + (size_t)8 * 1024 * 1024;         // [2048,640] bf16 (post layers)
    float* vnb[2] = {vnA, vnB};

    // weight packing / transposes
    {
        long tf = (long)kL * WFRAG_PER_L;
        pack_w1_k<<<dim3((unsigned)((tf + 255) / 256)), 256, 0, stream>>>(gin_W1, W1f, tf);
        pack_w2_k<<<dim3((unsigned)((tf + 255) / 256)), 256, 0, stream>>>(gin_W2, W2f, tf);
        long t3 = (long)(kL - 1) * NP_H2 * KP_H;
        transpose_k<<<dim3((unsigned)((t3 + 255) / 256)), 256, 0, stream>>>(vn_W1, Wt_v1, kH, kH2, NP_H2, KP_H, t3);
        long t4 = (long)(kL - 1) * NP_H * KP_H2;
        transpose_k<<<dim3((unsigned)((t4 + 255) / 256)), 256, 0, stream>>>(vn_W2, Wt_v2, kH2, kH, NP_H, KP_H2, t4);
        long t5 = (long)NP_H2 * KP_DG;
        transpose_k<<<dim3((unsigned)((t5 + 255) / 256)), 256, 0, stream>>>(Wp1, Wt_p1, kDG, kH2, NP_H2, KP_DG, t5);
    }

    // graph ranges + node CSR
    hipMemsetAsync(counts, 0, kG * 4, stream);
    hipMemsetAsync(cnt_n, 0, (size_t)kN * 4, stream);
    hipMemsetAsync(fill_n, 0, (size_t)kN * 4, stream);
    hist_g_k<<<kN / 256, 256, 0, stream>>>(batch, counts);
    scan_g_k<<<1, 1024, 0, stream>>>(counts, starts);
    hist_n_k<<<kE / 256, 256, 0, stream>>>(ei, cnt_n);
    scanA_k<<<kN / 1024, 1024, 0, stream>>>(cnt_n, start_n, bsum);
    scanB_k<<<1, 64, 0, stream>>>(bsum);
    scanC_k<<<kN / 1024, 1024, 0, stream>>>(start_n, bsum);
    fill_n_k<<<kE / 256, 256, 0, stream>>>(ei, start_n, fill_n, perm);

    embed_k<<<kN / 4, 256, 0, stream>>>(x, W_emb, b_emb, vn0, (u32*)hvbf);
    vninit_k<<<kG, 320, 0, stream>>>(vn0, vnA);

    for (int l = 0; l < kL; l++) {
        float* vcur = vnb[l & 1];
        float* vnxt = vnb[(l + 1) & 1];
        gather_combine_k<<<kN / 4, 256, 0, stream>>>(
            (const u32*)hvbf, start_n, perm, eps, l, (u32*)hv, stats);
        if (l < kL - 1) {
            vt_fin_k<<<kG / 4, 256, 0, stream>>>(
                (const u32*)hvbf, vcur, counts, starts, (u32*)vt_in);
            gemm_k<1, 1, 0><<<dim3(16, NP_H2 / 128), 256, 0, stream>>>(
                vt_in, Wt_v1 + (size_t)l * NP_H2 * KP_H, vn_b1 + l * kH2,
                z1v, nullptr, KP_H, kH2, KP_H2, KP_H2);
            gemm64_k<0, 2, 0><<<dim3(16, NP_H / 64), 256, 0, stream>>>(
                z1v, Wt_v2 + (size_t)l * NP_H * KP_H2, vn_b2 + l * kH,
                vnxt, nullptr, vcur, KP_H2, kH, kH, kH);
        }
        // fused node MLP v5: hv -> hv (in-place), z1 never leaves LDS, 3 blocks/CU
        fused_mlp_k<<<kN / 64, 256, 0, stream>>>(
            hv, W1f + (size_t)l * WFRAG_PER_L, gin_b1 + l * kH2,
            W2f + (size_t)l * WFRAG_PER_L, gin_b2 + l * kH,
            hv, stats);
        if (l < kL - 1)
            resid_k<1><<<kN / 4, 256, 0, stream>>>(
                (u32*)hvbf, (const u32*)hv, stats, bn_scale, bn_bias, l, batch, vcur, vnxt);
        else
            resid_k<0><<<kN / 4, 256, 0, stream>>>(
                (u32*)hvbf, (const u32*)hv, stats, bn_scale, bn_bias, l, batch, vcur, vcur);
    }

    float* vnlast = vnb[(kL - 1) & 1];
    pooled_k<<<kG / 4, 256, 0, stream>>>(
        (const u32*)hvbf, vnlast, counts, starts, (u32*)hrep);
    {
        long tr = (long)kG * (KP_DG - kH);
        hrep_rest_k<<<dim3((unsigned)((tr + 255) / 256)), 256, 0, stream>>>(morgan, maccs, counts, hrep);
    }
    gemm_k<1, 1, 0><<<dim3(16, NP_H2 / 128), 256, 0, stream>>>(
        hrep, Wt_p1, bp1, zp, nullptr, KP_DG, kH2, KP_H2, KP_H2);
    final_k<<<kG / 4, 256, 0, stream>>>(zp, Wp2, bp2, out);
}

// Round 11
// 1259.324 us; speedup vs baseline: 1.7462x; 1.7462x over previous
//
#include <hip/hip_runtime.h>

typedef unsigned short u16;
typedef unsigned int u32;
typedef __attribute__((ext_vector_type(8))) short bf16x8_t;
typedef __attribute__((ext_vector_type(4))) float f32x4_t;

// problem constants
#define kN 65536
#define kE 262144
#define kG 2048
#define kH 300
#define kH2 600
#define kL 5
#define kF 32
#define kDG 1523
// padded dims
#define KP_H 320     // K pad of H
#define KP_H2 640    // K pad of 2H
#define KP_DG 1536   // K pad of DG
#define NP_H2 640    // N pad of 2H (128-tiled)
#define NP_H 320     // N pad of H (64-tiled)
// hvbf row stride (u16 / u32)
#define HVS 320
#define HVS32 160
// fragment-packed weight size per layer: 5*4*2*10*64*8 == 5*4*5*4*64*8 == 204800 u16
#define WFRAG_PER_L 204800

__device__ __forceinline__ float bf2f(u16 x) {
    union { u32 u; float f; } v; v.u = ((u32)x) << 16; return v.f;
}
__device__ __forceinline__ u16 f2bf(float f) {
    union { float f; u32 u; } v; v.f = f;
    u32 u = v.u;
    u32 r = (u + 0x7fffu + ((u >> 16) & 1u)) >> 16;  // RNE
    return (u16)r;
}
__device__ __forceinline__ float blo(u32 v) { return bf2f((u16)(v & 0xffffu)); }
__device__ __forceinline__ float bhi(u32 v) { return bf2f((u16)(v >> 16)); }
__device__ __forceinline__ u32 pack2(float lo, float hi) {
    return (u32)f2bf(lo) | ((u32)f2bf(hi) << 16);
}

// async 16B global -> LDS
__device__ __forceinline__ void gld16(const u16* g, u16* l) {
    __builtin_amdgcn_global_load_lds(
        (const __attribute__((address_space(1))) u32*)g,
        (__attribute__((address_space(3))) u32*)l, 16, 0, 0);
}

// counted vmcnt waits + raw barrier
__device__ __forceinline__ void vwait6() { asm volatile("s_waitcnt vmcnt(6)" ::: "memory"); }
__device__ __forceinline__ void vwait8() { asm volatile("s_waitcnt vmcnt(8)" ::: "memory"); }
__device__ __forceinline__ void vwait0() { asm volatile("s_waitcnt vmcnt(0)" ::: "memory"); }
__device__ __forceinline__ void lwait0() { asm volatile("s_waitcnt lgkmcnt(0)" ::: "memory"); }
__device__ __forceinline__ void rbar() {
    __builtin_amdgcn_sched_barrier(0);
    __builtin_amdgcn_s_barrier();
    __builtin_amdgcn_sched_barrier(0);
}

// XCD-bijective tile swizzle (requires gridDim.x % 8 == 0; holds: 16).
__device__ __forceinline__ void swz_tile(int& m, int& n) {
    int p = blockIdx.x + gridDim.x * blockIdx.y;
    int xcd = p & 7;
    int q = p >> 3;
    int NB = gridDim.y;
    int mb8 = gridDim.x >> 3;
    m = xcd * mb8 + q / NB;
    n = q % NB;
}

// ---------------- weight transpose: W[b][k][n] (f32) -> Wt[b][n][k] (bf16), zero-padded ----------------
__global__ void transpose_k(const float* __restrict__ W, u16* __restrict__ Wt,
                            int K, int NN, int NP, int KP, long total) {
    long idx = (long)blockIdx.x * 256 + threadIdx.x;
    if (idx >= total) return;
    int per = NP * KP;
    int b = (int)(idx / per);
    int r = (int)(idx % per);
    int n = r / KP;
    int k = r % KP;
    u16 v = 0;
    if (n < NN && k < K) v = f2bf(W[(long)b * K * NN + (long)k * NN + n]);
    Wt[idx] = v;
}

// ---------------- fragment-pack W1 (gin_W1 [L][300][600]) -> W1f [L][c][w][nt][tk][lane][8] ----------------
__global__ void pack_w1_k(const float* __restrict__ W, u16* __restrict__ Wf, long total) {
    long idx = (long)blockIdx.x * 256 + threadIdx.x;
    if (idx >= total) return;
    int l = (int)(idx / WFRAG_PER_L);
    long r = idx % WFRAG_PER_L;
    int e = (int)(r & 7);
    long r1 = r >> 3;
    int ln = (int)(r1 & 63);
    int l16 = ln & 15, quad = ln >> 4;
    long s = r1 >> 6;
    int tk = (int)(s % 10);
    long s2 = s / 10;
    int nt = (int)(s2 & 1);
    long s3 = s2 >> 1;
    int w = (int)(s3 & 3);
    int c = (int)(s3 >> 2);
    int n = c * 128 + w * 32 + nt * 16 + l16;
    int k = tk * 32 + quad * 8 + e;
    u16 v = 0;
    if (n < kH2 && k < kH) v = f2bf(W[(long)l * kH * kH2 + (long)k * kH2 + n]);
    Wf[idx] = v;
}

// ---------------- fragment-pack W2 (gin_W2 [L][600][300]) -> W2f [L][c][w][nt][ks][lane][8] ----------------
__global__ void pack_w2_k(const float* __restrict__ W, u16* __restrict__ Wf, long total) {
    long idx = (long)blockIdx.x * 256 + threadIdx.x;
    if (idx >= total) return;
    int l = (int)(idx / WFRAG_PER_L);
    long r = idx % WFRAG_PER_L;
    int e = (int)(r & 7);
    long r1 = r >> 3;
    int ln = (int)(r1 & 63);
    int l16 = ln & 15, quad = ln >> 4;
    long s = r1 >> 6;
    int ks = (int)(s & 3);
    long s2 = s >> 2;
    int nt = (int)(s2 % 5);
    long s3 = s2 / 5;
    int w = (int)(s3 & 3);
    int c = (int)(s3 >> 2);
    int n = w * 80 + nt * 16 + l16;
    int k = c * 128 + ks * 32 + quad * 8 + e;
    u16 v = 0;
    if (n < kH && k < kH2) v = f2bf(W[(long)l * kH2 * kH + (long)k * kH + n]);
    Wf[idx] = v;
}

// ---------------- graph histogram + scan ----------------
__global__ void hist_g_k(const int* __restrict__ batch, int* __restrict__ counts) {
    int n = blockIdx.x * 256 + threadIdx.x;
    if (n < kN) atomicAdd(&counts[batch[n]], 1);
}

__global__ void scan_g_k(const int* __restrict__ counts, int* __restrict__ starts) {
    __shared__ int s[1024];
    int t = threadIdx.x;
    int c0 = counts[2 * t], c1 = counts[2 * t + 1];
    s[t] = c0 + c1;
    __syncthreads();
    for (int off = 1; off < 1024; off <<= 1) {
        int v = (t >= off) ? s[t - off] : 0;
        __syncthreads();
        s[t] += v;
        __syncthreads();
    }
    int excl = (t > 0) ? s[t - 1] : 0;
    starts[2 * t] = excl;
    starts[2 * t + 1] = excl + c0;
}

// ---------------- node CSR build ----------------
__global__ void hist_n_k(const int* __restrict__ ei, int* __restrict__ cnt) {
    int e = blockIdx.x * 256 + threadIdx.x;
    if (e < kE) atomicAdd(&cnt[ei[kE + e]], 1);
}

__global__ void scanA_k(const int* __restrict__ cnt, int* __restrict__ start, int* __restrict__ bsum) {
    __shared__ int s[1024];
    int b = blockIdx.x, t = threadIdx.x;
    int v = cnt[b * 1024 + t];
    s[t] = v;
    __syncthreads();
    for (int off = 1; off < 1024; off <<= 1) {
        int u = (t >= off) ? s[t - off] : 0;
        __syncthreads();
        s[t] += u;
        __syncthreads();
    }
    start[b * 1024 + t] = s[t] - v;
    if (t == 1023) bsum[b] = s[1023];
}

__global__ void scanB_k(int* __restrict__ bsum) {
    if (threadIdx.x == 0) {
        int s = 0;
        for (int i = 0; i < kN / 1024; i++) { s += bsum[i]; bsum[i] = s; }
    }
}

__global__ void scanC_k(int* __restrict__ start, const int* __restrict__ bsum) {
    int b = blockIdx.x, t = threadIdx.x;
    int add = (b > 0) ? bsum[b - 1] : 0;
    start[b * 1024 + t] += add;
    if (b == kN / 1024 - 1 && t == 1023) start[kN] = bsum[kN / 1024 - 1];
}

__global__ void fill_n_k(const int* __restrict__ ei, const int* __restrict__ start,
                         int* __restrict__ fill, int* __restrict__ perm) {
    int e = blockIdx.x * 256 + threadIdx.x;
    if (e >= kE) return;
    int s = ei[e], d = ei[kE + e];
    int pos = start[d] + atomicAdd(&fill[d], 1);
    perm[pos] = s;
}

// ---------------- node embedding: hvbf = bf16(x@W+b + vn0) ----------------
__global__ __launch_bounds__(256) void embed_k(
    const float* __restrict__ x, const float* __restrict__ W,
    const float* __restrict__ b, const float* __restrict__ vn0,
    u32* __restrict__ hv32) {
    __shared__ float sW[9 * kH];
    __shared__ float sBV[kH];
    int tid = threadIdx.x;
    for (int i = tid; i < 9 * kH; i += 256) sW[i] = W[i];
    for (int i = tid; i < kH; i += 256) sBV[i] = b[i] + vn0[i];
    __syncthreads();
    int wave = tid >> 6, lane = tid & 63;
    int n = blockIdx.x * 4 + wave;
    float xv[9];
    #pragma unroll
    for (int d = 0; d < 9; d++) xv[d] = x[n * 9 + d];
    #pragma unroll
    for (int p = 0; p < 3; p++) {
        int ii = lane + p * 64;
        if (ii < 150) {
            int c0 = 2 * ii;
            float a0 = sBV[c0], a1 = sBV[c0 + 1];
            #pragma unroll
            for (int d = 0; d < 9; d++) {
                a0 += xv[d] * sW[d * kH + c0];
                a1 += xv[d] * sW[d * kH + c0 + 1];
            }
            hv32[(long)n * HVS32 + ii] = pack2(a0, a1);
        } else if (ii < HVS32) {
            hv32[(long)n * HVS32 + ii] = 0u;
        }
    }
}

__global__ void vninit_k(const float* __restrict__ vn0, float* __restrict__ vn) {
    int g = blockIdx.x, c = threadIdx.x;
    if (c < kH) vn[g * kH + c] = vn0[c];
}

// ---------------- gather + combine ----------------
__global__ __launch_bounds__(256) void gather_combine_k(
    const u32* __restrict__ hv32, const int* __restrict__ start_n,
    const int* __restrict__ perm, const float* __restrict__ eps, int l,
    u32* __restrict__ out32, float* __restrict__ stats) {
    int tid = threadIdx.x;
    int wave = tid >> 6, lane = tid & 63;
    int n = blockIdx.x * 4 + wave;
    int st = start_n[n], en = start_n[n + 1];
    int i0 = lane, i1 = lane + 64, i2 = lane + 128;
    bool p2 = (i2 < 150);
    float a0 = 0.f, b0 = 0.f, a1 = 0.f, b1 = 0.f, a2 = 0.f, b2 = 0.f;
    int e = st;
    for (; e + 4 <= en; e += 4) {
        const u32* rA = hv32 + (long)perm[e] * HVS32;
        const u32* rB = hv32 + (long)perm[e + 1] * HVS32;
        const u32* rC = hv32 + (long)perm[e + 2] * HVS32;
        const u32* rD = hv32 + (long)perm[e + 3] * HVS32;
        u32 vA0 = rA[i0], vA1 = rA[i1], vA2 = p2 ? rA[i2] : 0u;
        u32 vB0 = rB[i0], vB1 = rB[i1], vB2 = p2 ? rB[i2] : 0u;
        u32 vC0 = rC[i0], vC1 = rC[i1], vC2 = p2 ? rC[i2] : 0u;
        u32 vD0 = rD[i0], vD1 = rD[i1], vD2 = p2 ? rD[i2] : 0u;
        a0 += (blo(vA0) + blo(vB0)) + (blo(vC0) + blo(vD0));
        b0 += (bhi(vA0) + bhi(vB0)) + (bhi(vC0) + bhi(vD0));
        a1 += (blo(vA1) + blo(vB1)) + (blo(vC1) + blo(vD1));
        b1 += (bhi(vA1) + bhi(vB1)) + (bhi(vC1) + bhi(vD1));
        a2 += (blo(vA2) + blo(vB2)) + (blo(vC2) + blo(vD2));
        b2 += (bhi(vA2) + bhi(vB2)) + (bhi(vC2) + bhi(vD2));
    }
    for (; e + 2 <= en; e += 2) {
        const u32* rA = hv32 + (long)perm[e] * HVS32;
        const u32* rB = hv32 + (long)perm[e + 1] * HVS32;
        u32 vA0 = rA[i0], vA1 = rA[i1], vA2 = p2 ? rA[i2] : 0u;
        u32 vB0 = rB[i0], vB1 = rB[i1], vB2 = p2 ? rB[i2] : 0u;
        a0 += blo(vA0) + blo(vB0); b0 += bhi(vA0) + bhi(vB0);
        a1 += blo(vA1) + blo(vB1); b1 += bhi(vA1) + bhi(vB1);
        a2 += blo(vA2) + blo(vB2); b2 += bhi(vA2) + bhi(vB2);
    }
    if (e < en) {
        const u32* rA = hv32 + (long)perm[e] * HVS32;
        u32 vA0 = rA[i0], vA1 = rA[i1], vA2 = p2 ? rA[i2] : 0u;
        a0 += blo(vA0); b0 += bhi(vA0);
        a1 += blo(vA1); b1 += bhi(vA1);
        a2 += blo(vA2); b2 += bhi(vA2);
    }
    const u32* self = hv32 + (long)n * HVS32;
    float ep = 1.f + eps[l];
    u32 s0 = self[i0], s1 = self[i1];
    u32* o = out32 + (long)n * HVS32;
    o[i0] = pack2(ep * blo(s0) + a0, ep * bhi(s0) + b0);
    o[i1] = pack2(ep * blo(s1) + a1, ep * bhi(s1) + b1);
    if (p2) {
        u32 s2 = self[i2];
        o[i2] = pack2(ep * blo(s2) + a2, ep * bhi(s2) + b2);
    } else if (i2 < HVS32) {
        o[i2] = 0u;
    }
    int gz = blockIdx.x * 256 + tid;
    if (gz < 2 * kH) stats[gz] = 0.f;
}

// ---------------- vt (wave per graph): vt[g] = sum_rows hvbf + vn_cur[g] ----------------
__global__ __launch_bounds__(256) void vt_fin_k(
    const u32* __restrict__ hv32, const float* __restrict__ vncur,
    const int* __restrict__ counts, const int* __restrict__ starts,
    u32* __restrict__ vt32) {
    int tid = threadIdx.x, wave = tid >> 6, lane = tid & 63;
    int g = blockIdx.x * 4 + wave;
    int cnt = counts[g], st = starts[g];
    int i0 = lane, i1 = lane + 64, i2 = lane + 128;
    bool p2 = (i2 < 150);
    float a0 = 0.f, b0 = 0.f, a1 = 0.f, b1 = 0.f, a2 = 0.f, b2 = 0.f;
    int i = 0;
    for (; i + 4 <= cnt; i += 4) {
        const u32* rA = hv32 + (long)(st + i) * HVS32;
        const u32* rB = hv32 + (long)(st + i + 1) * HVS32;
        const u32* rC = hv32 + (long)(st + i + 2) * HVS32;
        const u32* rD = hv32 + (long)(st + i + 3) * HVS32;
        u32 vA0 = rA[i0], vA1 = rA[i1], vA2 = p2 ? rA[i2] : 0u;
        u32 vB0 = rB[i0], vB1 = rB[i1], vB2 = p2 ? rB[i2] : 0u;
        u32 vC0 = rC[i0], vC1 = rC[i1], vC2 = p2 ? rC[i2] : 0u;
        u32 vD0 = rD[i0], vD1 = rD[i1], vD2 = p2 ? rD[i2] : 0u;
        a0 += (blo(vA0) + blo(vB0)) + (blo(vC0) + blo(vD0));
        b0 += (bhi(vA0) + bhi(vB0)) + (bhi(vC0) + bhi(vD0));
        a1 += (blo(vA1) + blo(vB1)) + (blo(vC1) + blo(vD1));
        b1 += (bhi(vA1) + bhi(vB1)) + (bhi(vC1) + bhi(vD1));
        a2 += (blo(vA2) + blo(vB2)) + (blo(vC2) + blo(vD2));
        b2 += (bhi(vA2) + bhi(vB2)) + (bhi(vC2) + bhi(vD2));
    }
    for (; i < cnt; i++) {
        const u32* rA = hv32 + (long)(st + i) * HVS32;
        u32 vA0 = rA[i0], vA1 = rA[i1], vA2 = p2 ? rA[i2] : 0u;
        a0 += blo(vA0); b0 += bhi(vA0);
        a1 += blo(vA1); b1 += bhi(vA1);
        a2 += blo(vA2); b2 += bhi(vA2);
    }
    const float* vg = vncur + g * kH;
    vt32[(long)g * HVS32 + i0] = pack2(a0 + vg[2 * i0], b0 + vg[2 * i0 + 1]);
    vt32[(long)g * HVS32 + i1] = pack2(a1 + vg[2 * i1], b1 + vg[2 * i1 + 1]);
    if (p2) vt32[(long)g * HVS32 + i2] = pack2(a2 + vg[2 * i2], b2 + vg[2 * i2 + 1]);
    else if (i2 < HVS32) vt32[(long)g * HVS32 + i2] = 0u;
}

// ---------------- FUSED node MLP v3.2 (round-7 verified best): 256 thr / 64-row strip, 2 blocks/CU ----------------
// A strip persisted in LDS; W1/W2 fragment-packed in global (coalesced lane*16B loads);
// z1 chunk in XOR-swizzled LDS; 2 barriers per chunk; chunk loop fully unrolled.
// Phase-A weights: distance-3 rotating prefetch in wf[4] (preload 3, fetch (tk+3)&3 != tk&3).
__global__ __launch_bounds__(256, 2) void fused_mlp_k(
    const u16* __restrict__ A,      // hv [kN x 320] bf16
    const u16* __restrict__ W1f,    // fragment-packed [5][4][2][10][64][8]
    const float* __restrict__ b1,   // [600]
    const u16* __restrict__ W2f,    // fragment-packed [5][4][5][4][64][8]
    const float* __restrict__ b2,   // [300]
    u16* __restrict__ outp,         // hv (in-place)
    float* __restrict__ stats) {
    __shared__ __align__(16) u16 lA[5][64 * 64];   // 40 KB persistent A strip
    __shared__ __align__(16) u16 z1c[64 * 128];    // 16 KB z1 chunk, XOR swizzle
    __shared__ float sred[320][2];                 // 2.5 KB BN partial sums

    const int tid = threadIdx.x;
    const int lane = tid & 63;
    const int wave = tid >> 6;      // 0..3
    const int l16 = lane & 15;
    const int quad = lane >> 4;
    const long tm = (long)blockIdx.x * 64;
    const int srow = lane >> 3;
    const int sch = (lane & 7) ^ srow;

    for (int i = tid; i < 320; i += 256) { sred[i][0] = 0.f; sred[i][1] = 0.f; }

    // stage the whole A strip once (5 k-tiles x 64 rows)
    #pragma unroll
    for (int t = 0; t < 5; t++) {
        #pragma unroll
        for (int j = 0; j < 2; j++) {
            int rb = wave * 16 + j * 8;
            gld16(A + (tm + rb + srow) * KP_H + t * 64 + sch * 8, &lA[t][rb * 64]);
        }
    }

    // preload biases (compile-time indexed after full unroll)
    float rb1[5][2];
    #pragma unroll
    for (int c = 0; c < 5; c++)
        #pragma unroll
        for (int nt = 0; nt < 2; nt++) {
            int gc = c * 128 + wave * 32 + nt * 16 + l16;
            rb1[c][nt] = (gc < kH2) ? b1[gc] : 0.f;
        }
    float rb2[5];
    #pragma unroll
    for (int nt = 0; nt < 5; nt++) {
        int col = wave * 80 + nt * 16 + l16;
        rb2[nt] = (col < kH) ? b2[col] : 0.f;
    }

    f32x4_t acc2[4][5];
    #pragma unroll
    for (int i = 0; i < 4; i++)
        #pragma unroll
        for (int j = 0; j < 5; j++) acc2[i][j] = (f32x4_t){0.f, 0.f, 0.f, 0.f};

    vwait0();
    rbar();  // A strip staged; sred zeroed

    #pragma unroll
    for (int c = 0; c < 5; c++) {
        // ---------- phase A (barrier-free): z1 chunk = A @ W1 chunk ----------
        f32x4_t acc1[4][2];
        #pragma unroll
        for (int i = 0; i < 4; i++) {
            acc1[i][0] = (f32x4_t){0.f, 0.f, 0.f, 0.f};
            acc1[i][1] = (f32x4_t){0.f, 0.f, 0.f, 0.f};
        }
        // fragment base for (c, wave): [((c*4+w)*2+nt)*10 + tk] frames of 512 u16
        const u16* w1p = W1f + ((long)((c * 4 + wave) * 2) * 10) * 512 + lane * 8;
        bf16x8_t wf[4][2];
        #pragma unroll
        for (int p = 0; p < 3; p++) {   // preload tk=0..2 (distance-3 rotation)
            wf[p][0] = *(const bf16x8_t*)(w1p + p * 512);
            wf[p][1] = *(const bf16x8_t*)(w1p + 10 * 512 + p * 512);
        }
        #pragma unroll
        for (int tk = 0; tk < 10; tk++) {
            if (tk + 3 < 10) {          // prefetch tk+3 into slot (tk+3)&3 != tk&3
                wf[(tk + 3) & 3][0] = *(const bf16x8_t*)(w1p + (tk + 3) * 512);
                wf[(tk + 3) & 3][1] = *(const bf16x8_t*)(w1p + 10 * 512 + (tk + 3) * 512);
            }
            const int t = tk >> 1, ks = tk & 1;
            bf16x8_t af[4];
            #pragma unroll
            for (int mt = 0; mt < 4; mt++) {
                int row = mt * 16 + l16;
                int phys = (ks * 4 + quad) ^ (l16 & 7);
                af[mt] = *(const bf16x8_t*)&lA[t][row * 64 + phys * 8];
            }
            #pragma unroll
            for (int mt = 0; mt < 4; mt++) {
                acc1[mt][0] = __builtin_amdgcn_mfma_f32_16x16x32_bf16(af[mt], wf[tk & 3][0], acc1[mt][0], 0, 0, 0);
                acc1[mt][1] = __builtin_amdgcn_mfma_f32_16x16x32_bf16(af[mt], wf[tk & 3][1], acc1[mt][1], 0, 0, 0);
            }
        }

        // ---------- z1c handoff ----------
        rbar();  // prior chunk's phase-B readers done with z1c
        #pragma unroll
        for (int nt = 0; nt < 2; nt++) {
            int col = wave * 32 + nt * 16 + l16;
            #pragma unroll
            for (int mt = 0; mt < 4; mt++) {
                #pragma unroll
                for (int r = 0; r < 4; r++) {
                    int row = mt * 16 + quad * 4 + r;
                    float v = fmaxf(acc1[mt][nt][r] + rb1[c][nt], 0.f);
                    int phys = (col >> 3) ^ (row & 15);
                    z1c[row * 128 + phys * 8 + (col & 7)] = f2bf(v);
                }
            }
        }
        lwait0();
        rbar();  // z1c visible to all waves

        // ---------- phase B (barrier-free): acc2 += z1c @ W2 chunk ----------
        const u16* w2p = W2f + ((long)((c * 4 + wave) * 5) * 4) * 512 + lane * 8;
        bf16x8_t wg[2][5];
        #pragma unroll
        for (int nt = 0; nt < 5; nt++)
            wg[0][nt] = *(const bf16x8_t*)(w2p + nt * 4 * 512);
        #pragma unroll
        for (int ks = 0; ks < 4; ks++) {
            if (ks + 1 < 4) {
                #pragma unroll
                for (int nt = 0; nt < 5; nt++)
                    wg[(ks + 1) & 1][nt] = *(const bf16x8_t*)(w2p + nt * 4 * 512 + (ks + 1) * 512);
            }
            bf16x8_t af[4];
            #pragma unroll
            for (int mt = 0; mt < 4; mt++) {
                int row = mt * 16 + l16;
                int phys = (ks * 4 + quad) ^ (row & 15);
                af[mt] = *(const bf16x8_t*)&z1c[row * 128 + phys * 8];
            }
            #pragma unroll
            for (int mt = 0; mt < 4; mt++)
                #pragma unroll
                for (int nt = 0; nt < 5; nt++)
                    acc2[mt][nt] = __builtin_amdgcn_mfma_f32_16x16x32_bf16(af[mt], wg[ks & 1][nt], acc2[mt][nt], 0, 0, 0);
        }
    }

    // ---------- epilogue: bias, bf16 store (in-place), BN stats ----------
    #pragma unroll
    for (int nt = 0; nt < 5; nt++) {
        int col = wave * 80 + nt * 16 + l16;
        float s = 0.f, s2 = 0.f;
        #pragma unroll
        for (int mt = 0; mt < 4; mt++) {
            #pragma unroll
            for (int r = 0; r < 4; r++) {
                long row = tm + mt * 16 + quad * 4 + r;
                float v = acc2[mt][nt][r] + rb2[nt];
                float sv = (col < kH) ? v : 0.f;
                outp[row * KP_H + col] = f2bf(sv);
                s += sv; s2 += sv * sv;
            }
        }
        atomicAdd(&sred[col][0], s);
        atomicAdd(&sred[col][1], s2);
    }
    __syncthreads();
    for (int i = tid; i < kH; i += 256) {
        atomicAdd(&stats[i], sred[i][0]);
        atomicAdd(&stats[kH + i], sred[i][1]);
    }
}

// ---------------- GEMM: 128x128 tile, BK=64, counted-vmcnt double-buffered pipeline ----------------
template<int ACT, int OUT_BF16, int BN_STATS>
__global__ __launch_bounds__(256) void gemm_k(
    const u16* __restrict__ A, const u16* __restrict__ Wt,
    const float* __restrict__ bias, void* __restrict__ out,
    float* __restrict__ stats,
    int KP, int NN, int out_stride, int store_cols) {
    __shared__ __align__(16) u16 lA[2][128 * 64];
    __shared__ __align__(16) u16 lB[2][128 * 64];
    __shared__ float sred[128][2];

    const int tid = threadIdx.x;
    const int lane = tid & 63;
    const int wave = tid >> 6;
    const int l16 = lane & 15;
    const int quad = lane >> 4;
    const int wm = (wave & 1) * 64;
    const int wn = (wave >> 1) * 64;
    int sm, sn;
    swz_tile(sm, sn);
    const long tm = (long)sm * 128;
    const int tn = sn * 128;

    const int srow = lane >> 3;
    const int sch = (lane & 7) ^ srow;

    f32x4_t acc[4][4];
    #pragma unroll
    for (int i = 0; i < 4; i++)
        #pragma unroll
        for (int j = 0; j < 4; j++) acc[i][j] = (f32x4_t){0.f, 0.f, 0.f, 0.f};

    auto stage = [&](int bb, int k0) {  // 8 VMEM per wave
        #pragma unroll
        for (int j = 0; j < 4; j++) {
            int rb = wave * 32 + j * 8;
            int r = rb + srow;
            gld16(A + (tm + r) * KP + k0 + sch * 8, &lA[bb][rb * 64]);
            gld16(Wt + (long)(tn + r) * KP + k0 + sch * 8, &lB[bb][rb * 64]);
        }
    };

    const int nk = KP >> 6;
    stage(0, 0);
    if (nk > 1) stage(1, 64);
    for (int t = 0; t < nk; t++) {
        if (t < nk - 1) vwait8(); else vwait0();
        rbar();
        const u16* la = lA[t & 1];
        const u16* lb = lB[t & 1];
        #pragma unroll
        for (int ks = 0; ks < 2; ks++) {
            bf16x8_t af[4], bfr[4];
            #pragma unroll
            for (int mt = 0; mt < 4; mt++) {
                int row = wm + mt * 16 + l16;
                int phys = (ks * 4 + quad) ^ (l16 & 7);
                af[mt] = *(const bf16x8_t*)&la[row * 64 + phys * 8];
            }
            #pragma unroll
            for (int nt = 0; nt < 4; nt++) {
                int row = wn + nt * 16 + l16;
                int phys = (ks * 4 + quad) ^ (l16 & 7);
                bfr[nt] = *(const bf16x8_t*)&lb[row * 64 + phys * 8];
            }
            #pragma unroll
            for (int mt = 0; mt < 4; mt++)
                #pragma unroll
                for (int nt = 0; nt < 4; nt++)
                    acc[mt][nt] = __builtin_amdgcn_mfma_f32_16x16x32_bf16(af[mt], bfr[nt], acc[mt][nt], 0, 0, 0);
        }
        rbar();
        if (t + 2 < nk) stage(t & 1, (t + 2) * 64);
    }

    if (BN_STATS) {
        if (tid < 128) { sred[tid][0] = 0.f; sred[tid][1] = 0.f; }
    }
    __syncthreads();

    #pragma unroll
    for (int nt = 0; nt < 4; nt++) {
        int col = tn + wn + nt * 16 + l16;
        float bv = (col < NN) ? bias[col] : 0.f;
        float s = 0.f, s2 = 0.f;
        #pragma unroll
        for (int mt = 0; mt < 4; mt++) {
            #pragma unroll
            for (int r = 0; r < 4; r++) {
                long row = tm + wm + mt * 16 + quad * 4 + r;
                float v = acc[mt][nt][r] + bv;
                if (ACT) v = fmaxf(v, 0.f);
                float sv = (col < NN) ? v : 0.f;
                if (col < store_cols) {
                    if (OUT_BF16) ((u16*)out)[row * out_stride + col] = f2bf(sv);
                    else          ((float*)out)[row * out_stride + col] = sv;
                }
                s += sv; s2 += sv * sv;
            }
        }
        if (BN_STATS) {
            atomicAdd(&sred[wn + nt * 16 + l16][0], s);
            atomicAdd(&sred[wn + nt * 16 + l16][1], s2);
        }
    }
    if (BN_STATS) {
        __syncthreads();
        if (tid < 128) {
            int col = tn + tid;
            if (col < NN) {
                atomicAdd(&stats[col], sred[tid][0]);
                atomicAdd(&stats[NN + col], sred[tid][1]);
            }
        }
    }
}

// ---------------- GEMM64: 128x64 tile; OUT_MODE: 0=f32, 1=bf16, 2=vn_nxt = vn_cur + relu(v) ----------------
template<int ACT, int OUT_MODE, int BN_STATS>
__global__ __launch_bounds__(256) void gemm64_k(
    const u16* __restrict__ A, const u16* __restrict__ Wt,
    const float* __restrict__ bias, void* __restrict__ out,
    float* __restrict__ stats, const float* __restrict__ vnacc,
    int KP, int NN, int out_stride, int store_cols) {
    __shared__ __align__(16) u16 lA[2][128 * 64];
    __shared__ __align__(16) u16 lB[2][64 * 64];
    __shared__ float sred[64][2];

    const int tid = threadIdx.x;
    const int lane = tid & 63;
    const int wave = tid >> 6;
    const int l16 = lane & 15;
    const int quad = lane >> 4;
    const int wm = (wave & 1) * 64;
    const int wn = (wave >> 1) * 32;
    int sm, sn;
    swz_tile(sm, sn);
    const long tm = (long)sm * 128;
    const int tn = sn * 64;

    const int srow = lane >> 3;
    const int sch = (lane & 7) ^ srow;

    f32x4_t acc[4][2];
    #pragma unroll
    for (int i = 0; i < 4; i++)
        #pragma unroll
        for (int j = 0; j < 2; j++) acc[i][j] = (f32x4_t){0.f, 0.f, 0.f, 0.f};

    auto stage = [&](int bb, int k0) {  // 6 VMEM per wave
        #pragma unroll
        for (int j = 0; j < 4; j++) {
            int rb = wave * 32 + j * 8;
            gld16(A + (tm + rb + srow) * KP + k0 + sch * 8, &lA[bb][rb * 64]);
        }
        #pragma unroll
        for (int j = 0; j < 2; j++) {
            int rb = wave * 16 + j * 8;
            gld16(Wt + (long)(tn + rb + srow) * KP + k0 + sch * 8, &lB[bb][rb * 64]);
        }
    };

    const int nk = KP >> 6;
    stage(0, 0);
    if (nk > 1) stage(1, 64);
    for (int t = 0; t < nk; t++) {
        if (t < nk - 1) vwait6(); else vwait0();
        rbar();
        const u16* la = lA[t & 1];
        const u16* lb = lB[t & 1];
        #pragma unroll
        for (int ks = 0; ks < 2; ks++) {
            bf16x8_t af[4], bfr[2];
            #pragma unroll
            for (int mt = 0; mt < 4; mt++) {
                int row = wm + mt * 16 + l16;
                int phys = (ks * 4 + quad) ^ (l16 & 7);
                af[mt] = *(const bf16x8_t*)&la[row * 64 + phys * 8];
            }
            #pragma unroll
            for (int nt = 0; nt < 2; nt++) {
                int row = wn + nt * 16 + l16;
                int phys = (ks * 4 + quad) ^ (l16 & 7);
                bfr[nt] = *(const bf16x8_t*)&lb[row * 64 + phys * 8];
            }
            #pragma unroll
            for (int mt = 0; mt < 4; mt++)
                #pragma unroll
                for (int nt = 0; nt < 2; nt++)
                    acc[mt][nt] = __builtin_amdgcn_mfma_f32_16x16x32_bf16(af[mt], bfr[nt], acc[mt][nt], 0, 0, 0);
        }
        rbar();
        if (t + 2 < nk) stage(t & 1, (t + 2) * 64);
    }

    if (BN_STATS) {
        if (tid < 64) { sred[tid][0] = 0.f; sred[tid][1] = 0.f; }
    }
    __syncthreads();

    #pragma unroll
    for (int nt = 0; nt < 2; nt++) {
        int col = tn + wn + nt * 16 + l16;
        float bv = (col < NN) ? bias[col] : 0.f;
        float s = 0.f, s2 = 0.f;
        #pragma unroll
        for (int mt = 0; mt < 4; mt++) {
            #pragma unroll
            for (int r = 0; r < 4; r++) {
                long row = tm + wm + mt * 16 + quad * 4 + r;
                float v = acc[mt][nt][r] + bv;
                if (ACT) v = fmaxf(v, 0.f);
                float sv = (col < NN) ? v : 0.f;
                if (col < store_cols) {
                    if (OUT_MODE == 1) ((u16*)out)[row * out_stride + col] = f2bf(sv);
                    else if (OUT_MODE == 2)
                        ((float*)out)[row * out_stride + col] =
                            vnacc[row * out_stride + col] + fmaxf(v, 0.f);
                    else ((float*)out)[row * out_stride + col] = sv;
                }
                s += sv; s2 += sv * sv;
            }
        }
        if (BN_STATS) {
            atomicAdd(&sred[wn + nt * 16 + l16][0], s);
            atomicAdd(&sred[wn + nt * 16 + l16][1], s2);
        }
    }
    if (BN_STATS) {
        __syncthreads();
        if (tid < 64) {
            int col = tn + tid;
            if (col < NN) {
                atomicAdd(&stats[col], sred[tid][0]);
                atomicAdd(&stats[NN + col], sred[tid][1]);
            }
        }
    }
}

// ---------------- BN-apply + (relu) + residual ----------------
template<int RELU>
__global__ __launch_bounds__(256) void resid_k(
    u32* __restrict__ hvb32, const u32* __restrict__ z32,
    const float* __restrict__ stats,
    const float* __restrict__ scale, const float* __restrict__ bias, int l,
    const int* __restrict__ batch,
    const float* __restrict__ vncur, const float* __restrict__ vnnxt) {
    int tid = threadIdx.x;
    int wave = tid >> 6, lane = tid & 63;
    int n = blockIdx.x * 4 + wave;
    int g = batch[n];
    #pragma unroll
    for (int p = 0; p < 3; p++) {
        int ii = lane + p * 64;
        if (ii >= 150) break;
        int c0 = 2 * ii;
        float m0 = stats[c0] * (1.f / (float)kN), m1 = stats[c0 + 1] * (1.f / (float)kN);
        float v0 = fmaxf(stats[kH + c0] * (1.f / (float)kN) - m0 * m0, 0.f);
        float v1 = fmaxf(stats[kH + c0 + 1] * (1.f / (float)kN) - m1 * m1, 0.f);
        float a0 = scale[l * kH + c0] * rsqrtf(v0 + 1e-5f);
        float a1 = scale[l * kH + c0 + 1] * rsqrtf(v1 + 1e-5f);
        float d0 = bias[l * kH + c0] - m0 * a0;
        float d1 = bias[l * kH + c0 + 1] - m1 * a1;
        u32 zz = z32[(long)n * HVS32 + ii];
        u32 ho = hvb32[(long)n * HVS32 + ii];
        float2 vc = *(const float2*)(vncur + g * kH + c0);
        float2 vx = *(const float2*)(vnnxt + g * kH + c0);
        float t0 = blo(zz) * a0 + d0;
        float t1 = bhi(zz) * a1 + d1;
        if (RELU) { t0 = fmaxf(t0, 0.f); t1 = fmaxf(t1, 0.f); }
        float h0 = (blo(ho) - vc.x) + t0;
        float h1 = (bhi(ho) - vc.y) + t1;
        hvb32[(long)n * HVS32 + ii] = pack2(h0 + vx.x, h1 + vx.y);
    }
}

// ---------------- pooled mean (wave per graph) ----------------
__global__ __launch_bounds__(256) void pooled_k(
    const u32* __restrict__ hv32, const float* __restrict__ vnlast,
    const int* __restrict__ counts, const int* __restrict__ starts,
    u32* __restrict__ hrep32) {
    int tid = threadIdx.x, wave = tid >> 6, lane = tid & 63;
    int g = blockIdx.x * 4 + wave;
    int cnt = counts[g], st = starts[g];
    int i0 = lane, i1 = lane + 64, i2 = lane + 128;
    bool p2 = (i2 < 150);
    float a0 = 0.f, b0 = 0.f, a1 = 0.f, b1 = 0.f, a2 = 0.f, b2 = 0.f;
    int i = 0;
    for (; i + 4 <= cnt; i += 4) {
        const u32* rA = hv32 + (long)(st + i) * HVS32;
        const u32* rB = hv32 + (long)(st + i + 1) * HVS32;
        const u32* rC = hv32 + (long)(st + i + 2) * HVS32;
        const u32* rD = hv32 + (long)(st + i + 3) * HVS32;
        u32 vA0 = rA[i0], vA1 = rA[i1], vA2 = p2 ? rA[i2] : 0u;
        u32 vB0 = rB[i0], vB1 = rB[i1], vB2 = p2 ? rB[i2] : 0u;
        u32 vC0 = rC[i0], vC1 = rC[i1], vC2 = p2 ? rC[i2] : 0u;
        u32 vD0 = rD[i0], vD1 = rD[i1], vD2 = p2 ? rD[i2] : 0u;
        a0 += (blo(vA0) + blo(vB0)) + (blo(vC0) + blo(vD0));
        b0 += (bhi(vA0) + bhi(vB0)) + (bhi(vC0) + bhi(vD0));
        a1 += (blo(vA1) + blo(vB1)) + (blo(vC1) + blo(vD1));
        b1 += (bhi(vA1) + bhi(vB1)) + (bhi(vC1) + bhi(vD1));
        a2 += (blo(vA2) + blo(vB2)) + (blo(vC2) + blo(vD2));
        b2 += (bhi(vA2) + bhi(vB2)) + (bhi(vC2) + bhi(vD2));
    }
    for (; i < cnt; i++) {
        const u32* rA = hv32 + (long)(st + i) * HVS32;
        u32 vA0 = rA[i0], vA1 = rA[i1], vA2 = p2 ? rA[i2] : 0u;
        a0 += blo(vA0); b0 += bhi(vA0);
        a1 += blo(vA1); b1 += bhi(vA1);
        a2 += blo(vA2); b2 += bhi(vA2);
    }
    float fc = (float)cnt;
    float inv = 1.f / (float)(cnt > 0 ? cnt : 1);
    const float* vg = vnlast + g * kH;
    hrep32[(long)g * 768 + i0] = pack2((a0 - fc * vg[2 * i0]) * inv, (b0 - fc * vg[2 * i0 + 1]) * inv);
    hrep32[(long)g * 768 + i1] = pack2((a1 - fc * vg[2 * i1]) * inv, (b1 - fc * vg[2 * i1 + 1]) * inv);
    if (p2)
        hrep32[(long)g * 768 + i2] = pack2((a2 - fc * vg[2 * i2]) * inv, (b2 - fc * vg[2 * i2 + 1]) * inv);
}

// ---------------- h_rep cols [300,1536) ----------------
__global__ void hrep_rest_k(const float* __restrict__ morgan, const float* __restrict__ maccs,
                            const int* __restrict__ counts, u16* __restrict__ hrep) {
    long idx = (long)blockIdx.x * 256 + threadIdx.x;
    if (idx >= (long)kG * (KP_DG - kH)) return;
    int g = (int)(idx / (KP_DG - kH));
    int j = (int)(idx % (KP_DG - kH));
    int col = kH + j;
    u16 v;
    if (j < kF) {
        int c = counts[g];
        int q = (j < c) ? ((c - 1 - j) / kF + 1) : 0;
        v = f2bf((float)q / (float)(c > 0 ? c : 1));
    } else if (j < kF + 1024) {
        v = f2bf(morgan[(long)g * 1024 + (j - kF)]);
    } else if (j < kF + 1024 + 167) {
        v = f2bf(maccs[(long)g * 167 + (j - kF - 1024)]);
    } else {
        v = 0;
    }
    hrep[(long)g * KP_DG + col] = v;
}

// ---------------- final ----------------
__global__ void final_k(const u16* __restrict__ zp, const float* __restrict__ Wp2,
                        const float* __restrict__ bp2, float* __restrict__ out) {
    int wave = threadIdx.x >> 6, lane = threadIdx.x & 63;
    int g = blockIdx.x * 4 + wave;
    float acc = 0.f;
    for (int c = lane; c < kH2; c += 64) acc += bf2f(zp[(long)g * KP_H2 + c]) * Wp2[c];
    #pragma unroll
    for (int off = 32; off; off >>= 1) acc += __shfl_down(acc, off);
    if (lane == 0) out[g] = acc + bp2[0];
}

extern "C" void kernel_launch(void* const* d_in, const int* in_sizes, int n_in,
                              void* d_out, int out_size, void* d_ws, size_t ws_size,
                              hipStream_t stream) {
    const float* x      = (const float*)d_in[0];
    const float* morgan = (const float*)d_in[1];
    const float* maccs  = (const float*)d_in[2];
    const int*   ei     = (const int*)d_in[3];
    const int*   batch  = (const int*)d_in[4];
    const float* W_emb  = (const float*)d_in[5];
    const float* b_emb  = (const float*)d_in[6];
    const float* gin_W1 = (const float*)d_in[7];
    const float* gin_b1 = (const float*)d_in[8];
    const float* gin_W2 = (const float*)d_in[9];
    const float* gin_b2 = (const float*)d_in[10];
    const float* bn_scale = (const float*)d_in[11];
    const float* bn_bias  = (const float*)d_in[12];
    const float* eps    = (const float*)d_in[13];
    const float* vn0    = (const float*)d_in[14];
    const float* vn_W1  = (const float*)d_in[15];
    const float* vn_b1  = (const float*)d_in[16];
    const float* vn_W2  = (const float*)d_in[17];
    const float* vn_b2  = (const float*)d_in[18];
    const float* Wp1    = (const float*)d_in[19];
    const float* bp1    = (const float*)d_in[20];
    const float* Wp2    = (const float*)d_in[21];
    const float* bp2    = (const float*)d_in[22];
    float* out = (float*)d_out;

    char* ws = (char*)d_ws;
    size_t off = 0;
    auto alloc = [&](size_t bytes) -> char* {
        char* p = ws + off;
        off += (bytes + 255) & ~(size_t)255;
        return p;
    };
    u16*   hvbf = (u16*)alloc((size_t)kN * HVS * 2);        // 41.9 MB
    u16*   hv   = (u16*)alloc((size_t)kN * KP_H * 2);       // 41.9 MB
    u16*   z1   = (u16*)alloc((size_t)kN * KP_H2 * 2);      // 83.9 MB (vn/pred overlays)
    float* vnA  = (float*)alloc((size_t)kG * kH * 4);
    float* vnB  = (float*)alloc((size_t)kG * kH * 4);
    int* counts = (int*)alloc(kG * 4);
    int* starts = (int*)alloc(kG * 4);
    float* stats = (float*)alloc(2 * kH * 4);
    int* cnt_n  = (int*)alloc((size_t)kN * 4);
    int* start_n = (int*)alloc((size_t)(kN + 1) * 4);
    int* fill_n = (int*)alloc((size_t)kN * 4);
    int* bsum   = (int*)alloc((kN / 1024) * 4);
    int* perm   = (int*)alloc((size_t)kE * 4);
    u16* W1f   = (u16*)alloc((size_t)kL * WFRAG_PER_L * 2);   // 2.05 MB fragment-packed gin_W1
    u16* W2f   = (u16*)alloc((size_t)kL * WFRAG_PER_L * 2);   // 2.05 MB fragment-packed gin_W2
    u16* Wt_v1 = (u16*)alloc((size_t)(kL - 1) * NP_H2 * KP_H * 2);
    u16* Wt_v2 = (u16*)alloc((size_t)(kL - 1) * NP_H * KP_H2 * 2);
    u16* Wt_p1 = (u16*)alloc((size_t)NP_H2 * KP_DG * 2);
    if (off > ws_size) return;

    // z1-region overlays (disjoint lifetimes):
    u16* vt_in = z1;                                   // [2048,320] bf16 (pre vn-G1)
    u16* z1v   = z1 + (size_t)4 * 1024 * 1024;         // [2048,640] bf16 (pre vn-G1)
    u16* hrep  = z1;                                   // [2048,1536] bf16 (post layers)
    u16* zp    = z1 + (size_t)8 * 1024 * 1024;         // [2048,640] bf16 (post layers)
    float* vnb[2] = {vnA, vnB};

    // weight packing / transposes
    {
        long tf = (long)kL * WFRAG_PER_L;
        pack_w1_k<<<dim3((unsigned)((tf + 255) / 256)), 256, 0, stream>>>(gin_W1, W1f, tf);
        pack_w2_k<<<dim3((unsigned)((tf + 255) / 256)), 256, 0, stream>>>(gin_W2, W2f, tf);
        long t3 = (long)(kL - 1) * NP_H2 * KP_H;
        transpose_k<<<dim3((unsigned)((t3 + 255) / 256)), 256, 0, stream>>>(vn_W1, Wt_v1, kH, kH2, NP_H2, KP_H, t3);
        long t4 = (long)(kL - 1) * NP_H * KP_H2;
        transpose_k<<<dim3((unsigned)((t4 + 255) / 256)), 256, 0, stream>>>(vn_W2, Wt_v2, kH2, kH, NP_H, KP_H2, t4);
        long t5 = (long)NP_H2 * KP_DG;
        transpose_k<<<dim3((unsigned)((t5 + 255) / 256)), 256, 0, stream>>>(Wp1, Wt_p1, kDG, kH2, NP_H2, KP_DG, t5);
    }

    // graph ranges + node CSR
    hipMemsetAsync(counts, 0, kG * 4, stream);
    hipMemsetAsync(cnt_n, 0, (size_t)kN * 4, stream);
    hipMemsetAsync(fill_n, 0, (size_t)kN * 4, stream);
    hist_g_k<<<kN / 256, 256, 0, stream>>>(batch, counts);
    scan_g_k<<<1, 1024, 0, stream>>>(counts, starts);
    hist_n_k<<<kE / 256, 256, 0, stream>>>(ei, cnt_n);
    scanA_k<<<kN / 1024, 1024, 0, stream>>>(cnt_n, start_n, bsum);
    scanB_k<<<1, 64, 0, stream>>>(bsum);
    scanC_k<<<kN / 1024, 1024, 0, stream>>>(start_n, bsum);
    fill_n_k<<<kE / 256, 256, 0, stream>>>(ei, start_n, fill_n, perm);

    embed_k<<<kN / 4, 256, 0, stream>>>(x, W_emb, b_emb, vn0, (u32*)hvbf);
    vninit_k<<<kG, 320, 0, stream>>>(vn0, vnA);

    for (int l = 0; l < kL; l++) {
        float* vcur = vnb[l & 1];
        float* vnxt = vnb[(l + 1) & 1];
        gather_combine_k<<<kN / 4, 256, 0, stream>>>(
            (const u32*)hvbf, start_n, perm, eps, l, (u32*)hv, stats);
        if (l < kL - 1) {
            vt_fin_k<<<kG / 4, 256, 0, stream>>>(
                (const u32*)hvbf, vcur, counts, starts, (u32*)vt_in);
            gemm_k<1, 1, 0><<<dim3(16, NP_H2 / 128), 256, 0, stream>>>(
                vt_in, Wt_v1 + (size_t)l * NP_H2 * KP_H, vn_b1 + l * kH2,
                z1v, nullptr, KP_H, kH2, KP_H2, KP_H2);
            gemm64_k<0, 2, 0><<<dim3(16, NP_H / 64), 256, 0, stream>>>(
                z1v, Wt_v2 + (size_t)l * NP_H * KP_H2, vn_b2 + l * kH,
                vnxt, nullptr, vcur, KP_H2, kH, kH, kH);
        }
        // fused node MLP v3.2 (round-7 verified): hv -> hv (in-place), z1 never leaves LDS
        fused_mlp_k<<<kN / 64, 256, 0, stream>>>(
            hv, W1f + (size_t)l * WFRAG_PER_L, gin_b1 + l * kH2,
            W2f + (size_t)l * WFRAG_PER_L, gin_b2 + l * kH,
            hv, stats);
        if (l < kL - 1)
            resid_k<1><<<kN / 4, 256, 0, stream>>>(
                (u32*)hvbf, (const u32*)hv, stats, bn_scale, bn_bias, l, batch, vcur, vnxt);
        else
            resid_k<0><<<kN / 4, 256, 0, stream>>>(
                (u32*)hvbf, (const u32*)hv, stats, bn_scale, bn_bias, l, batch, vcur, vcur);
    }

    float* vnlast = vnb[(kL - 1) & 1];
    pooled_k<<<kG / 4, 256, 0, stream>>>(
        (const u32*)hvbf, vnlast, counts, starts, (u32*)hrep);
    {
        long tr = (long)kG * (KP_DG - kH);
        hrep_rest_k<<<dim3((unsigned)((tr + 255) / 256)), 256, 0, stream>>>(morgan, maccs, counts, hrep);
    }
    gemm_k<1, 1, 0><<<dim3(16, NP_H2 / 128), 256, 0, stream>>>(
        hrep, Wt_p1, bp1, zp, nullptr, KP_DG, kH2, KP_H2, KP_H2);
    final_k<<<kG / 4, 256, 0, stream>>>(zp, Wp2, bp2, out);
}

// Round 12
// 1181.657 us; speedup vs baseline: 1.8610x; 1.0657x over previous
//
#include <hip/hip_runtime.h>

typedef unsigned short u16;
typedef unsigned int u32;
typedef __attribute__((ext_vector_type(8))) short bf16x8_t;
typedef __attribute__((ext_vector_type(4))) float f32x4_t;

// problem constants
#define kN 65536
#define kE 262144
#define kG 2048
#define kH 300
#define kH2 600
#define kL 5
#define kF 32
#define kDG 1523
// padded dims
#define KP_H 320     // K pad of H
#define KP_H2 640    // K pad of 2H
#define KP_DG 1536   // K pad of DG
#define NP_H2 640    // N pad of 2H (128-tiled)
#define NP_H 320     // N pad of H (64-tiled)
// hvbf row stride (u16 / u32)
#define HVS 320
#define HVS32 160
// fragment-packed weight size per layer: 5*4*2*10*64*8 == 5*4*5*4*64*8 == 204800 u16
#define WFRAG_PER_L 204800

__device__ __forceinline__ float bf2f(u16 x) {
    union { u32 u; float f; } v; v.u = ((u32)x) << 16; return v.f;
}
__device__ __forceinline__ u16 f2bf(float f) {
    union { float f; u32 u; } v; v.f = f;
    u32 u = v.u;
    u32 r = (u + 0x7fffu + ((u >> 16) & 1u)) >> 16;  // RNE
    return (u16)r;
}
__device__ __forceinline__ float blo(u32 v) { return bf2f((u16)(v & 0xffffu)); }
__device__ __forceinline__ float bhi(u32 v) { return bf2f((u16)(v >> 16)); }
__device__ __forceinline__ u32 pack2(float lo, float hi) {
    return (u32)f2bf(lo) | ((u32)f2bf(hi) << 16);
}

// async 16B global -> LDS
__device__ __forceinline__ void gld16(const u16* g, u16* l) {
    __builtin_amdgcn_global_load_lds(
        (const __attribute__((address_space(1))) u32*)g,
        (__attribute__((address_space(3))) u32*)l, 16, 0, 0);
}

// counted vmcnt waits + raw barrier
__device__ __forceinline__ void vwait6() { asm volatile("s_waitcnt vmcnt(6)" ::: "memory"); }
__device__ __forceinline__ void vwait8() { asm volatile("s_waitcnt vmcnt(8)" ::: "memory"); }
__device__ __forceinline__ void vwait0() { asm volatile("s_waitcnt vmcnt(0)" ::: "memory"); }
__device__ __forceinline__ void lwait0() { asm volatile("s_waitcnt lgkmcnt(0)" ::: "memory"); }
__device__ __forceinline__ void rbar() {
    __builtin_amdgcn_sched_barrier(0);
    __builtin_amdgcn_s_barrier();
    __builtin_amdgcn_sched_barrier(0);
}

// XCD-bijective tile swizzle (requires gridDim.x % 8 == 0; holds: 16).
__device__ __forceinline__ void swz_tile(int& m, int& n) {
    int p = blockIdx.x + gridDim.x * blockIdx.y;
    int xcd = p & 7;
    int q = p >> 3;
    int NB = gridDim.y;
    int mb8 = gridDim.x >> 3;
    m = xcd * mb8 + q / NB;
    n = q % NB;
}

// ---------------- weight transpose: W[b][k][n] (f32) -> Wt[b][n][k] (bf16), zero-padded ----------------
__global__ void transpose_k(const float* __restrict__ W, u16* __restrict__ Wt,
                            int K, int NN, int NP, int KP, long total) {
    long idx = (long)blockIdx.x * 256 + threadIdx.x;
    if (idx >= total) return;
    int per = NP * KP;
    int b = (int)(idx / per);
    int r = (int)(idx % per);
    int n = r / KP;
    int k = r % KP;
    u16 v = 0;
    if (n < NN && k < K) v = f2bf(W[(long)b * K * NN + (long)k * NN + n]);
    Wt[idx] = v;
}

// ---------------- fragment-pack W1 (gin_W1 [L][300][600]) -> W1f [L][c][w][nt][tk][lane][8] ----------------
__global__ void pack_w1_k(const float* __restrict__ W, u16* __restrict__ Wf, long total) {
    long idx = (long)blockIdx.x * 256 + threadIdx.x;
    if (idx >= total) return;
    int l = (int)(idx / WFRAG_PER_L);
    long r = idx % WFRAG_PER_L;
    int e = (int)(r & 7);
    long r1 = r >> 3;
    int ln = (int)(r1 & 63);
    int l16 = ln & 15, quad = ln >> 4;
    long s = r1 >> 6;
    int tk = (int)(s % 10);
    long s2 = s / 10;
    int nt = (int)(s2 & 1);
    long s3 = s2 >> 1;
    int w = (int)(s3 & 3);
    int c = (int)(s3 >> 2);
    int n = c * 128 + w * 32 + nt * 16 + l16;
    int k = tk * 32 + quad * 8 + e;
    u16 v = 0;
    if (n < kH2 && k < kH) v = f2bf(W[(long)l * kH * kH2 + (long)k * kH2 + n]);
    Wf[idx] = v;
}

// ---------------- fragment-pack W2 (gin_W2 [L][600][300]) -> W2f [L][c][w][nt][ks][lane][8] ----------------
__global__ void pack_w2_k(const float* __restrict__ W, u16* __restrict__ Wf, long total) {
    long idx = (long)blockIdx.x * 256 + threadIdx.x;
    if (idx >= total) return;
    int l = (int)(idx / WFRAG_PER_L);
    long r = idx % WFRAG_PER_L;
    int e = (int)(r & 7);
    long r1 = r >> 3;
    int ln = (int)(r1 & 63);
    int l16 = ln & 15, quad = ln >> 4;
    long s = r1 >> 6;
    int ks = (int)(s & 3);
    long s2 = s >> 2;
    int nt = (int)(s2 % 5);
    long s3 = s2 / 5;
    int w = (int)(s3 & 3);
    int c = (int)(s3 >> 2);
    int n = w * 80 + nt * 16 + l16;
    int k = c * 128 + ks * 32 + quad * 8 + e;
    u16 v = 0;
    if (n < kH && k < kH2) v = f2bf(W[(long)l * kH2 * kH + (long)k * kH + n]);
    Wf[idx] = v;
}

// ---------------- graph histogram + scan ----------------
__global__ void hist_g_k(const int* __restrict__ batch, int* __restrict__ counts) {
    int n = blockIdx.x * 256 + threadIdx.x;
    if (n < kN) atomicAdd(&counts[batch[n]], 1);
}

__global__ void scan_g_k(const int* __restrict__ counts, int* __restrict__ starts) {
    __shared__ int s[1024];
    int t = threadIdx.x;
    int c0 = counts[2 * t], c1 = counts[2 * t + 1];
    s[t] = c0 + c1;
    __syncthreads();
    for (int off = 1; off < 1024; off <<= 1) {
        int v = (t >= off) ? s[t - off] : 0;
        __syncthreads();
        s[t] += v;
        __syncthreads();
    }
    int excl = (t > 0) ? s[t - 1] : 0;
    starts[2 * t] = excl;
    starts[2 * t + 1] = excl + c0;
}

// ---------------- node CSR build ----------------
__global__ void hist_n_k(const int* __restrict__ ei, int* __restrict__ cnt) {
    int e = blockIdx.x * 256 + threadIdx.x;
    if (e < kE) atomicAdd(&cnt[ei[kE + e]], 1);
}

__global__ void scanA_k(const int* __restrict__ cnt, int* __restrict__ start, int* __restrict__ bsum) {
    __shared__ int s[1024];
    int b = blockIdx.x, t = threadIdx.x;
    int v = cnt[b * 1024 + t];
    s[t] = v;
    __syncthreads();
    for (int off = 1; off < 1024; off <<= 1) {
        int u = (t >= off) ? s[t - off] : 0;
        __syncthreads();
        s[t] += u;
        __syncthreads();
    }
    start[b * 1024 + t] = s[t] - v;
    if (t == 1023) bsum[b] = s[1023];
}

__global__ void scanB_k(int* __restrict__ bsum) {
    if (threadIdx.x == 0) {
        int s = 0;
        for (int i = 0; i < kN / 1024; i++) { s += bsum[i]; bsum[i] = s; }
    }
}

__global__ void scanC_k(int* __restrict__ start, const int* __restrict__ bsum) {
    int b = blockIdx.x, t = threadIdx.x;
    int add = (b > 0) ? bsum[b - 1] : 0;
    start[b * 1024 + t] += add;
    if (b == kN / 1024 - 1 && t == 1023) start[kN] = bsum[kN / 1024 - 1];
}

__global__ void fill_n_k(const int* __restrict__ ei, const int* __restrict__ start,
                         int* __restrict__ fill, int* __restrict__ perm) {
    int e = blockIdx.x * 256 + threadIdx.x;
    if (e >= kE) return;
    int s = ei[e], d = ei[kE + e];
    int pos = start[d] + atomicAdd(&fill[d], 1);
    perm[pos] = s;
}

// ---------------- node embedding: hvbf = bf16(x@W+b + vn0) ----------------
__global__ __launch_bounds__(256) void embed_k(
    const float* __restrict__ x, const float* __restrict__ W,
    const float* __restrict__ b, const float* __restrict__ vn0,
    u32* __restrict__ hv32) {
    __shared__ float sW[9 * kH];
    __shared__ float sBV[kH];
    int tid = threadIdx.x;
    for (int i = tid; i < 9 * kH; i += 256) sW[i] = W[i];
    for (int i = tid; i < kH; i += 256) sBV[i] = b[i] + vn0[i];
    __syncthreads();
    int wave = tid >> 6, lane = tid & 63;
    int n = blockIdx.x * 4 + wave;
    float xv[9];
    #pragma unroll
    for (int d = 0; d < 9; d++) xv[d] = x[n * 9 + d];
    #pragma unroll
    for (int p = 0; p < 3; p++) {
        int ii = lane + p * 64;
        if (ii < 150) {
            int c0 = 2 * ii;
            float a0 = sBV[c0], a1 = sBV[c0 + 1];
            #pragma unroll
            for (int d = 0; d < 9; d++) {
                a0 += xv[d] * sW[d * kH + c0];
                a1 += xv[d] * sW[d * kH + c0 + 1];
            }
            hv32[(long)n * HVS32 + ii] = pack2(a0, a1);
        } else if (ii < HVS32) {
            hv32[(long)n * HVS32 + ii] = 0u;
        }
    }
}

__global__ void vninit_k(const float* __restrict__ vn0, float* __restrict__ vn) {
    int g = blockIdx.x, c = threadIdx.x;
    if (c < kH) vn[g * kH + c] = vn0[c];
}

// ---------------- gather + combine ----------------
__global__ __launch_bounds__(256) void gather_combine_k(
    const u32* __restrict__ hv32, const int* __restrict__ start_n,
    const int* __restrict__ perm, const float* __restrict__ eps, int l,
    u32* __restrict__ out32, float* __restrict__ stats) {
    int tid = threadIdx.x;
    int wave = tid >> 6, lane = tid & 63;
    int n = blockIdx.x * 4 + wave;
    int st = start_n[n], en = start_n[n + 1];
    int i0 = lane, i1 = lane + 64, i2 = lane + 128;
    bool p2 = (i2 < 150);
    float a0 = 0.f, b0 = 0.f, a1 = 0.f, b1 = 0.f, a2 = 0.f, b2 = 0.f;
    int e = st;
    for (; e + 4 <= en; e += 4) {
        const u32* rA = hv32 + (long)perm[e] * HVS32;
        const u32* rB = hv32 + (long)perm[e + 1] * HVS32;
        const u32* rC = hv32 + (long)perm[e + 2] * HVS32;
        const u32* rD = hv32 + (long)perm[e + 3] * HVS32;
        u32 vA0 = rA[i0], vA1 = rA[i1], vA2 = p2 ? rA[i2] : 0u;
        u32 vB0 = rB[i0], vB1 = rB[i1], vB2 = p2 ? rB[i2] : 0u;
        u32 vC0 = rC[i0], vC1 = rC[i1], vC2 = p2 ? rC[i2] : 0u;
        u32 vD0 = rD[i0], vD1 = rD[i1], vD2 = p2 ? rD[i2] : 0u;
        a0 += (blo(vA0) + blo(vB0)) + (blo(vC0) + blo(vD0));
        b0 += (bhi(vA0) + bhi(vB0)) + (bhi(vC0) + bhi(vD0));
        a1 += (blo(vA1) + blo(vB1)) + (blo(vC1) + blo(vD1));
        b1 += (bhi(vA1) + bhi(vB1)) + (bhi(vC1) + bhi(vD1));
        a2 += (blo(vA2) + blo(vB2)) + (blo(vC2) + blo(vD2));
        b2 += (bhi(vA2) + bhi(vB2)) + (bhi(vC2) + bhi(vD2));
    }
    for (; e + 2 <= en; e += 2) {
        const u32* rA = hv32 + (long)perm[e] * HVS32;
        const u32* rB = hv32 + (long)perm[e + 1] * HVS32;
        u32 vA0 = rA[i0], vA1 = rA[i1], vA2 = p2 ? rA[i2] : 0u;
        u32 vB0 = rB[i0], vB1 = rB[i1], vB2 = p2 ? rB[i2] : 0u;
        a0 += blo(vA0) + blo(vB0); b0 += bhi(vA0) + bhi(vB0);
        a1 += blo(vA1) + blo(vB1); b1 += bhi(vA1) + bhi(vB1);
        a2 += blo(vA2) + blo(vB2); b2 += bhi(vA2) + bhi(vB2);
    }
    if (e < en) {
        const u32* rA = hv32 + (long)perm[e] * HVS32;
        u32 vA0 = rA[i0], vA1 = rA[i1], vA2 = p2 ? rA[i2] : 0u;
        a0 += blo(vA0); b0 += bhi(vA0);
        a1 += blo(vA1); b1 += bhi(vA1);
        a2 += blo(vA2); b2 += bhi(vA2);
    }
    const u32* self = hv32 + (long)n * HVS32;
    float ep = 1.f + eps[l];
    u32 s0 = self[i0], s1 = self[i1];
    u32* o = out32 + (long)n * HVS32;
    o[i0] = pack2(ep * blo(s0) + a0, ep * bhi(s0) + b0);
    o[i1] = pack2(ep * blo(s1) + a1, ep * bhi(s1) + b1);
    if (p2) {
        u32 s2 = self[i2];
        o[i2] = pack2(ep * blo(s2) + a2, ep * bhi(s2) + b2);
    } else if (i2 < HVS32) {
        o[i2] = 0u;
    }
    int gz = blockIdx.x * 256 + tid;
    if (gz < 2 * kH) stats[gz] = 0.f;
}

// ---------------- vt (wave per graph): vt[g] = sum_rows hvbf + vn_cur[g] ----------------
__global__ __launch_bounds__(256) void vt_fin_k(
    const u32* __restrict__ hv32, const float* __restrict__ vncur,
    const int* __restrict__ counts, const int* __restrict__ starts,
    u32* __restrict__ vt32) {
    int tid = threadIdx.x, wave = tid >> 6, lane = tid & 63;
    int g = blockIdx.x * 4 + wave;
    int cnt = counts[g], st = starts[g];
    int i0 = lane, i1 = lane + 64, i2 = lane + 128;
    bool p2 = (i2 < 150);
    float a0 = 0.f, b0 = 0.f, a1 = 0.f, b1 = 0.f, a2 = 0.f, b2 = 0.f;
    int i = 0;
    for (; i + 4 <= cnt; i += 4) {
        const u32* rA = hv32 + (long)(st + i) * HVS32;
        const u32* rB = hv32 + (long)(st + i + 1) * HVS32;
        const u32* rC = hv32 + (long)(st + i + 2) * HVS32;
        const u32* rD = hv32 + (long)(st + i + 3) * HVS32;
        u32 vA0 = rA[i0], vA1 = rA[i1], vA2 = p2 ? rA[i2] : 0u;
        u32 vB0 = rB[i0], vB1 = rB[i1], vB2 = p2 ? rB[i2] : 0u;
        u32 vC0 = rC[i0], vC1 = rC[i1], vC2 = p2 ? rC[i2] : 0u;
        u32 vD0 = rD[i0], vD1 = rD[i1], vD2 = p2 ? rD[i2] : 0u;
        a0 += (blo(vA0) + blo(vB0)) + (blo(vC0) + blo(vD0));
        b0 += (bhi(vA0) + bhi(vB0)) + (bhi(vC0) + bhi(vD0));
        a1 += (blo(vA1) + blo(vB1)) + (blo(vC1) + blo(vD1));
        b1 += (bhi(vA1) + bhi(vB1)) + (bhi(vC1) + bhi(vD1));
        a2 += (blo(vA2) + blo(vB2)) + (blo(vC2) + blo(vD2));
        b2 += (bhi(vA2) + bhi(vB2)) + (bhi(vC2) + bhi(vD2));
    }
    for (; i < cnt; i++) {
        const u32* rA = hv32 + (long)(st + i) * HVS32;
        u32 vA0 = rA[i0], vA1 = rA[i1], vA2 = p2 ? rA[i2] : 0u;
        a0 += blo(vA0); b0 += bhi(vA0);
        a1 += blo(vA1); b1 += bhi(vA1);
        a2 += blo(vA2); b2 += bhi(vA2);
    }
    const float* vg = vncur + g * kH;
    vt32[(long)g * HVS32 + i0] = pack2(a0 + vg[2 * i0], b0 + vg[2 * i0 + 1]);
    vt32[(long)g * HVS32 + i1] = pack2(a1 + vg[2 * i1], b1 + vg[2 * i1 + 1]);
    if (p2) vt32[(long)g * HVS32 + i2] = pack2(a2 + vg[2 * i2], b2 + vg[2 * i2 + 1]);
    else if (i2 < HVS32) vt32[(long)g * HVS32 + i2] = 0u;
}

// ---------------- FUSED node MLP v6: r7 structure + double-buffered z1c (1 barrier/chunk) ----------------
// 256 thr / 64-row strip, 2 blocks/CU. A strip persisted in LDS; W1/W2 fragment-packed in
// global (coalesced lane*16B loads); z1 handoff via z1c[2] (32 KB) so the leading
// "readers done" barrier per chunk is deleted: chunk c+1's write to buf[(c+1)&1] is
// separated from phase-B(c-1)'s reads of that buffer by chunk c's barrier in program order.
// LDS = 40 + 32 + 2.5 = 74.5 KB -> still 2 blocks/CU (149 < 160 KB).
__global__ __launch_bounds__(256, 2) void fused_mlp_k(
    const u16* __restrict__ A,      // hv [kN x 320] bf16
    const u16* __restrict__ W1f,    // fragment-packed [5][4][2][10][64][8]
    const float* __restrict__ b1,   // [600]
    const u16* __restrict__ W2f,    // fragment-packed [5][4][5][4][64][8]
    const float* __restrict__ b2,   // [300]
    u16* __restrict__ outp,         // hv (in-place)
    float* __restrict__ stats) {
    __shared__ __align__(16) u16 lA[5][64 * 64];    // 40 KB persistent A strip
    __shared__ __align__(16) u16 z1c[2][64 * 128];  // 32 KB z1 chunk dbuf, XOR swizzle
    __shared__ float sred[320][2];                  // 2.5 KB BN partial sums

    const int tid = threadIdx.x;
    const int lane = tid & 63;
    const int wave = tid >> 6;      // 0..3
    const int l16 = lane & 15;
    const int quad = lane >> 4;
    const long tm = (long)blockIdx.x * 64;
    const int srow = lane >> 3;
    const int sch = (lane & 7) ^ srow;

    for (int i = tid; i < 320; i += 256) { sred[i][0] = 0.f; sred[i][1] = 0.f; }

    // stage the whole A strip once (5 k-tiles x 64 rows)
    #pragma unroll
    for (int t = 0; t < 5; t++) {
        #pragma unroll
        for (int j = 0; j < 2; j++) {
            int rb = wave * 16 + j * 8;
            gld16(A + (tm + rb + srow) * KP_H + t * 64 + sch * 8, &lA[t][rb * 64]);
        }
    }

    // preload biases (compile-time indexed after full unroll)
    float rb1[5][2];
    #pragma unroll
    for (int c = 0; c < 5; c++)
        #pragma unroll
        for (int nt = 0; nt < 2; nt++) {
            int gc = c * 128 + wave * 32 + nt * 16 + l16;
            rb1[c][nt] = (gc < kH2) ? b1[gc] : 0.f;
        }
    float rb2[5];
    #pragma unroll
    for (int nt = 0; nt < 5; nt++) {
        int col = wave * 80 + nt * 16 + l16;
        rb2[nt] = (col < kH) ? b2[col] : 0.f;
    }

    f32x4_t acc2[4][5];
    #pragma unroll
    for (int i = 0; i < 4; i++)
        #pragma unroll
        for (int j = 0; j < 5; j++) acc2[i][j] = (f32x4_t){0.f, 0.f, 0.f, 0.f};

    vwait0();
    rbar();  // A strip staged; sred zeroed

    #pragma unroll
    for (int c = 0; c < 5; c++) {
        // ---------- phase A (barrier-free): z1 chunk = A @ W1 chunk ----------
        f32x4_t acc1[4][2];
        #pragma unroll
        for (int i = 0; i < 4; i++) {
            acc1[i][0] = (f32x4_t){0.f, 0.f, 0.f, 0.f};
            acc1[i][1] = (f32x4_t){0.f, 0.f, 0.f, 0.f};
        }
        // fragment base for (c, wave): [((c*4+w)*2+nt)*10 + tk] frames of 512 u16
        const u16* w1p = W1f + ((long)((c * 4 + wave) * 2) * 10) * 512 + lane * 8;
        bf16x8_t wf[4][2];
        #pragma unroll
        for (int p = 0; p < 3; p++) {   // preload tk=0..2 (distance-3 rotation)
            wf[p][0] = *(const bf16x8_t*)(w1p + p * 512);
            wf[p][1] = *(const bf16x8_t*)(w1p + 10 * 512 + p * 512);
        }
        #pragma unroll
        for (int tk = 0; tk < 10; tk++) {
            if (tk + 3 < 10) {          // prefetch tk+3 into slot (tk+3)&3 != tk&3
                wf[(tk + 3) & 3][0] = *(const bf16x8_t*)(w1p + (tk + 3) * 512);
                wf[(tk + 3) & 3][1] = *(const bf16x8_t*)(w1p + 10 * 512 + (tk + 3) * 512);
            }
            const int t = tk >> 1, ks = tk & 1;
            bf16x8_t af[4];
            #pragma unroll
            for (int mt = 0; mt < 4; mt++) {
                int row = mt * 16 + l16;
                int phys = (ks * 4 + quad) ^ (l16 & 7);
                af[mt] = *(const bf16x8_t*)&lA[t][row * 64 + phys * 8];
            }
            #pragma unroll
            for (int mt = 0; mt < 4; mt++) {
                acc1[mt][0] = __builtin_amdgcn_mfma_f32_16x16x32_bf16(af[mt], wf[tk & 3][0], acc1[mt][0], 0, 0, 0);
                acc1[mt][1] = __builtin_amdgcn_mfma_f32_16x16x32_bf16(af[mt], wf[tk & 3][1], acc1[mt][1], 0, 0, 0);
            }
        }

        // ---------- z1c handoff into buf[c&1] (no leading barrier needed: dbuf) ----------
        u16* zb = z1c[c & 1];
        #pragma unroll
        for (int nt = 0; nt < 2; nt++) {
            int col = wave * 32 + nt * 16 + l16;
            #pragma unroll
            for (int mt = 0; mt < 4; mt++) {
                #pragma unroll
                for (int r = 0; r < 4; r++) {
                    int row = mt * 16 + quad * 4 + r;
                    float v = fmaxf(acc1[mt][nt][r] + rb1[c][nt], 0.f);
                    int phys = (col >> 3) ^ (row & 15);
                    zb[row * 128 + phys * 8 + (col & 7)] = f2bf(v);
                }
            }
        }
        lwait0();
        rbar();  // z1c[c&1] visible to all waves (also orders next chunk's writes)

        // ---------- phase B (barrier-free): acc2 += z1c[c&1] @ W2 chunk ----------
        const u16* w2p = W2f + ((long)((c * 4 + wave) * 5) * 4) * 512 + lane * 8;
        bf16x8_t wg[2][5];
        #pragma unroll
        for (int nt = 0; nt < 5; nt++)
            wg[0][nt] = *(const bf16x8_t*)(w2p + nt * 4 * 512);
        #pragma unroll
        for (int ks = 0; ks < 4; ks++) {
            if (ks + 1 < 4) {
                #pragma unroll
                for (int nt = 0; nt < 5; nt++)
                    wg[(ks + 1) & 1][nt] = *(const bf16x8_t*)(w2p + nt * 4 * 512 + (ks + 1) * 512);
            }
            bf16x8_t af[4];
            #pragma unroll
            for (int mt = 0; mt < 4; mt++) {
                int row = mt * 16 + l16;
                int phys = (ks * 4 + quad) ^ (row & 15);
                af[mt] = *(const bf16x8_t*)&zb[row * 128 + phys * 8];
            }
            #pragma unroll
            for (int mt = 0; mt < 4; mt++)
                #pragma unroll
                for (int nt = 0; nt < 5; nt++)
                    acc2[mt][nt] = __builtin_amdgcn_mfma_f32_16x16x32_bf16(af[mt], wg[ks & 1][nt], acc2[mt][nt], 0, 0, 0);
        }
    }

    // ---------- epilogue: bias, bf16 store (in-place), BN stats ----------
    #pragma unroll
    for (int nt = 0; nt < 5; nt++) {
        int col = wave * 80 + nt * 16 + l16;
        float s = 0.f, s2 = 0.f;
        #pragma unroll
        for (int mt = 0; mt < 4; mt++) {
            #pragma unroll
            for (int r = 0; r < 4; r++) {
                long row = tm + mt * 16 + quad * 4 + r;
                float v = acc2[mt][nt][r] + rb2[nt];
                float sv = (col < kH) ? v : 0.f;
                outp[row * KP_H + col] = f2bf(sv);
                s += sv; s2 += sv * sv;
            }
        }
        atomicAdd(&sred[col][0], s);
        atomicAdd(&sred[col][1], s2);
    }
    __syncthreads();
    for (int i = tid; i < kH; i += 256) {
        atomicAdd(&stats[i], sred[i][0]);
        atomicAdd(&stats[kH + i], sred[i][1]);
    }
}

// ---------------- GEMM: 128x128 tile, BK=64, counted-vmcnt double-buffered pipeline ----------------
template<int ACT, int OUT_BF16, int BN_STATS>
__global__ __launch_bounds__(256) void gemm_k(
    const u16* __restrict__ A, const u16* __restrict__ Wt,
    const float* __restrict__ bias, void* __restrict__ out,
    float* __restrict__ stats,
    int KP, int NN, int out_stride, int store_cols) {
    __shared__ __align__(16) u16 lA[2][128 * 64];
    __shared__ __align__(16) u16 lB[2][128 * 64];
    __shared__ float sred[128][2];

    const int tid = threadIdx.x;
    const int lane = tid & 63;
    const int wave = tid >> 6;
    const int l16 = lane & 15;
    const int quad = lane >> 4;
    const int wm = (wave & 1) * 64;
    const int wn = (wave >> 1) * 64;
    int sm, sn;
    swz_tile(sm, sn);
    const long tm = (long)sm * 128;
    const int tn = sn * 128;

    const int srow = lane >> 3;
    const int sch = (lane & 7) ^ srow;

    f32x4_t acc[4][4];
    #pragma unroll
    for (int i = 0; i < 4; i++)
        #pragma unroll
        for (int j = 0; j < 4; j++) acc[i][j] = (f32x4_t){0.f, 0.f, 0.f, 0.f};

    auto stage = [&](int bb, int k0) {  // 8 VMEM per wave
        #pragma unroll
        for (int j = 0; j < 4; j++) {
            int rb = wave * 32 + j * 8;
            int r = rb + srow;
            gld16(A + (tm + r) * KP + k0 + sch * 8, &lA[bb][rb * 64]);
            gld16(Wt + (long)(tn + r) * KP + k0 + sch * 8, &lB[bb][rb * 64]);
        }
    };

    const int nk = KP >> 6;
    stage(0, 0);
    if (nk > 1) stage(1, 64);
    for (int t = 0; t < nk; t++) {
        if (t < nk - 1) vwait8(); else vwait0();
        rbar();
        const u16* la = lA[t & 1];
        const u16* lb = lB[t & 1];
        #pragma unroll
        for (int ks = 0; ks < 2; ks++) {
            bf16x8_t af[4], bfr[4];
            #pragma unroll
            for (int mt = 0; mt < 4; mt++) {
                int row = wm + mt * 16 + l16;
                int phys = (ks * 4 + quad) ^ (l16 & 7);
                af[mt] = *(const bf16x8_t*)&la[row * 64 + phys * 8];
            }
            #pragma unroll
            for (int nt = 0; nt < 4; nt++) {
                int row = wn + nt * 16 + l16;
                int phys = (ks * 4 + quad) ^ (l16 & 7);
                bfr[nt] = *(const bf16x8_t*)&lb[row * 64 + phys * 8];
            }
            #pragma unroll
            for (int mt = 0; mt < 4; mt++)
                #pragma unroll
                for (int nt = 0; nt < 4; nt++)
                    acc[mt][nt] = __builtin_amdgcn_mfma_f32_16x16x32_bf16(af[mt], bfr[nt], acc[mt][nt], 0, 0, 0);
        }
        rbar();
        if (t + 2 < nk) stage(t & 1, (t + 2) * 64);
    }

    if (BN_STATS) {
        if (tid < 128) { sred[tid][0] = 0.f; sred[tid][1] = 0.f; }
    }
    __syncthreads();

    #pragma unroll
    for (int nt = 0; nt < 4; nt++) {
        int col = tn + wn + nt * 16 + l16;
        float bv = (col < NN) ? bias[col] : 0.f;
        float s = 0.f, s2 = 0.f;
        #pragma unroll
        for (int mt = 0; mt < 4; mt++) {
            #pragma unroll
            for (int r = 0; r < 4; r++) {
                long row = tm + wm + mt * 16 + quad * 4 + r;
                float v = acc[mt][nt][r] + bv;
                if (ACT) v = fmaxf(v, 0.f);
                float sv = (col < NN) ? v : 0.f;
                if (col < store_cols) {
                    if (OUT_BF16) ((u16*)out)[row * out_stride + col] = f2bf(sv);
                    else          ((float*)out)[row * out_stride + col] = sv;
                }
                s += sv; s2 += sv * sv;
            }
        }
        if (BN_STATS) {
            atomicAdd(&sred[wn + nt * 16 + l16][0], s);
            atomicAdd(&sred[wn + nt * 16 + l16][1], s2);
        }
    }
    if (BN_STATS) {
        __syncthreads();
        if (tid < 128) {
            int col = tn + tid;
            if (col < NN) {
                atomicAdd(&stats[col], sred[tid][0]);
                atomicAdd(&stats[NN + col], sred[tid][1]);
            }
        }
    }
}

// ---------------- GEMM64: 128x64 tile; OUT_MODE: 0=f32, 1=bf16, 2=vn_nxt = vn_cur + relu(v) ----------------
template<int ACT, int OUT_MODE, int BN_STATS>
__global__ __launch_bounds__(256) void gemm64_k(
    const u16* __restrict__ A, const u16* __restrict__ Wt,
    const float* __restrict__ bias, void* __restrict__ out,
    float* __restrict__ stats, const float* __restrict__ vnacc,
    int KP, int NN, int out_stride, int store_cols) {
    __shared__ __align__(16) u16 lA[2][128 * 64];
    __shared__ __align__(16) u16 lB[2][64 * 64];
    __shared__ float sred[64][2];

    const int tid = threadIdx.x;
    const int lane = tid & 63;
    const int wave = tid >> 6;
    const int l16 = lane & 15;
    const int quad = lane >> 4;
    const int wm = (wave & 1) * 64;
    const int wn = (wave >> 1) * 32;
    int sm, sn;
    swz_tile(sm, sn);
    const long tm = (long)sm * 128;
    const int tn = sn * 64;

    const int srow = lane >> 3;
    const int sch = (lane & 7) ^ srow;

    f32x4_t acc[4][2];
    #pragma unroll
    for (int i = 0; i < 4; i++)
        #pragma unroll
        for (int j = 0; j < 2; j++) acc[i][j] = (f32x4_t){0.f, 0.f, 0.f, 0.f};

    auto stage = [&](int bb, int k0) {  // 6 VMEM per wave
        #pragma unroll
        for (int j = 0; j < 4; j++) {
            int rb = wave * 32 + j * 8;
            gld16(A + (tm + rb + srow) * KP + k0 + sch * 8, &lA[bb][rb * 64]);
        }
        #pragma unroll
        for (int j = 0; j < 2; j++) {
            int rb = wave * 16 + j * 8;
            gld16(Wt + (long)(tn + rb + srow) * KP + k0 + sch * 8, &lB[bb][rb * 64]);
        }
    };

    const int nk = KP >> 6;
    stage(0, 0);
    if (nk > 1) stage(1, 64);
    for (int t = 0; t < nk; t++) {
        if (t < nk - 1) vwait6(); else vwait0();
        rbar();
        const u16* la = lA[t & 1];
        const u16* lb = lB[t & 1];
        #pragma unroll
        for (int ks = 0; ks < 2; ks++) {
            bf16x8_t af[4], bfr[2];
            #pragma unroll
            for (int mt = 0; mt < 4; mt++) {
                int row = wm + mt * 16 + l16;
                int phys = (ks * 4 + quad) ^ (l16 & 7);
                af[mt] = *(const bf16x8_t*)&la[row * 64 + phys * 8];
            }
            #pragma unroll
            for (int nt = 0; nt < 2; nt++) {
                int row = wn + nt * 16 + l16;
                int phys = (ks * 4 + quad) ^ (l16 & 7);
                bfr[nt] = *(const bf16x8_t*)&lb[row * 64 + phys * 8];
            }
            #pragma unroll
            for (int mt = 0; mt < 4; mt++)
                #pragma unroll
                for (int nt = 0; nt < 2; nt++)
                    acc[mt][nt] = __builtin_amdgcn_mfma_f32_16x16x32_bf16(af[mt], bfr[nt], acc[mt][nt], 0, 0, 0);
        }
        rbar();
        if (t + 2 < nk) stage(t & 1, (t + 2) * 64);
    }

    if (BN_STATS) {
        if (tid < 64) { sred[tid][0] = 0.f; sred[tid][1] = 0.f; }
    }
    __syncthreads();

    #pragma unroll
    for (int nt = 0; nt < 2; nt++) {
        int col = tn + wn + nt * 16 + l16;
        float bv = (col < NN) ? bias[col] : 0.f;
        float s = 0.f, s2 = 0.f;
        #pragma unroll
        for (int mt = 0; mt < 4; mt++) {
            #pragma unroll
            for (int r = 0; r < 4; r++) {
                long row = tm + wm + mt * 16 + quad * 4 + r;
                float v = acc[mt][nt][r] + bv;
                if (ACT) v = fmaxf(v, 0.f);
                float sv = (col < NN) ? v : 0.f;
                if (col < store_cols) {
                    if (OUT_MODE == 1) ((u16*)out)[row * out_stride + col] = f2bf(sv);
                    else if (OUT_MODE == 2)
                        ((float*)out)[row * out_stride + col] =
                            vnacc[row * out_stride + col] + fmaxf(v, 0.f);
                    else ((float*)out)[row * out_stride + col] = sv;
                }
                s += sv; s2 += sv * sv;
            }
        }
        if (BN_STATS) {
            atomicAdd(&sred[wn + nt * 16 + l16][0], s);
            atomicAdd(&sred[wn + nt * 16 + l16][1], s2);
        }
    }
    if (BN_STATS) {
        __syncthreads();
        if (tid < 64) {
            int col = tn + tid;
            if (col < NN) {
                atomicAdd(&stats[col], sred[tid][0]);
                atomicAdd(&stats[NN + col], sred[tid][1]);
            }
        }
    }
}

// ---------------- BN-apply + (relu) + residual ----------------
template<int RELU>
__global__ __launch_bounds__(256) void resid_k(
    u32* __restrict__ hvb32, const u32* __restrict__ z32,
    const float* __restrict__ stats,
    const float* __restrict__ scale, const float* __restrict__ bias, int l,
    const int* __restrict__ batch,
    const float* __restrict__ vncur, const float* __restrict__ vnnxt) {
    int tid = threadIdx.x;
    int wave = tid >> 6, lane = tid & 63;
    int n = blockIdx.x * 4 + wave;
    int g = batch[n];
    #pragma unroll
    for (int p = 0; p < 3; p++) {
        int ii = lane + p * 64;
        if (ii >= 150) break;
        int c0 = 2 * ii;
        float m0 = stats[c0] * (1.f / (float)kN), m1 = stats[c0 + 1] * (1.f / (float)kN);
        float v0 = fmaxf(stats[kH + c0] * (1.f / (float)kN) - m0 * m0, 0.f);
        float v1 = fmaxf(stats[kH + c0 + 1] * (1.f / (float)kN) - m1 * m1, 0.f);
        float a0 = scale[l * kH + c0] * rsqrtf(v0 + 1e-5f);
        float a1 = scale[l * kH + c0 + 1] * rsqrtf(v1 + 1e-5f);
        float d0 = bias[l * kH + c0] - m0 * a0;
        float d1 = bias[l * kH + c0 + 1] - m1 * a1;
        u32 zz = z32[(long)n * HVS32 + ii];
        u32 ho = hvb32[(long)n * HVS32 + ii];
        float2 vc = *(const float2*)(vncur + g * kH + c0);
        float2 vx = *(const float2*)(vnnxt + g * kH + c0);
        float t0 = blo(zz) * a0 + d0;
        float t1 = bhi(zz) * a1 + d1;
        if (RELU) { t0 = fmaxf(t0, 0.f); t1 = fmaxf(t1, 0.f); }
        float h0 = (blo(ho) - vc.x) + t0;
        float h1 = (bhi(ho) - vc.y) + t1;
        hvb32[(long)n * HVS32 + ii] = pack2(h0 + vx.x, h1 + vx.y);
    }
}

// ---------------- pooled mean (wave per graph) ----------------
__global__ __launch_bounds__(256) void pooled_k(
    const u32* __restrict__ hv32, const float* __restrict__ vnlast,
    const int* __restrict__ counts, const int* __restrict__ starts,
    u32* __restrict__ hrep32) {
    int tid = threadIdx.x, wave = tid >> 6, lane = tid & 63;
    int g = blockIdx.x * 4 + wave;
    int cnt = counts[g], st = starts[g];
    int i0 = lane, i1 = lane + 64, i2 = lane + 128;
    bool p2 = (i2 < 150);
    float a0 = 0.f, b0 = 0.f, a1 = 0.f, b1 = 0.f, a2 = 0.f, b2 = 0.f;
    int i = 0;
    for (; i + 4 <= cnt; i += 4) {
        const u32* rA = hv32 + (long)(st + i) * HVS32;
        const u32* rB = hv32 + (long)(st + i + 1) * HVS32;
        const u32* rC = hv32 + (long)(st + i + 2) * HVS32;
        const u32* rD = hv32 + (long)(st + i + 3) * HVS32;
        u32 vA0 = rA[i0], vA1 = rA[i1], vA2 = p2 ? rA[i2] : 0u;
        u32 vB0 = rB[i0], vB1 = rB[i1], vB2 = p2 ? rB[i2] : 0u;
        u32 vC0 = rC[i0], vC1 = rC[i1], vC2 = p2 ? rC[i2] : 0u;
        u32 vD0 = rD[i0], vD1 = rD[i1], vD2 = p2 ? rD[i2] : 0u;
        a0 += (blo(vA0) + blo(vB0)) + (blo(vC0) + blo(vD0));
        b0 += (bhi(vA0) + bhi(vB0)) + (bhi(vC0) + bhi(vD0));
        a1 += (blo(vA1) + blo(vB1)) + (blo(vC1) + blo(vD1));
        b1 += (bhi(vA1) + bhi(vB1)) + (bhi(vC1) + bhi(vD1));
        a2 += (blo(vA2) + blo(vB2)) + (blo(vC2) + blo(vD2));
        b2 += (bhi(vA2) + bhi(vB2)) + (bhi(vC2) + bhi(vD2));
    }
    for (; i < cnt; i++) {
        const u32* rA = hv32 + (long)(st + i) * HVS32;
        u32 vA0 = rA[i0], vA1 = rA[i1], vA2 = p2 ? rA[i2] : 0u;
        a0 += blo(vA0); b0 += bhi(vA0);
        a1 += blo(vA1); b1 += bhi(vA1);
        a2 += blo(vA2); b2 += bhi(vA2);
    }
    float fc = (float)cnt;
    float inv = 1.f / (float)(cnt > 0 ? cnt : 1);
    const float* vg = vnlast + g * kH;
    hrep32[(long)g * 768 + i0] = pack2((a0 - fc * vg[2 * i0]) * inv, (b0 - fc * vg[2 * i0 + 1]) * inv);
    hrep32[(long)g * 768 + i1] = pack2((a1 - fc * vg[2 * i1]) * inv, (b1 - fc * vg[2 * i1 + 1]) * inv);
    if (p2)
        hrep32[(long)g * 768 + i2] = pack2((a2 - fc * vg[2 * i2]) * inv, (b2 - fc * vg[2 * i2 + 1]) * inv);
}

// ---------------- h_rep cols [300,1536) ----------------
__global__ void hrep_rest_k(const float* __restrict__ morgan, const float* __restrict__ maccs,
                            const int* __restrict__ counts, u16* __restrict__ hrep) {
    long idx = (long)blockIdx.x * 256 + threadIdx.x;
    if (idx >= (long)kG * (KP_DG - kH)) return;
    int g = (int)(idx / (KP_DG - kH));
    int j = (int)(idx % (KP_DG - kH));
    int col = kH + j;
    u16 v;
    if (j < kF) {
        int c = counts[g];
        int q = (j < c) ? ((c - 1 - j) / kF + 1) : 0;
        v = f2bf((float)q / (float)(c > 0 ? c : 1));
    } else if (j < kF + 1024) {
        v = f2bf(morgan[(long)g * 1024 + (j - kF)]);
    } else if (j < kF + 1024 + 167) {
        v = f2bf(maccs[(long)g * 167 + (j - kF - 1024)]);
    } else {
        v = 0;
    }
    hrep[(long)g * KP_DG + col] = v;
}

// ---------------- final ----------------
__global__ void final_k(const u16* __restrict__ zp, const float* __restrict__ Wp2,
                        const float* __restrict__ bp2, float* __restrict__ out) {
    int wave = threadIdx.x >> 6, lane = threadIdx.x & 63;
    int g = blockIdx.x * 4 + wave;
    float acc = 0.f;
    for (int c = lane; c < kH2; c += 64) acc += bf2f(zp[(long)g * KP_H2 + c]) * Wp2[c];
    #pragma unroll
    for (int off = 32; off; off >>= 1) acc += __shfl_down(acc, off);
    if (lane == 0) out[g] = acc + bp2[0];
}

extern "C" void kernel_launch(void* const* d_in, const int* in_sizes, int n_in,
                              void* d_out, int out_size, void* d_ws, size_t ws_size,
                              hipStream_t stream) {
    const float* x      = (const float*)d_in[0];
    const float* morgan = (const float*)d_in[1];
    const float* maccs  = (const float*)d_in[2];
    const int*   ei     = (const int*)d_in[3];
    const int*   batch  = (const int*)d_in[4];
    const float* W_emb  = (const float*)d_in[5];
    const float* b_emb  = (const float*)d_in[6];
    const float* gin_W1 = (const float*)d_in[7];
    const float* gin_b1 = (const float*)d_in[8];
    const float* gin_W2 = (const float*)d_in[9];
    const float* gin_b2 = (const float*)d_in[10];
    const float* bn_scale = (const float*)d_in[11];
    const float* bn_bias  = (const float*)d_in[12];
    const float* eps    = (const float*)d_in[13];
    const float* vn0    = (const float*)d_in[14];
    const float* vn_W1  = (const float*)d_in[15];
    const float* vn_b1  = (const float*)d_in[16];
    const float* vn_W2  = (const float*)d_in[17];
    const float* vn_b2  = (const float*)d_in[18];
    const float* Wp1    = (const float*)d_in[19];
    const float* bp1    = (const float*)d_in[20];
    const float* Wp2    = (const float*)d_in[21];
    const float* bp2    = (const float*)d_in[22];
    float* out = (float*)d_out;

    char* ws = (char*)d_ws;
    size_t off = 0;
    auto alloc = [&](size_t bytes) -> char* {
        char* p = ws + off;
        off += (bytes + 255) & ~(size_t)255;
        return p;
    };
    u16*   hvbf = (u16*)alloc((size_t)kN * HVS * 2);        // 41.9 MB
    u16*   hv   = (u16*)alloc((size_t)kN * KP_H * 2);       // 41.9 MB
    u16*   z1   = (u16*)alloc((size_t)kN * KP_H2 * 2);      // 83.9 MB (vn/pred overlays)
    float* vnA  = (float*)alloc((size_t)kG * kH * 4);
    float* vnB  = (float*)alloc((size_t)kG * kH * 4);
    int* counts = (int*)alloc(kG * 4);
    int* starts = (int*)alloc(kG * 4);
    float* stats = (float*)alloc(2 * kH * 4);
    int* cnt_n  = (int*)alloc((size_t)kN * 4);
    int* start_n = (int*)alloc((size_t)(kN + 1) * 4);
    int* fill_n = (int*)alloc((size_t)kN * 4);
    int* bsum   = (int*)alloc((kN / 1024) * 4);
    int* perm   = (int*)alloc((size_t)kE * 4);
    u16* W1f   = (u16*)alloc((size_t)kL * WFRAG_PER_L * 2);   // 2.05 MB fragment-packed gin_W1
    u16* W2f   = (u16*)alloc((size_t)kL * WFRAG_PER_L * 2);   // 2.05 MB fragment-packed gin_W2
    u16* Wt_v1 = (u16*)alloc((size_t)(kL - 1) * NP_H2 * KP_H * 2);
    u16* Wt_v2 = (u16*)alloc((size_t)(kL - 1) * NP_H * KP_H2 * 2);
    u16* Wt_p1 = (u16*)alloc((size_t)NP_H2 * KP_DG * 2);
    if (off > ws_size) return;

    // z1-region overlays (disjoint lifetimes):
    u16* vt_in = z1;                                   // [2048,320] bf16 (pre vn-G1)
    u16* z1v   = z1 + (size_t)4 * 1024 * 1024;         // [2048,640] bf16 (pre vn-G1)
    u16* hrep  = z1;                                   // [2048,1536] bf16 (post layers)
    u16* zp    = z1 + (size_t)8 * 1024 * 1024;         // [2048,640] bf16 (post layers)
    float* vnb[2] = {vnA, vnB};

    // weight packing / transposes
    {
        long tf = (long)kL * WFRAG_PER_L;
        pack_w1_k<<<dim3((unsigned)((tf + 255) / 256)), 256, 0, stream>>>(gin_W1, W1f, tf);
        pack_w2_k<<<dim3((unsigned)((tf + 255) / 256)), 256, 0, stream>>>(gin_W2, W2f, tf);
        long t3 = (long)(kL - 1) * NP_H2 * KP_H;
        transpose_k<<<dim3((unsigned)((t3 + 255) / 256)), 256, 0, stream>>>(vn_W1, Wt_v1, kH, kH2, NP_H2, KP_H, t3);
        long t4 = (long)(kL - 1) * NP_H * KP_H2;
        transpose_k<<<dim3((unsigned)((t4 + 255) / 256)), 256, 0, stream>>>(vn_W2, Wt_v2, kH2, kH, NP_H, KP_H2, t4);
        long t5 = (long)NP_H2 * KP_DG;
        transpose_k<<<dim3((unsigned)((t5 + 255) / 256)), 256, 0, stream>>>(Wp1, Wt_p1, kDG, kH2, NP_H2, KP_DG, t5);
    }

    // graph ranges + node CSR
    hipMemsetAsync(counts, 0, kG * 4, stream);
    hipMemsetAsync(cnt_n, 0, (size_t)kN * 4, stream);
    hipMemsetAsync(fill_n, 0, (size_t)kN * 4, stream);
    hist_g_k<<<kN / 256, 256, 0, stream>>>(batch, counts);
    scan_g_k<<<1, 1024, 0, stream>>>(counts, starts);
    hist_n_k<<<kE / 256, 256, 0, stream>>>(ei, cnt_n);
    scanA_k<<<kN / 1024, 1024, 0, stream>>>(cnt_n, start_n, bsum);
    scanB_k<<<1, 64, 0, stream>>>(bsum);
    scanC_k<<<kN / 1024, 1024, 0, stream>>>(start_n, bsum);
    fill_n_k<<<kE / 256, 256, 0, stream>>>(ei, start_n, fill_n, perm);

    embed_k<<<kN / 4, 256, 0, stream>>>(x, W_emb, b_emb, vn0, (u32*)hvbf);
    vninit_k<<<kG, 320, 0, stream>>>(vn0, vnA);

    for (int l = 0; l < kL; l++) {
        float* vcur = vnb[l & 1];
        float* vnxt = vnb[(l + 1) & 1];
        gather_combine_k<<<kN / 4, 256, 0, stream>>>(
            (const u32*)hvbf, start_n, perm, eps, l, (u32*)hv, stats);
        if (l < kL - 1) {
            vt_fin_k<<<kG / 4, 256, 0, stream>>>(
                (const u32*)hvbf, vcur, counts, starts, (u32*)vt_in);
            gemm_k<1, 1, 0><<<dim3(16, NP_H2 / 128), 256, 0, stream>>>(
                vt_in, Wt_v1 + (size_t)l * NP_H2 * KP_H, vn_b1 + l * kH2,
                z1v, nullptr, KP_H, kH2, KP_H2, KP_H2);
            gemm64_k<0, 2, 0><<<dim3(16, NP_H / 64), 256, 0, stream>>>(
                z1v, Wt_v2 + (size_t)l * NP_H * KP_H2, vn_b2 + l * kH,
                vnxt, nullptr, vcur, KP_H2, kH, kH, kH);
        }
        // fused node MLP v6: hv -> hv (in-place), z1c double-buffered (1 barrier/chunk)
        fused_mlp_k<<<kN / 64, 256, 0, stream>>>(
            hv, W1f + (size_t)l * WFRAG_PER_L, gin_b1 + l * kH2,
            W2f + (size_t)l * WFRAG_PER_L, gin_b2 + l * kH,
            hv, stats);
        if (l < kL - 1)
            resid_k<1><<<kN / 4, 256, 0, stream>>>(
                (u32*)hvbf, (const u32*)hv, stats, bn_scale, bn_bias, l, batch, vcur, vnxt);
        else
            resid_k<0><<<kN / 4, 256, 0, stream>>>(
                (u32*)hvbf, (const u32*)hv, stats, bn_scale, bn_bias, l, batch, vcur, vcur);
    }

    float* vnlast = vnb[(kL - 1) & 1];
    pooled_k<<<kG / 4, 256, 0, stream>>>(
        (const u32*)hvbf, vnlast, counts, starts, (u32*)hrep);
    {
        long tr = (long)kG * (KP_DG - kH);
        hrep_rest_k<<<dim3((unsigned)((tr + 255) / 256)), 256, 0, stream>>>(morgan, maccs, counts, hrep);
    }
    gemm_k<1, 1, 0><<<dim3(16, NP_H2 / 128), 256, 0, stream>>>(
        hrep, Wt_p1, bp1, zp, nullptr, KP_DG, kH2, KP_H2, KP_H2);
    final_k<<<kG / 4, 256, 0, stream>>>(zp, Wp2, bp2, out);
}

// Round 13
// 1152.432 us; speedup vs baseline: 1.9082x; 1.0254x over previous
//
#include <hip/hip_runtime.h>

typedef unsigned short u16;
typedef unsigned int u32;
typedef __attribute__((ext_vector_type(8))) short bf16x8_t;
typedef __attribute__((ext_vector_type(4))) float f32x4_t;

// problem constants
#define kN 65536
#define kE 262144
#define kG 2048
#define kH 300
#define kH2 600
#define kL 5
#define kF 32
#define kDG 1523
// padded dims
#define KP_H 320     // K pad of H
#define KP_H2 640    // K pad of 2H
#define KP_DG 1536   // K pad of DG
#define NP_H2 640    // N pad of 2H (128-tiled)
#define NP_H 320     // N pad of H (64-tiled)
// hvbf row stride (u16 / u32)
#define HVS 320
#define HVS32 160
// fragment-packed weight size per layer: 5*4*2*10*64*8 == 5*4*5*4*64*8 == 204800 u16
#define WFRAG_PER_L 204800

__device__ __forceinline__ float bf2f(u16 x) {
    union { u32 u; float f; } v; v.u = ((u32)x) << 16; return v.f;
}
__device__ __forceinline__ u16 f2bf(float f) {
    union { float f; u32 u; } v; v.f = f;
    u32 u = v.u;
    u32 r = (u + 0x7fffu + ((u >> 16) & 1u)) >> 16;  // RNE
    return (u16)r;
}
__device__ __forceinline__ float blo(u32 v) { return bf2f((u16)(v & 0xffffu)); }
__device__ __forceinline__ float bhi(u32 v) { return bf2f((u16)(v >> 16)); }
__device__ __forceinline__ u32 pack2(float lo, float hi) {
    return (u32)f2bf(lo) | ((u32)f2bf(hi) << 16);
}

// async 16B global -> LDS
__device__ __forceinline__ void gld16(const u16* g, u16* l) {
    __builtin_amdgcn_global_load_lds(
        (const __attribute__((address_space(1))) u32*)g,
        (__attribute__((address_space(3))) u32*)l, 16, 0, 0);
}

// counted vmcnt waits + raw barrier
__device__ __forceinline__ void vwait6() { asm volatile("s_waitcnt vmcnt(6)" ::: "memory"); }
__device__ __forceinline__ void vwait8() { asm volatile("s_waitcnt vmcnt(8)" ::: "memory"); }
__device__ __forceinline__ void vwait0() { asm volatile("s_waitcnt vmcnt(0)" ::: "memory"); }
__device__ __forceinline__ void lwait0() { asm volatile("s_waitcnt lgkmcnt(0)" ::: "memory"); }
__device__ __forceinline__ void rbar() {
    __builtin_amdgcn_sched_barrier(0);
    __builtin_amdgcn_s_barrier();
    __builtin_amdgcn_sched_barrier(0);
}

// XCD-bijective tile swizzle (requires gridDim.x % 8 == 0; holds: 16).
__device__ __forceinline__ void swz_tile(int& m, int& n) {
    int p = blockIdx.x + gridDim.x * blockIdx.y;
    int xcd = p & 7;
    int q = p >> 3;
    int NB = gridDim.y;
    int mb8 = gridDim.x >> 3;
    m = xcd * mb8 + q / NB;
    n = q % NB;
}

// ---------------- weight transpose: W[b][k][n] (f32) -> Wt[b][n][k] (bf16), zero-padded ----------------
__global__ void transpose_k(const float* __restrict__ W, u16* __restrict__ Wt,
                            int K, int NN, int NP, int KP, long total) {
    long idx = (long)blockIdx.x * 256 + threadIdx.x;
    if (idx >= total) return;
    int per = NP * KP;
    int b = (int)(idx / per);
    int r = (int)(idx % per);
    int n = r / KP;
    int k = r % KP;
    u16 v = 0;
    if (n < NN && k < K) v = f2bf(W[(long)b * K * NN + (long)k * NN + n]);
    Wt[idx] = v;
}

// ---------------- fragment-pack W1 (gin_W1 [L][300][600]) -> W1f [L][c][w][nt][tk][lane][8] ----------------
__global__ void pack_w1_k(const float* __restrict__ W, u16* __restrict__ Wf, long total) {
    long idx = (long)blockIdx.x * 256 + threadIdx.x;
    if (idx >= total) return;
    int l = (int)(idx / WFRAG_PER_L);
    long r = idx % WFRAG_PER_L;
    int e = (int)(r & 7);
    long r1 = r >> 3;
    int ln = (int)(r1 & 63);
    int l16 = ln & 15, quad = ln >> 4;
    long s = r1 >> 6;
    int tk = (int)(s % 10);
    long s2 = s / 10;
    int nt = (int)(s2 & 1);
    long s3 = s2 >> 1;
    int w = (int)(s3 & 3);
    int c = (int)(s3 >> 2);
    int n = c * 128 + w * 32 + nt * 16 + l16;
    int k = tk * 32 + quad * 8 + e;
    u16 v = 0;
    if (n < kH2 && k < kH) v = f2bf(W[(long)l * kH * kH2 + (long)k * kH2 + n]);
    Wf[idx] = v;
}

// ---------------- fragment-pack W2 (gin_W2 [L][600][300]) -> W2f [L][c][w][nt][ks][lane][8] ----------------
__global__ void pack_w2_k(const float* __restrict__ W, u16* __restrict__ Wf, long total) {
    long idx = (long)blockIdx.x * 256 + threadIdx.x;
    if (idx >= total) return;
    int l = (int)(idx / WFRAG_PER_L);
    long r = idx % WFRAG_PER_L;
    int e = (int)(r & 7);
    long r1 = r >> 3;
    int ln = (int)(r1 & 63);
    int l16 = ln & 15, quad = ln >> 4;
    long s = r1 >> 6;
    int ks = (int)(s & 3);
    long s2 = s >> 2;
    int nt = (int)(s2 % 5);
    long s3 = s2 / 5;
    int w = (int)(s3 & 3);
    int c = (int)(s3 >> 2);
    int n = w * 80 + nt * 16 + l16;
    int k = c * 128 + ks * 32 + quad * 8 + e;
    u16 v = 0;
    if (n < kH && k < kH2) v = f2bf(W[(long)l * kH2 * kH + (long)k * kH + n]);
    Wf[idx] = v;
}

// ---------------- graph histogram + scan ----------------
__global__ void hist_g_k(const int* __restrict__ batch, int* __restrict__ counts) {
    int n = blockIdx.x * 256 + threadIdx.x;
    if (n < kN) atomicAdd(&counts[batch[n]], 1);
}

__global__ void scan_g_k(const int* __restrict__ counts, int* __restrict__ starts) {
    __shared__ int s[1024];
    int t = threadIdx.x;
    int c0 = counts[2 * t], c1 = counts[2 * t + 1];
    s[t] = c0 + c1;
    __syncthreads();
    for (int off = 1; off < 1024; off <<= 1) {
        int v = (t >= off) ? s[t - off] : 0;
        __syncthreads();
        s[t] += v;
        __syncthreads();
    }
    int excl = (t > 0) ? s[t - 1] : 0;
    starts[2 * t] = excl;
    starts[2 * t + 1] = excl + c0;
}

// ---------------- node CSR build ----------------
__global__ void hist_n_k(const int* __restrict__ ei, int* __restrict__ cnt) {
    int e = blockIdx.x * 256 + threadIdx.x;
    if (e < kE) atomicAdd(&cnt[ei[kE + e]], 1);
}

__global__ void scanA_k(const int* __restrict__ cnt, int* __restrict__ start, int* __restrict__ bsum) {
    __shared__ int s[1024];
    int b = blockIdx.x, t = threadIdx.x;
    int v = cnt[b * 1024 + t];
    s[t] = v;
    __syncthreads();
    for (int off = 1; off < 1024; off <<= 1) {
        int u = (t >= off) ? s[t - off] : 0;
        __syncthreads();
        s[t] += u;
        __syncthreads();
    }
    start[b * 1024 + t] = s[t] - v;
    if (t == 1023) bsum[b] = s[1023];
}

__global__ void scanB_k(int* __restrict__ bsum) {
    if (threadIdx.x == 0) {
        int s = 0;
        for (int i = 0; i < kN / 1024; i++) { s += bsum[i]; bsum[i] = s; }
    }
}

__global__ void scanC_k(int* __restrict__ start, const int* __restrict__ bsum) {
    int b = blockIdx.x, t = threadIdx.x;
    int add = (b > 0) ? bsum[b - 1] : 0;
    start[b * 1024 + t] += add;
    if (b == kN / 1024 - 1 && t == 1023) start[kN] = bsum[kN / 1024 - 1];
}

__global__ void fill_n_k(const int* __restrict__ ei, const int* __restrict__ start,
                         int* __restrict__ fill, int* __restrict__ perm) {
    int e = blockIdx.x * 256 + threadIdx.x;
    if (e >= kE) return;
    int s = ei[e], d = ei[kE + e];
    int pos = start[d] + atomicAdd(&fill[d], 1);
    perm[pos] = s;
}

// ---------------- node embedding: hvbf = bf16(x@W+b + vn0) ----------------
__global__ __launch_bounds__(256) void embed_k(
    const float* __restrict__ x, const float* __restrict__ W,
    const float* __restrict__ b, const float* __restrict__ vn0,
    u32* __restrict__ hv32) {
    __shared__ float sW[9 * kH];
    __shared__ float sBV[kH];
    int tid = threadIdx.x;
    for (int i = tid; i < 9 * kH; i += 256) sW[i] = W[i];
    for (int i = tid; i < kH; i += 256) sBV[i] = b[i] + vn0[i];
    __syncthreads();
    int wave = tid >> 6, lane = tid & 63;
    int n = blockIdx.x * 4 + wave;
    float xv[9];
    #pragma unroll
    for (int d = 0; d < 9; d++) xv[d] = x[n * 9 + d];
    #pragma unroll
    for (int p = 0; p < 3; p++) {
        int ii = lane + p * 64;
        if (ii < 150) {
            int c0 = 2 * ii;
            float a0 = sBV[c0], a1 = sBV[c0 + 1];
            #pragma unroll
            for (int d = 0; d < 9; d++) {
                a0 += xv[d] * sW[d * kH + c0];
                a1 += xv[d] * sW[d * kH + c0 + 1];
            }
            hv32[(long)n * HVS32 + ii] = pack2(a0, a1);
        } else if (ii < HVS32) {
            hv32[(long)n * HVS32 + ii] = 0u;
        }
    }
}

__global__ void vninit_k(const float* __restrict__ vn0, float* __restrict__ vn) {
    int g = blockIdx.x, c = threadIdx.x;
    if (c < kH) vn[g * kH + c] = vn0[c];
}

// ---------------- gather + combine ----------------
__global__ __launch_bounds__(256) void gather_combine_k(
    const u32* __restrict__ hv32, const int* __restrict__ start_n,
    const int* __restrict__ perm, const float* __restrict__ eps, int l,
    u32* __restrict__ out32, float* __restrict__ stats) {
    int tid = threadIdx.x;
    int wave = tid >> 6, lane = tid & 63;
    int n = blockIdx.x * 4 + wave;
    int st = start_n[n], en = start_n[n + 1];
    int i0 = lane, i1 = lane + 64, i2 = lane + 128;
    bool p2 = (i2 < 150);
    float a0 = 0.f, b0 = 0.f, a1 = 0.f, b1 = 0.f, a2 = 0.f, b2 = 0.f;
    int e = st;
    for (; e + 4 <= en; e += 4) {
        const u32* rA = hv32 + (long)perm[e] * HVS32;
        const u32* rB = hv32 + (long)perm[e + 1] * HVS32;
        const u32* rC = hv32 + (long)perm[e + 2] * HVS32;
        const u32* rD = hv32 + (long)perm[e + 3] * HVS32;
        u32 vA0 = rA[i0], vA1 = rA[i1], vA2 = p2 ? rA[i2] : 0u;
        u32 vB0 = rB[i0], vB1 = rB[i1], vB2 = p2 ? rB[i2] : 0u;
        u32 vC0 = rC[i0], vC1 = rC[i1], vC2 = p2 ? rC[i2] : 0u;
        u32 vD0 = rD[i0], vD1 = rD[i1], vD2 = p2 ? rD[i2] : 0u;
        a0 += (blo(vA0) + blo(vB0)) + (blo(vC0) + blo(vD0));
        b0 += (bhi(vA0) + bhi(vB0)) + (bhi(vC0) + bhi(vD0));
        a1 += (blo(vA1) + blo(vB1)) + (blo(vC1) + blo(vD1));
        b1 += (bhi(vA1) + bhi(vB1)) + (bhi(vC1) + bhi(vD1));
        a2 += (blo(vA2) + blo(vB2)) + (blo(vC2) + blo(vD2));
        b2 += (bhi(vA2) + bhi(vB2)) + (bhi(vC2) + bhi(vD2));
    }
    for (; e + 2 <= en; e += 2) {
        const u32* rA = hv32 + (long)perm[e] * HVS32;
        const u32* rB = hv32 + (long)perm[e + 1] * HVS32;
        u32 vA0 = rA[i0], vA1 = rA[i1], vA2 = p2 ? rA[i2] : 0u;
        u32 vB0 = rB[i0], vB1 = rB[i1], vB2 = p2 ? rB[i2] : 0u;
        a0 += blo(vA0) + blo(vB0); b0 += bhi(vA0) + bhi(vB0);
        a1 += blo(vA1) + blo(vB1); b1 += bhi(vA1) + bhi(vB1);
        a2 += blo(vA2) + blo(vB2); b2 += bhi(vA2) + bhi(vB2);
    }
    if (e < en) {
        const u32* rA = hv32 + (long)perm[e] * HVS32;
        u32 vA0 = rA[i0], vA1 = rA[i1], vA2 = p2 ? rA[i2] : 0u;
        a0 += blo(vA0); b0 += bhi(vA0);
        a1 += blo(vA1); b1 += bhi(vA1);
        a2 += blo(vA2); b2 += bhi(vA2);
    }
    const u32* self = hv32 + (long)n * HVS32;
    float ep = 1.f + eps[l];
    u32 s0 = self[i0], s1 = self[i1];
    u32* o = out32 + (long)n * HVS32;
    o[i0] = pack2(ep * blo(s0) + a0, ep * bhi(s0) + b0);
    o[i1] = pack2(ep * blo(s1) + a1, ep * bhi(s1) + b1);
    if (p2) {
        u32 s2 = self[i2];
        o[i2] = pack2(ep * blo(s2) + a2, ep * bhi(s2) + b2);
    } else if (i2 < HVS32) {
        o[i2] = 0u;
    }
    int gz = blockIdx.x * 256 + tid;
    if (gz < 2 * kH) stats[gz] = 0.f;
}

// ---------------- vt (wave per graph): vt[g] = sum_rows hvbf + vn_cur[g] ----------------
__global__ __launch_bounds__(256) void vt_fin_k(
    const u32* __restrict__ hv32, const float* __restrict__ vncur,
    const int* __restrict__ counts, const int* __restrict__ starts,
    u32* __restrict__ vt32) {
    int tid = threadIdx.x, wave = tid >> 6, lane = tid & 63;
    int g = blockIdx.x * 4 + wave;
    int cnt = counts[g], st = starts[g];
    int i0 = lane, i1 = lane + 64, i2 = lane + 128;
    bool p2 = (i2 < 150);
    float a0 = 0.f, b0 = 0.f, a1 = 0.f, b1 = 0.f, a2 = 0.f, b2 = 0.f;
    int i = 0;
    for (; i + 4 <= cnt; i += 4) {
        const u32* rA = hv32 + (long)(st + i) * HVS32;
        const u32* rB = hv32 + (long)(st + i + 1) * HVS32;
        const u32* rC = hv32 + (long)(st + i + 2) * HVS32;
        const u32* rD = hv32 + (long)(st + i + 3) * HVS32;
        u32 vA0 = rA[i0], vA1 = rA[i1], vA2 = p2 ? rA[i2] : 0u;
        u32 vB0 = rB[i0], vB1 = rB[i1], vB2 = p2 ? rB[i2] : 0u;
        u32 vC0 = rC[i0], vC1 = rC[i1], vC2 = p2 ? rC[i2] : 0u;
        u32 vD0 = rD[i0], vD1 = rD[i1], vD2 = p2 ? rD[i2] : 0u;
        a0 += (blo(vA0) + blo(vB0)) + (blo(vC0) + blo(vD0));
        b0 += (bhi(vA0) + bhi(vB0)) + (bhi(vC0) + bhi(vD0));
        a1 += (blo(vA1) + blo(vB1)) + (blo(vC1) + blo(vD1));
        b1 += (bhi(vA1) + bhi(vB1)) + (bhi(vC1) + bhi(vD1));
        a2 += (blo(vA2) + blo(vB2)) + (blo(vC2) + blo(vD2));
        b2 += (bhi(vA2) + bhi(vB2)) + (bhi(vC2) + bhi(vD2));
    }
    for (; i < cnt; i++) {
        const u32* rA = hv32 + (long)(st + i) * HVS32;
        u32 vA0 = rA[i0], vA1 = rA[i1], vA2 = p2 ? rA[i2] : 0u;
        a0 += blo(vA0); b0 += bhi(vA0);
        a1 += blo(vA1); b1 += bhi(vA1);
        a2 += blo(vA2); b2 += bhi(vA2);
    }
    const float* vg = vncur + g * kH;
    vt32[(long)g * HVS32 + i0] = pack2(a0 + vg[2 * i0], b0 + vg[2 * i0 + 1]);
    vt32[(long)g * HVS32 + i1] = pack2(a1 + vg[2 * i1], b1 + vg[2 * i1 + 1]);
    if (p2) vt32[(long)g * HVS32 + i2] = pack2(a2 + vg[2 * i2], b2 + vg[2 * i2 + 1]);
    else if (i2 < HVS32) vt32[(long)g * HVS32 + i2] = 0u;
}

// ---------------- FUSED node MLP v7: dbuf z1c + early phase-B weight issue ----------------
// 256 thr / 64-row strip, 2 blocks/CU. v6 (dbuf z1c, 1 barrier/chunk) + wg[0..1] issued
// BEFORE the handoff writes (latency hides under ds_writes + barrier) and in-loop
// prefetch of ks+2 placed AFTER the consuming MFMAs (full-iteration cover, no collision).
__global__ __launch_bounds__(256, 2) void fused_mlp_k(
    const u16* __restrict__ A,      // hv [kN x 320] bf16
    const u16* __restrict__ W1f,    // fragment-packed [5][4][2][10][64][8]
    const float* __restrict__ b1,   // [600]
    const u16* __restrict__ W2f,    // fragment-packed [5][4][5][4][64][8]
    const float* __restrict__ b2,   // [300]
    u16* __restrict__ outp,         // hv (in-place)
    float* __restrict__ stats) {
    __shared__ __align__(16) u16 lA[5][64 * 64];    // 40 KB persistent A strip
    __shared__ __align__(16) u16 z1c[2][64 * 128];  // 32 KB z1 chunk dbuf, XOR swizzle
    __shared__ float sred[320][2];                  // 2.5 KB BN partial sums

    const int tid = threadIdx.x;
    const int lane = tid & 63;
    const int wave = tid >> 6;      // 0..3
    const int l16 = lane & 15;
    const int quad = lane >> 4;
    const long tm = (long)blockIdx.x * 64;
    const int srow = lane >> 3;
    const int sch = (lane & 7) ^ srow;

    for (int i = tid; i < 320; i += 256) { sred[i][0] = 0.f; sred[i][1] = 0.f; }

    // stage the whole A strip once (5 k-tiles x 64 rows)
    #pragma unroll
    for (int t = 0; t < 5; t++) {
        #pragma unroll
        for (int j = 0; j < 2; j++) {
            int rb = wave * 16 + j * 8;
            gld16(A + (tm + rb + srow) * KP_H + t * 64 + sch * 8, &lA[t][rb * 64]);
        }
    }

    // preload biases (compile-time indexed after full unroll)
    float rb1[5][2];
    #pragma unroll
    for (int c = 0; c < 5; c++)
        #pragma unroll
        for (int nt = 0; nt < 2; nt++) {
            int gc = c * 128 + wave * 32 + nt * 16 + l16;
            rb1[c][nt] = (gc < kH2) ? b1[gc] : 0.f;
        }
    float rb2[5];
    #pragma unroll
    for (int nt = 0; nt < 5; nt++) {
        int col = wave * 80 + nt * 16 + l16;
        rb2[nt] = (col < kH) ? b2[col] : 0.f;
    }

    f32x4_t acc2[4][5];
    #pragma unroll
    for (int i = 0; i < 4; i++)
        #pragma unroll
        for (int j = 0; j < 5; j++) acc2[i][j] = (f32x4_t){0.f, 0.f, 0.f, 0.f};

    vwait0();
    rbar();  // A strip staged; sred zeroed

    #pragma unroll
    for (int c = 0; c < 5; c++) {
        // ---------- phase A (barrier-free): z1 chunk = A @ W1 chunk ----------
        f32x4_t acc1[4][2];
        #pragma unroll
        for (int i = 0; i < 4; i++) {
            acc1[i][0] = (f32x4_t){0.f, 0.f, 0.f, 0.f};
            acc1[i][1] = (f32x4_t){0.f, 0.f, 0.f, 0.f};
        }
        // fragment base for (c, wave): [((c*4+w)*2+nt)*10 + tk] frames of 512 u16
        const u16* w1p = W1f + ((long)((c * 4 + wave) * 2) * 10) * 512 + lane * 8;
        bf16x8_t wf[4][2];
        #pragma unroll
        for (int p = 0; p < 3; p++) {   // preload tk=0..2 (distance-3 rotation)
            wf[p][0] = *(const bf16x8_t*)(w1p + p * 512);
            wf[p][1] = *(const bf16x8_t*)(w1p + 10 * 512 + p * 512);
        }
        #pragma unroll
        for (int tk = 0; tk < 10; tk++) {
            if (tk + 3 < 10) {          // prefetch tk+3 into slot (tk+3)&3 != tk&3
                wf[(tk + 3) & 3][0] = *(const bf16x8_t*)(w1p + (tk + 3) * 512);
                wf[(tk + 3) & 3][1] = *(const bf16x8_t*)(w1p + 10 * 512 + (tk + 3) * 512);
            }
            const int t = tk >> 1, ks = tk & 1;
            bf16x8_t af[4];
            #pragma unroll
            for (int mt = 0; mt < 4; mt++) {
                int row = mt * 16 + l16;
                int phys = (ks * 4 + quad) ^ (l16 & 7);
                af[mt] = *(const bf16x8_t*)&lA[t][row * 64 + phys * 8];
            }
            #pragma unroll
            for (int mt = 0; mt < 4; mt++) {
                acc1[mt][0] = __builtin_amdgcn_mfma_f32_16x16x32_bf16(af[mt], wf[tk & 3][0], acc1[mt][0], 0, 0, 0);
                acc1[mt][1] = __builtin_amdgcn_mfma_f32_16x16x32_bf16(af[mt], wf[tk & 3][1], acc1[mt][1], 0, 0, 0);
            }
        }

        // issue phase-B ks=0,1 weights NOW — latency hides under handoff + barrier
        const u16* w2p = W2f + ((long)((c * 4 + wave) * 5) * 4) * 512 + lane * 8;
        bf16x8_t wg[2][5];
        #pragma unroll
        for (int nt = 0; nt < 5; nt++) {
            wg[0][nt] = *(const bf16x8_t*)(w2p + nt * 4 * 512);
            wg[1][nt] = *(const bf16x8_t*)(w2p + nt * 4 * 512 + 512);
        }

        // ---------- z1c handoff into buf[c&1] (no leading barrier needed: dbuf) ----------
        u16* zb = z1c[c & 1];
        #pragma unroll
        for (int nt = 0; nt < 2; nt++) {
            int col = wave * 32 + nt * 16 + l16;
            #pragma unroll
            for (int mt = 0; mt < 4; mt++) {
                #pragma unroll
                for (int r = 0; r < 4; r++) {
                    int row = mt * 16 + quad * 4 + r;
                    float v = fmaxf(acc1[mt][nt][r] + rb1[c][nt], 0.f);
                    int phys = (col >> 3) ^ (row & 15);
                    zb[row * 128 + phys * 8 + (col & 7)] = f2bf(v);
                }
            }
        }
        lwait0();
        rbar();  // z1c[c&1] visible to all waves (also orders next chunk's writes)

        // ---------- phase B (barrier-free): acc2 += z1c[c&1] @ W2 chunk ----------
        #pragma unroll
        for (int ks = 0; ks < 4; ks++) {
            bf16x8_t af[4];
            #pragma unroll
            for (int mt = 0; mt < 4; mt++) {
                int row = mt * 16 + l16;
                int phys = (ks * 4 + quad) ^ (row & 15);
                af[mt] = *(const bf16x8_t*)&zb[row * 128 + phys * 8];
            }
            #pragma unroll
            for (int mt = 0; mt < 4; mt++)
                #pragma unroll
                for (int nt = 0; nt < 5; nt++)
                    acc2[mt][nt] = __builtin_amdgcn_mfma_f32_16x16x32_bf16(af[mt], wg[ks & 1][nt], acc2[mt][nt], 0, 0, 0);
            if (ks + 2 < 4) {  // refill consumed slot with ks+2 (full-iteration latency cover)
                #pragma unroll
                for (int nt = 0; nt < 5; nt++)
                    wg[ks & 1][nt] = *(const bf16x8_t*)(w2p + nt * 4 * 512 + (ks + 2) * 512);
            }
        }
    }

    // ---------- epilogue: bias, bf16 store (in-place), BN stats ----------
    #pragma unroll
    for (int nt = 0; nt < 5; nt++) {
        int col = wave * 80 + nt * 16 + l16;
        float s = 0.f, s2 = 0.f;
        #pragma unroll
        for (int mt = 0; mt < 4; mt++) {
            #pragma unroll
            for (int r = 0; r < 4; r++) {
                long row = tm + mt * 16 + quad * 4 + r;
                float v = acc2[mt][nt][r] + rb2[nt];
                float sv = (col < kH) ? v : 0.f;
                outp[row * KP_H + col] = f2bf(sv);
                s += sv; s2 += sv * sv;
            }
        }
        atomicAdd(&sred[col][0], s);
        atomicAdd(&sred[col][1], s2);
    }
    __syncthreads();
    for (int i = tid; i < kH; i += 256) {
        atomicAdd(&stats[i], sred[i][0]);
        atomicAdd(&stats[kH + i], sred[i][1]);
    }
}

// ---------------- GEMM: 128x128 tile, BK=64, counted-vmcnt double-buffered pipeline ----------------
template<int ACT, int OUT_BF16, int BN_STATS>
__global__ __launch_bounds__(256) void gemm_k(
    const u16* __restrict__ A, const u16* __restrict__ Wt,
    const float* __restrict__ bias, void* __restrict__ out,
    float* __restrict__ stats,
    int KP, int NN, int out_stride, int store_cols) {
    __shared__ __align__(16) u16 lA[2][128 * 64];
    __shared__ __align__(16) u16 lB[2][128 * 64];
    __shared__ float sred[128][2];

    const int tid = threadIdx.x;
    const int lane = tid & 63;
    const int wave = tid >> 6;
    const int l16 = lane & 15;
    const int quad = lane >> 4;
    const int wm = (wave & 1) * 64;
    const int wn = (wave >> 1) * 64;
    int sm, sn;
    swz_tile(sm, sn);
    const long tm = (long)sm * 128;
    const int tn = sn * 128;

    const int srow = lane >> 3;
    const int sch = (lane & 7) ^ srow;

    f32x4_t acc[4][4];
    #pragma unroll
    for (int i = 0; i < 4; i++)
        #pragma unroll
        for (int j = 0; j < 4; j++) acc[i][j] = (f32x4_t){0.f, 0.f, 0.f, 0.f};

    auto stage = [&](int bb, int k0) {  // 8 VMEM per wave
        #pragma unroll
        for (int j = 0; j < 4; j++) {
            int rb = wave * 32 + j * 8;
            int r = rb + srow;
            gld16(A + (tm + r) * KP + k0 + sch * 8, &lA[bb][rb * 64]);
            gld16(Wt + (long)(tn + r) * KP + k0 + sch * 8, &lB[bb][rb * 64]);
        }
    };

    const int nk = KP >> 6;
    stage(0, 0);
    if (nk > 1) stage(1, 64);
    for (int t = 0; t < nk; t++) {
        if (t < nk - 1) vwait8(); else vwait0();
        rbar();
        const u16* la = lA[t & 1];
        const u16* lb = lB[t & 1];
        #pragma unroll
        for (int ks = 0; ks < 2; ks++) {
            bf16x8_t af[4], bfr[4];
            #pragma unroll
            for (int mt = 0; mt < 4; mt++) {
                int row = wm + mt * 16 + l16;
                int phys = (ks * 4 + quad) ^ (l16 & 7);
                af[mt] = *(const bf16x8_t*)&la[row * 64 + phys * 8];
            }
            #pragma unroll
            for (int nt = 0; nt < 4; nt++) {
                int row = wn + nt * 16 + l16;
                int phys = (ks * 4 + quad) ^ (l16 & 7);
                bfr[nt] = *(const bf16x8_t*)&lb[row * 64 + phys * 8];
            }
            #pragma unroll
            for (int mt = 0; mt < 4; mt++)
                #pragma unroll
                for (int nt = 0; nt < 4; nt++)
                    acc[mt][nt] = __builtin_amdgcn_mfma_f32_16x16x32_bf16(af[mt], bfr[nt], acc[mt][nt], 0, 0, 0);
        }
        rbar();
        if (t + 2 < nk) stage(t & 1, (t + 2) * 64);
    }

    if (BN_STATS) {
        if (tid < 128) { sred[tid][0] = 0.f; sred[tid][1] = 0.f; }
    }
    __syncthreads();

    #pragma unroll
    for (int nt = 0; nt < 4; nt++) {
        int col = tn + wn + nt * 16 + l16;
        float bv = (col < NN) ? bias[col] : 0.f;
        float s = 0.f, s2 = 0.f;
        #pragma unroll
        for (int mt = 0; mt < 4; mt++) {
            #pragma unroll
            for (int r = 0; r < 4; r++) {
                long row = tm + wm + mt * 16 + quad * 4 + r;
                float v = acc[mt][nt][r] + bv;
                if (ACT) v = fmaxf(v, 0.f);
                float sv = (col < NN) ? v : 0.f;
                if (col < store_cols) {
                    if (OUT_BF16) ((u16*)out)[row * out_stride + col] = f2bf(sv);
                    else          ((float*)out)[row * out_stride + col] = sv;
                }
                s += sv; s2 += sv * sv;
            }
        }
        if (BN_STATS) {
            atomicAdd(&sred[wn + nt * 16 + l16][0], s);
            atomicAdd(&sred[wn + nt * 16 + l16][1], s2);
        }
    }
    if (BN_STATS) {
        __syncthreads();
        if (tid < 128) {
            int col = tn + tid;
            if (col < NN) {
                atomicAdd(&stats[col], sred[tid][0]);
                atomicAdd(&stats[NN + col], sred[tid][1]);
            }
        }
    }
}

// ---------------- GEMM64: 128x64 tile; OUT_MODE: 0=f32, 1=bf16, 2=vn_nxt = vn_cur + relu(v) ----------------
template<int ACT, int OUT_MODE, int BN_STATS>
__global__ __launch_bounds__(256) void gemm64_k(
    const u16* __restrict__ A, const u16* __restrict__ Wt,
    const float* __restrict__ bias, void* __restrict__ out,
    float* __restrict__ stats, const float* __restrict__ vnacc,
    int KP, int NN, int out_stride, int store_cols) {
    __shared__ __align__(16) u16 lA[2][128 * 64];
    __shared__ __align__(16) u16 lB[2][64 * 64];
    __shared__ float sred[64][2];

    const int tid = threadIdx.x;
    const int lane = tid & 63;
    const int wave = tid >> 6;
    const int l16 = lane & 15;
    const int quad = lane >> 4;
    const int wm = (wave & 1) * 64;
    const int wn = (wave >> 1) * 32;
    int sm, sn;
    swz_tile(sm, sn);
    const long tm = (long)sm * 128;
    const int tn = sn * 64;

    const int srow = lane >> 3;
    const int sch = (lane & 7) ^ srow;

    f32x4_t acc[4][2];
    #pragma unroll
    for (int i = 0; i < 4; i++)
        #pragma unroll
        for (int j = 0; j < 2; j++) acc[i][j] = (f32x4_t){0.f, 0.f, 0.f, 0.f};

    auto stage = [&](int bb, int k0) {  // 6 VMEM per wave
        #pragma unroll
        for (int j = 0; j < 4; j++) {
            int rb = wave * 32 + j * 8;
            gld16(A + (tm + rb + srow) * KP + k0 + sch * 8, &lA[bb][rb * 64]);
        }
        #pragma unroll
        for (int j = 0; j < 2; j++) {
            int rb = wave * 16 + j * 8;
            gld16(Wt + (long)(tn + rb + srow) * KP + k0 + sch * 8, &lB[bb][rb * 64]);
        }
    };

    const int nk = KP >> 6;
    stage(0, 0);
    if (nk > 1) stage(1, 64);
    for (int t = 0; t < nk; t++) {
        if (t < nk - 1) vwait6(); else vwait0();
        rbar();
        const u16* la = lA[t & 1];
        const u16* lb = lB[t & 1];
        #pragma unroll
        for (int ks = 0; ks < 2; ks++) {
            bf16x8_t af[4], bfr[2];
            #pragma unroll
            for (int mt = 0; mt < 4; mt++) {
                int row = wm + mt * 16 + l16;
                int phys = (ks * 4 + quad) ^ (l16 & 7);
                af[mt] = *(const bf16x8_t*)&la[row * 64 + phys * 8];
            }
            #pragma unroll
            for (int nt = 0; nt < 2; nt++) {
                int row = wn + nt * 16 + l16;
                int phys = (ks * 4 + quad) ^ (l16 & 7);
                bfr[nt] = *(const bf16x8_t*)&lb[row * 64 + phys * 8];
            }
            #pragma unroll
            for (int mt = 0; mt < 4; mt++)
                #pragma unroll
                for (int nt = 0; nt < 2; nt++)
                    acc[mt][nt] = __builtin_amdgcn_mfma_f32_16x16x32_bf16(af[mt], bfr[nt], acc[mt][nt], 0, 0, 0);
        }
        rbar();
        if (t + 2 < nk) stage(t & 1, (t + 2) * 64);
    }

    if (BN_STATS) {
        if (tid < 64) { sred[tid][0] = 0.f; sred[tid][1] = 0.f; }
    }
    __syncthreads();

    #pragma unroll
    for (int nt = 0; nt < 2; nt++) {
        int col = tn + wn + nt * 16 + l16;
        float bv = (col < NN) ? bias[col] : 0.f;
        float s = 0.f, s2 = 0.f;
        #pragma unroll
        for (int mt = 0; mt < 4; mt++) {
            #pragma unroll
            for (int r = 0; r < 4; r++) {
                long row = tm + wm + mt * 16 + quad * 4 + r;
                float v = acc[mt][nt][r] + bv;
                if (ACT) v = fmaxf(v, 0.f);
                float sv = (col < NN) ? v : 0.f;
                if (col < store_cols) {
                    if (OUT_MODE == 1) ((u16*)out)[row * out_stride + col] = f2bf(sv);
                    else if (OUT_MODE == 2)
                        ((float*)out)[row * out_stride + col] =
                            vnacc[row * out_stride + col] + fmaxf(v, 0.f);
                    else ((float*)out)[row * out_stride + col] = sv;
                }
                s += sv; s2 += sv * sv;
            }
        }
        if (BN_STATS) {
            atomicAdd(&sred[wn + nt * 16 + l16][0], s);
            atomicAdd(&sred[wn + nt * 16 + l16][1], s2);
        }
    }
    if (BN_STATS) {
        __syncthreads();
        if (tid < 64) {
            int col = tn + tid;
            if (col < NN) {
                atomicAdd(&stats[col], sred[tid][0]);
                atomicAdd(&stats[NN + col], sred[tid][1]);
            }
        }
    }
}

// ---------------- BN-apply + (relu) + residual ----------------
template<int RELU>
__global__ __launch_bounds__(256) void resid_k(
    u32* __restrict__ hvb32, const u32* __restrict__ z32,
    const float* __restrict__ stats,
    const float* __restrict__ scale, const float* __restrict__ bias, int l,
    const int* __restrict__ batch,
    const float* __restrict__ vncur, const float* __restrict__ vnnxt) {
    int tid = threadIdx.x;
    int wave = tid >> 6, lane = tid & 63;
    int n = blockIdx.x * 4 + wave;
    int g = batch[n];
    #pragma unroll
    for (int p = 0; p < 3; p++) {
        int ii = lane + p * 64;
        if (ii >= 150) break;
        int c0 = 2 * ii;
        float m0 = stats[c0] * (1.f / (float)kN), m1 = stats[c0 + 1] * (1.f / (float)kN);
        float v0 = fmaxf(stats[kH + c0] * (1.f / (float)kN) - m0 * m0, 0.f);
        float v1 = fmaxf(stats[kH + c0 + 1] * (1.f / (float)kN) - m1 * m1, 0.f);
        float a0 = scale[l * kH + c0] * rsqrtf(v0 + 1e-5f);
        float a1 = scale[l * kH + c0 + 1] * rsqrtf(v1 + 1e-5f);
        float d0 = bias[l * kH + c0] - m0 * a0;
        float d1 = bias[l * kH + c0 + 1] - m1 * a1;
        u32 zz = z32[(long)n * HVS32 + ii];
        u32 ho = hvb32[(long)n * HVS32 + ii];
        float2 vc = *(const float2*)(vncur + g * kH + c0);
        float2 vx = *(const float2*)(vnnxt + g * kH + c0);
        float t0 = blo(zz) * a0 + d0;
        float t1 = bhi(zz) * a1 + d1;
        if (RELU) { t0 = fmaxf(t0, 0.f); t1 = fmaxf(t1, 0.f); }
        float h0 = (blo(ho) - vc.x) + t0;
        float h1 = (bhi(ho) - vc.y) + t1;
        hvb32[(long)n * HVS32 + ii] = pack2(h0 + vx.x, h1 + vx.y);
    }
}

// ---------------- pooled mean (wave per graph) ----------------
__global__ __launch_bounds__(256) void pooled_k(
    const u32* __restrict__ hv32, const float* __restrict__ vnlast,
    const int* __restrict__ counts, const int* __restrict__ starts,
    u32* __restrict__ hrep32) {
    int tid = threadIdx.x, wave = tid >> 6, lane = tid & 63;
    int g = blockIdx.x * 4 + wave;
    int cnt = counts[g], st = starts[g];
    int i0 = lane, i1 = lane + 64, i2 = lane + 128;
    bool p2 = (i2 < 150);
    float a0 = 0.f, b0 = 0.f, a1 = 0.f, b1 = 0.f, a2 = 0.f, b2 = 0.f;
    int i = 0;
    for (; i + 4 <= cnt; i += 4) {
        const u32* rA = hv32 + (long)(st + i) * HVS32;
        const u32* rB = hv32 + (long)(st + i + 1) * HVS32;
        const u32* rC = hv32 + (long)(st + i + 2) * HVS32;
        const u32* rD = hv32 + (long)(st + i + 3) * HVS32;
        u32 vA0 = rA[i0], vA1 = rA[i1], vA2 = p2 ? rA[i2] : 0u;
        u32 vB0 = rB[i0], vB1 = rB[i1], vB2 = p2 ? rB[i2] : 0u;
        u32 vC0 = rC[i0], vC1 = rC[i1], vC2 = p2 ? rC[i2] : 0u;
        u32 vD0 = rD[i0], vD1 = rD[i1], vD2 = p2 ? rD[i2] : 0u;
        a0 += (blo(vA0) + blo(vB0)) + (blo(vC0) + blo(vD0));
        b0 += (bhi(vA0) + bhi(vB0)) + (bhi(vC0) + bhi(vD0));
        a1 += (blo(vA1) + blo(vB1)) + (blo(vC1) + blo(vD1));
        b1 += (bhi(vA1) + bhi(vB1)) + (bhi(vC1) + bhi(vD1));
        a2 += (blo(vA2) + blo(vB2)) + (blo(vC2) + blo(vD2));
        b2 += (bhi(vA2) + bhi(vB2)) + (bhi(vC2) + bhi(vD2));
    }
    for (; i < cnt; i++) {
        const u32* rA = hv32 + (long)(st + i) * HVS32;
        u32 vA0 = rA[i0], vA1 = rA[i1], vA2 = p2 ? rA[i2] : 0u;
        a0 += blo(vA0); b0 += bhi(vA0);
        a1 += blo(vA1); b1 += bhi(vA1);
        a2 += blo(vA2); b2 += bhi(vA2);
    }
    float fc = (float)cnt;
    float inv = 1.f / (float)(cnt > 0 ? cnt : 1);
    const float* vg = vnlast + g * kH;
    hrep32[(long)g * 768 + i0] = pack2((a0 - fc * vg[2 * i0]) * inv, (b0 - fc * vg[2 * i0 + 1]) * inv);
    hrep32[(long)g * 768 + i1] = pack2((a1 - fc * vg[2 * i1]) * inv, (b1 - fc * vg[2 * i1 + 1]) * inv);
    if (p2)
        hrep32[(long)g * 768 + i2] = pack2((a2 - fc * vg[2 * i2]) * inv, (b2 - fc * vg[2 * i2 + 1]) * inv);
}

// ---------------- h_rep cols [300,1536) ----------------
__global__ void hrep_rest_k(const float* __restrict__ morgan, const float* __restrict__ maccs,
                            const int* __restrict__ counts, u16* __restrict__ hrep) {
    long idx = (long)blockIdx.x * 256 + threadIdx.x;
    if (idx >= (long)kG * (KP_DG - kH)) return;
    int g = (int)(idx / (KP_DG - kH));
    int j = (int)(idx % (KP_DG - kH));
    int col = kH + j;
    u16 v;
    if (j < kF) {
        int c = counts[g];
        int q = (j < c) ? ((c - 1 - j) / kF + 1) : 0;
        v = f2bf((float)q / (float)(c > 0 ? c : 1));
    } else if (j < kF + 1024) {
        v = f2bf(morgan[(long)g * 1024 + (j - kF)]);
    } else if (j < kF + 1024 + 167) {
        v = f2bf(maccs[(long)g * 167 + (j - kF - 1024)]);
    } else {
        v = 0;
    }
    hrep[(long)g * KP_DG + col] = v;
}

// ---------------- final ----------------
__global__ void final_k(const u16* __restrict__ zp, const float* __restrict__ Wp2,
                        const float* __restrict__ bp2, float* __restrict__ out) {
    int wave = threadIdx.x >> 6, lane = threadIdx.x & 63;
    int g = blockIdx.x * 4 + wave;
    float acc = 0.f;
    for (int c = lane; c < kH2; c += 64) acc += bf2f(zp[(long)g * KP_H2 + c]) * Wp2[c];
    #pragma unroll
    for (int off = 32; off; off >>= 1) acc += __shfl_down(acc, off);
    if (lane == 0) out[g] = acc + bp2[0];
}

extern "C" void kernel_launch(void* const* d_in, const int* in_sizes, int n_in,
                              void* d_out, int out_size, void* d_ws, size_t ws_size,
                              hipStream_t stream) {
    const float* x      = (const float*)d_in[0];
    const float* morgan = (const float*)d_in[1];
    const float* maccs  = (const float*)d_in[2];
    const int*   ei     = (const int*)d_in[3];
    const int*   batch  = (const int*)d_in[4];
    const float* W_emb  = (const float*)d_in[5];
    const float* b_emb  = (const float*)d_in[6];
    const float* gin_W1 = (const float*)d_in[7];
    const float* gin_b1 = (const float*)d_in[8];
    const float* gin_W2 = (const float*)d_in[9];
    const float* gin_b2 = (const float*)d_in[10];
    const float* bn_scale = (const float*)d_in[11];
    const float* bn_bias  = (const float*)d_in[12];
    const float* eps    = (const float*)d_in[13];
    const float* vn0    = (const float*)d_in[14];
    const float* vn_W1  = (const float*)d_in[15];
    const float* vn_b1  = (const float*)d_in[16];
    const float* vn_W2  = (const float*)d_in[17];
    const float* vn_b2  = (const float*)d_in[18];
    const float* Wp1    = (const float*)d_in[19];
    const float* bp1    = (const float*)d_in[20];
    const float* Wp2    = (const float*)d_in[21];
    const float* bp2    = (const float*)d_in[22];
    float* out = (float*)d_out;

    char* ws = (char*)d_ws;
    size_t off = 0;
    auto alloc = [&](size_t bytes) -> char* {
        char* p = ws + off;
        off += (bytes + 255) & ~(size_t)255;
        return p;
    };
    u16*   hvbf = (u16*)alloc((size_t)kN * HVS * 2);        // 41.9 MB
    u16*   hv   = (u16*)alloc((size_t)kN * KP_H * 2);       // 41.9 MB
    u16*   z1   = (u16*)alloc((size_t)kN * KP_H2 * 2);      // 83.9 MB (vn/pred overlays)
    float* vnA  = (float*)alloc((size_t)kG * kH * 4);
    float* vnB  = (float*)alloc((size_t)kG * kH * 4);
    int* counts = (int*)alloc(kG * 4);
    int* starts = (int*)alloc(kG * 4);
    float* stats = (float*)alloc(2 * kH * 4);
    int* cnt_n  = (int*)alloc((size_t)kN * 4);
    int* start_n = (int*)alloc((size_t)(kN + 1) * 4);
    int* fill_n = (int*)alloc((size_t)kN * 4);
    int* bsum   = (int*)alloc((kN / 1024) * 4);
    int* perm   = (int*)alloc((size_t)kE * 4);
    u16* W1f   = (u16*)alloc((size_t)kL * WFRAG_PER_L * 2);   // 2.05 MB fragment-packed gin_W1
    u16* W2f   = (u16*)alloc((size_t)kL * WFRAG_PER_L * 2);   // 2.05 MB fragment-packed gin_W2
    u16* Wt_v1 = (u16*)alloc((size_t)(kL - 1) * NP_H2 * KP_H * 2);
    u16* Wt_v2 = (u16*)alloc((size_t)(kL - 1) * NP_H * KP_H2 * 2);
    u16* Wt_p1 = (u16*)alloc((size_t)NP_H2 * KP_DG * 2);
    if (off > ws_size) return;

    // z1-region overlays (disjoint lifetimes):
    u16* vt_in = z1;                                   // [2048,320] bf16 (pre vn-G1)
    u16* z1v   = z1 + (size_t)4 * 1024 * 1024;         // [2048,640] bf16 (pre vn-G1)
    u16* hrep  = z1;                                   // [2048,1536] bf16 (post layers)
    u16* zp    = z1 + (size_t)8 * 1024 * 1024;         // [2048,640] bf16 (post layers)
    float* vnb[2] = {vnA, vnB};

    // weight packing / transposes
    {
        long tf = (long)kL * WFRAG_PER_L;
        pack_w1_k<<<dim3((unsigned)((tf + 255) / 256)), 256, 0, stream>>>(gin_W1, W1f, tf);
        pack_w2_k<<<dim3((unsigned)((tf + 255) / 256)), 256, 0, stream>>>(gin_W2, W2f, tf);
        long t3 = (long)(kL - 1) * NP_H2 * KP_H;
        transpose_k<<<dim3((unsigned)((t3 + 255) / 256)), 256, 0, stream>>>(vn_W1, Wt_v1, kH, kH2, NP_H2, KP_H, t3);
        long t4 = (long)(kL - 1) * NP_H * KP_H2;
        transpose_k<<<dim3((unsigned)((t4 + 255) / 256)), 256, 0, stream>>>(vn_W2, Wt_v2, kH2, kH, NP_H, KP_H2, t4);
        long t5 = (long)NP_H2 * KP_DG;
        transpose_k<<<dim3((unsigned)((t5 + 255) / 256)), 256, 0, stream>>>(Wp1, Wt_p1, kDG, kH2, NP_H2, KP_DG, t5);
    }

    // graph ranges + node CSR
    hipMemsetAsync(counts, 0, kG * 4, stream);
    hipMemsetAsync(cnt_n, 0, (size_t)kN * 4, stream);
    hipMemsetAsync(fill_n, 0, (size_t)kN * 4, stream);
    hist_g_k<<<kN / 256, 256, 0, stream>>>(batch, counts);
    scan_g_k<<<1, 1024, 0, stream>>>(counts, starts);
    hist_n_k<<<kE / 256, 256, 0, stream>>>(ei, cnt_n);
    scanA_k<<<kN / 1024, 1024, 0, stream>>>(cnt_n, start_n, bsum);
    scanB_k<<<1, 64, 0, stream>>>(bsum);
    scanC_k<<<kN / 1024, 1024, 0, stream>>>(start_n, bsum);
    fill_n_k<<<kE / 256, 256, 0, stream>>>(ei, start_n, fill_n, perm);

    embed_k<<<kN / 4, 256, 0, stream>>>(x, W_emb, b_emb, vn0, (u32*)hvbf);
    vninit_k<<<kG, 320, 0, stream>>>(vn0, vnA);

    for (int l = 0; l < kL; l++) {
        float* vcur = vnb[l & 1];
        float* vnxt = vnb[(l + 1) & 1];
        gather_combine_k<<<kN / 4, 256, 0, stream>>>(
            (const u32*)hvbf, start_n, perm, eps, l, (u32*)hv, stats);
        if (l < kL - 1) {
            vt_fin_k<<<kG / 4, 256, 0, stream>>>(
                (const u32*)hvbf, vcur, counts, starts, (u32*)vt_in);
            gemm_k<1, 1, 0><<<dim3(16, NP_H2 / 128), 256, 0, stream>>>(
                vt_in, Wt_v1 + (size_t)l * NP_H2 * KP_H, vn_b1 + l * kH2,
                z1v, nullptr, KP_H, kH2, KP_H2, KP_H2);
            gemm64_k<0, 2, 0><<<dim3(16, NP_H / 64), 256, 0, stream>>>(
                z1v, Wt_v2 + (size_t)l * NP_H * KP_H2, vn_b2 + l * kH,
                vnxt, nullptr, vcur, KP_H2, kH, kH, kH);
        }
        // fused node MLP v7: dbuf z1c + early phase-B weight issue
        fused_mlp_k<<<kN / 64, 256, 0, stream>>>(
            hv, W1f + (size_t)l * WFRAG_PER_L, gin_b1 + l * kH2,
            W2f + (size_t)l * WFRAG_PER_L, gin_b2 + l * kH,
            hv, stats);
        if (l < kL - 1)
            resid_k<1><<<kN / 4, 256, 0, stream>>>(
                (u32*)hvbf, (const u32*)hv, stats, bn_scale, bn_bias, l, batch, vcur, vnxt);
        else
            resid_k<0><<<kN / 4, 256, 0, stream>>>(
                (u32*)hvbf, (const u32*)hv, stats, bn_scale, bn_bias, l, batch, vcur, vcur);
    }

    float* vnlast = vnb[(kL - 1) & 1];
    pooled_k<<<kG / 4, 256, 0, stream>>>(
        (const u32*)hvbf, vnlast, counts, starts, (u32*)hrep);
    {
        long tr = (long)kG * (KP_DG - kH);
        hrep_rest_k<<<dim3((unsigned)((tr + 255) / 256)), 256, 0, stream>>>(morgan, maccs, counts, hrep);
    }
    gemm_k<1, 1, 0><<<dim3(16, NP_H2 / 128), 256, 0, stream>>>(
        hrep, Wt_p1, bp1, zp, nullptr, KP_DG, kH2, KP_H2, KP_H2);
    final_k<<<kG / 4, 256, 0, stream>>>(zp, Wp2, bp2, out);
}

// Round 14
// 1150.746 us; speedup vs baseline: 1.9110x; 1.0015x over previous
//
#include <hip/hip_runtime.h>

typedef unsigned short u16;
typedef unsigned int u32;
typedef __attribute__((ext_vector_type(8))) short bf16x8_t;
typedef __attribute__((ext_vector_type(4))) float f32x4_t;

// problem constants
#define kN 65536
#define kE 262144
#define kG 2048
#define kH 300
#define kH2 600
#define kL 5
#define kF 32
#define kDG 1523
// padded dims
#define KP_H 320     // K pad of H
#define KP_H2 640    // K pad of 2H
#define KP_DG 1536   // K pad of DG
#define NP_H2 640    // N pad of 2H (128-tiled)
#define NP_H 320     // N pad of H (64-tiled)
// hvbf row stride (u16 / u32)
#define HVS 320
#define HVS32 160
// fragment-packed weight size per layer: 5*4*2*10*64*8 == 5*4*5*4*64*8 == 204800 u16
#define WFRAG_PER_L 204800

__device__ __forceinline__ float bf2f(u16 x) {
    union { u32 u; float f; } v; v.u = ((u32)x) << 16; return v.f;
}
__device__ __forceinline__ u16 f2bf(float f) {
    union { float f; u32 u; } v; v.f = f;
    u32 u = v.u;
    u32 r = (u + 0x7fffu + ((u >> 16) & 1u)) >> 16;  // RNE
    return (u16)r;
}
__device__ __forceinline__ float blo(u32 v) { return bf2f((u16)(v & 0xffffu)); }
__device__ __forceinline__ float bhi(u32 v) { return bf2f((u16)(v >> 16)); }
__device__ __forceinline__ u32 pack2(float lo, float hi) {
    return (u32)f2bf(lo) | ((u32)f2bf(hi) << 16);
}

// async 16B global -> LDS
__device__ __forceinline__ void gld16(const u16* g, u16* l) {
    __builtin_amdgcn_global_load_lds(
        (const __attribute__((address_space(1))) u32*)g,
        (__attribute__((address_space(3))) u32*)l, 16, 0, 0);
}

// counted vmcnt waits + raw barrier
__device__ __forceinline__ void vwait6() { asm volatile("s_waitcnt vmcnt(6)" ::: "memory"); }
__device__ __forceinline__ void vwait8() { asm volatile("s_waitcnt vmcnt(8)" ::: "memory"); }
__device__ __forceinline__ void vwait0() { asm volatile("s_waitcnt vmcnt(0)" ::: "memory"); }
__device__ __forceinline__ void lwait0() { asm volatile("s_waitcnt lgkmcnt(0)" ::: "memory"); }
__device__ __forceinline__ void rbar() {
    __builtin_amdgcn_sched_barrier(0);
    __builtin_amdgcn_s_barrier();
    __builtin_amdgcn_sched_barrier(0);
}

// XCD-bijective tile swizzle (requires gridDim.x % 8 == 0; holds: 16).
__device__ __forceinline__ void swz_tile(int& m, int& n) {
    int p = blockIdx.x + gridDim.x * blockIdx.y;
    int xcd = p & 7;
    int q = p >> 3;
    int NB = gridDim.y;
    int mb8 = gridDim.x >> 3;
    m = xcd * mb8 + q / NB;
    n = q % NB;
}

// ---------------- weight transpose: W[b][k][n] (f32) -> Wt[b][n][k] (bf16), zero-padded ----------------
__global__ void transpose_k(const float* __restrict__ W, u16* __restrict__ Wt,
                            int K, int NN, int NP, int KP, long total) {
    long idx = (long)blockIdx.x * 256 + threadIdx.x;
    if (idx >= total) return;
    int per = NP * KP;
    int b = (int)(idx / per);
    int r = (int)(idx % per);
    int n = r / KP;
    int k = r % KP;
    u16 v = 0;
    if (n < NN && k < K) v = f2bf(W[(long)b * K * NN + (long)k * NN + n]);
    Wt[idx] = v;
}

// ---------------- fragment-pack W1 (gin_W1 [L][300][600]) -> W1f [L][c][w][nt][tk][lane][8] ----------------
__global__ void pack_w1_k(const float* __restrict__ W, u16* __restrict__ Wf, long total) {
    long idx = (long)blockIdx.x * 256 + threadIdx.x;
    if (idx >= total) return;
    int l = (int)(idx / WFRAG_PER_L);
    long r = idx % WFRAG_PER_L;
    int e = (int)(r & 7);
    long r1 = r >> 3;
    int ln = (int)(r1 & 63);
    int l16 = ln & 15, quad = ln >> 4;
    long s = r1 >> 6;
    int tk = (int)(s % 10);
    long s2 = s / 10;
    int nt = (int)(s2 & 1);
    long s3 = s2 >> 1;
    int w = (int)(s3 & 3);
    int c = (int)(s3 >> 2);
    int n = c * 128 + w * 32 + nt * 16 + l16;
    int k = tk * 32 + quad * 8 + e;
    u16 v = 0;
    if (n < kH2 && k < kH) v = f2bf(W[(long)l * kH * kH2 + (long)k * kH2 + n]);
    Wf[idx] = v;
}

// ---------------- fragment-pack W2 (gin_W2 [L][600][300]) -> W2f [L][c][w][nt][ks][lane][8] ----------------
__global__ void pack_w2_k(const float* __restrict__ W, u16* __restrict__ Wf, long total) {
    long idx = (long)blockIdx.x * 256 + threadIdx.x;
    if (idx >= total) return;
    int l = (int)(idx / WFRAG_PER_L);
    long r = idx % WFRAG_PER_L;
    int e = (int)(r & 7);
    long r1 = r >> 3;
    int ln = (int)(r1 & 63);
    int l16 = ln & 15, quad = ln >> 4;
    long s = r1 >> 6;
    int ks = (int)(s & 3);
    long s2 = s >> 2;
    int nt = (int)(s2 % 5);
    long s3 = s2 / 5;
    int w = (int)(s3 & 3);
    int c = (int)(s3 >> 2);
    int n = w * 80 + nt * 16 + l16;
    int k = c * 128 + ks * 32 + quad * 8 + e;
    u16 v = 0;
    if (n < kH && k < kH2) v = f2bf(W[(long)l * kH2 * kH + (long)k * kH + n]);
    Wf[idx] = v;
}

// ---------------- graph histogram + scan ----------------
__global__ void hist_g_k(const int* __restrict__ batch, int* __restrict__ counts) {
    int n = blockIdx.x * 256 + threadIdx.x;
    if (n < kN) atomicAdd(&counts[batch[n]], 1);
}

__global__ void scan_g_k(const int* __restrict__ counts, int* __restrict__ starts) {
    __shared__ int s[1024];
    int t = threadIdx.x;
    int c0 = counts[2 * t], c1 = counts[2 * t + 1];
    s[t] = c0 + c1;
    __syncthreads();
    for (int off = 1; off < 1024; off <<= 1) {
        int v = (t >= off) ? s[t - off] : 0;
        __syncthreads();
        s[t] += v;
        __syncthreads();
    }
    int excl = (t > 0) ? s[t - 1] : 0;
    starts[2 * t] = excl;
    starts[2 * t + 1] = excl + c0;
}

// ---------------- node CSR build ----------------
__global__ void hist_n_k(const int* __restrict__ ei, int* __restrict__ cnt) {
    int e = blockIdx.x * 256 + threadIdx.x;
    if (e < kE) atomicAdd(&cnt[ei[kE + e]], 1);
}

__global__ void scanA_k(const int* __restrict__ cnt, int* __restrict__ start, int* __restrict__ bsum) {
    __shared__ int s[1024];
    int b = blockIdx.x, t = threadIdx.x;
    int v = cnt[b * 1024 + t];
    s[t] = v;
    __syncthreads();
    for (int off = 1; off < 1024; off <<= 1) {
        int u = (t >= off) ? s[t - off] : 0;
        __syncthreads();
        s[t] += u;
        __syncthreads();
    }
    start[b * 1024 + t] = s[t] - v;
    if (t == 1023) bsum[b] = s[1023];
}

__global__ void scanB_k(int* __restrict__ bsum) {
    if (threadIdx.x == 0) {
        int s = 0;
        for (int i = 0; i < kN / 1024; i++) { s += bsum[i]; bsum[i] = s; }
    }
}

__global__ void scanC_k(int* __restrict__ start, const int* __restrict__ bsum) {
    int b = blockIdx.x, t = threadIdx.x;
    int add = (b > 0) ? bsum[b - 1] : 0;
    start[b * 1024 + t] += add;
    if (b == kN / 1024 - 1 && t == 1023) start[kN] = bsum[kN / 1024 - 1];
}

__global__ void fill_n_k(const int* __restrict__ ei, const int* __restrict__ start,
                         int* __restrict__ fill, int* __restrict__ perm) {
    int e = blockIdx.x * 256 + threadIdx.x;
    if (e >= kE) return;
    int s = ei[e], d = ei[kE + e];
    int pos = start[d] + atomicAdd(&fill[d], 1);
    perm[pos] = s;
}

// ---------------- node embedding: hvbf = bf16(x@W+b + vn0) ----------------
__global__ __launch_bounds__(256) void embed_k(
    const float* __restrict__ x, const float* __restrict__ W,
    const float* __restrict__ b, const float* __restrict__ vn0,
    u32* __restrict__ hv32) {
    __shared__ float sW[9 * kH];
    __shared__ float sBV[kH];
    int tid = threadIdx.x;
    for (int i = tid; i < 9 * kH; i += 256) sW[i] = W[i];
    for (int i = tid; i < kH; i += 256) sBV[i] = b[i] + vn0[i];
    __syncthreads();
    int wave = tid >> 6, lane = tid & 63;
    int n = blockIdx.x * 4 + wave;
    float xv[9];
    #pragma unroll
    for (int d = 0; d < 9; d++) xv[d] = x[n * 9 + d];
    #pragma unroll
    for (int p = 0; p < 3; p++) {
        int ii = lane + p * 64;
        if (ii < 150) {
            int c0 = 2 * ii;
            float a0 = sBV[c0], a1 = sBV[c0 + 1];
            #pragma unroll
            for (int d = 0; d < 9; d++) {
                a0 += xv[d] * sW[d * kH + c0];
                a1 += xv[d] * sW[d * kH + c0 + 1];
            }
            hv32[(long)n * HVS32 + ii] = pack2(a0, a1);
        } else if (ii < HVS32) {
            hv32[(long)n * HVS32 + ii] = 0u;
        }
    }
}

__global__ void vninit_k(const float* __restrict__ vn0, float* __restrict__ vn) {
    int g = blockIdx.x, c = threadIdx.x;
    if (c < kH) vn[g * kH + c] = vn0[c];
}

// ---------------- gather + combine ----------------
__global__ __launch_bounds__(256) void gather_combine_k(
    const u32* __restrict__ hv32, const int* __restrict__ start_n,
    const int* __restrict__ perm, const float* __restrict__ eps, int l,
    u32* __restrict__ out32, float* __restrict__ stats) {
    int tid = threadIdx.x;
    int wave = tid >> 6, lane = tid & 63;
    int n = blockIdx.x * 4 + wave;
    int st = start_n[n], en = start_n[n + 1];
    int i0 = lane, i1 = lane + 64, i2 = lane + 128;
    bool p2 = (i2 < 150);
    float a0 = 0.f, b0 = 0.f, a1 = 0.f, b1 = 0.f, a2 = 0.f, b2 = 0.f;
    int e = st;
    for (; e + 4 <= en; e += 4) {
        const u32* rA = hv32 + (long)perm[e] * HVS32;
        const u32* rB = hv32 + (long)perm[e + 1] * HVS32;
        const u32* rC = hv32 + (long)perm[e + 2] * HVS32;
        const u32* rD = hv32 + (long)perm[e + 3] * HVS32;
        u32 vA0 = rA[i0], vA1 = rA[i1], vA2 = p2 ? rA[i2] : 0u;
        u32 vB0 = rB[i0], vB1 = rB[i1], vB2 = p2 ? rB[i2] : 0u;
        u32 vC0 = rC[i0], vC1 = rC[i1], vC2 = p2 ? rC[i2] : 0u;
        u32 vD0 = rD[i0], vD1 = rD[i1], vD2 = p2 ? rD[i2] : 0u;
        a0 += (blo(vA0) + blo(vB0)) + (blo(vC0) + blo(vD0));
        b0 += (bhi(vA0) + bhi(vB0)) + (bhi(vC0) + bhi(vD0));
        a1 += (blo(vA1) + blo(vB1)) + (blo(vC1) + blo(vD1));
        b1 += (bhi(vA1) + bhi(vB1)) + (bhi(vC1) + bhi(vD1));
        a2 += (blo(vA2) + blo(vB2)) + (blo(vC2) + blo(vD2));
        b2 += (bhi(vA2) + bhi(vB2)) + (bhi(vC2) + bhi(vD2));
    }
    for (; e + 2 <= en; e += 2) {
        const u32* rA = hv32 + (long)perm[e] * HVS32;
        const u32* rB = hv32 + (long)perm[e + 1] * HVS32;
        u32 vA0 = rA[i0], vA1 = rA[i1], vA2 = p2 ? rA[i2] : 0u;
        u32 vB0 = rB[i0], vB1 = rB[i1], vB2 = p2 ? rB[i2] : 0u;
        a0 += blo(vA0) + blo(vB0); b0 += bhi(vA0) + bhi(vB0);
        a1 += blo(vA1) + blo(vB1); b1 += bhi(vA1) + bhi(vB1);
        a2 += blo(vA2) + blo(vB2); b2 += bhi(vA2) + bhi(vB2);
    }
    if (e < en) {
        const u32* rA = hv32 + (long)perm[e] * HVS32;
        u32 vA0 = rA[i0], vA1 = rA[i1], vA2 = p2 ? rA[i2] : 0u;
        a0 += blo(vA0); b0 += bhi(vA0);
        a1 += blo(vA1); b1 += bhi(vA1);
        a2 += blo(vA2); b2 += bhi(vA2);
    }
    const u32* self = hv32 + (long)n * HVS32;
    float ep = 1.f + eps[l];
    u32 s0 = self[i0], s1 = self[i1];
    u32* o = out32 + (long)n * HVS32;
    o[i0] = pack2(ep * blo(s0) + a0, ep * bhi(s0) + b0);
    o[i1] = pack2(ep * blo(s1) + a1, ep * bhi(s1) + b1);
    if (p2) {
        u32 s2 = self[i2];
        o[i2] = pack2(ep * blo(s2) + a2, ep * bhi(s2) + b2);
    } else if (i2 < HVS32) {
        o[i2] = 0u;
    }
    int gz = blockIdx.x * 256 + tid;
    if (gz < 2 * kH) stats[gz] = 0.f;
}

// ---------------- vt (wave per graph): vt[g] = sum_rows hvbf + vn_cur[g] ----------------
__global__ __launch_bounds__(256) void vt_fin_k(
    const u32* __restrict__ hv32, const float* __restrict__ vncur,
    const int* __restrict__ counts, const int* __restrict__ starts,
    u32* __restrict__ vt32) {
    int tid = threadIdx.x, wave = tid >> 6, lane = tid & 63;
    int g = blockIdx.x * 4 + wave;
    int cnt = counts[g], st = starts[g];
    int i0 = lane, i1 = lane + 64, i2 = lane + 128;
    bool p2 = (i2 < 150);
    float a0 = 0.f, b0 = 0.f, a1 = 0.f, b1 = 0.f, a2 = 0.f, b2 = 0.f;
    int i = 0;
    for (; i + 4 <= cnt; i += 4) {
        const u32* rA = hv32 + (long)(st + i) * HVS32;
        const u32* rB = hv32 + (long)(st + i + 1) * HVS32;
        const u32* rC = hv32 + (long)(st + i + 2) * HVS32;
        const u32* rD = hv32 + (long)(st + i + 3) * HVS32;
        u32 vA0 = rA[i0], vA1 = rA[i1], vA2 = p2 ? rA[i2] : 0u;
        u32 vB0 = rB[i0], vB1 = rB[i1], vB2 = p2 ? rB[i2] : 0u;
        u32 vC0 = rC[i0], vC1 = rC[i1], vC2 = p2 ? rC[i2] : 0u;
        u32 vD0 = rD[i0], vD1 = rD[i1], vD2 = p2 ? rD[i2] : 0u;
        a0 += (blo(vA0) + blo(vB0)) + (blo(vC0) + blo(vD0));
        b0 += (bhi(vA0) + bhi(vB0)) + (bhi(vC0) + bhi(vD0));
        a1 += (blo(vA1) + blo(vB1)) + (blo(vC1) + blo(vD1));
        b1 += (bhi(vA1) + bhi(vB1)) + (bhi(vC1) + bhi(vD1));
        a2 += (blo(vA2) + blo(vB2)) + (blo(vC2) + blo(vD2));
        b2 += (bhi(vA2) + bhi(vB2)) + (bhi(vC2) + bhi(vD2));
    }
    for (; i < cnt; i++) {
        const u32* rA = hv32 + (long)(st + i) * HVS32;
        u32 vA0 = rA[i0], vA1 = rA[i1], vA2 = p2 ? rA[i2] : 0u;
        a0 += blo(vA0); b0 += bhi(vA0);
        a1 += blo(vA1); b1 += bhi(vA1);
        a2 += blo(vA2); b2 += bhi(vA2);
    }
    const float* vg = vncur + g * kH;
    vt32[(long)g * HVS32 + i0] = pack2(a0 + vg[2 * i0], b0 + vg[2 * i0 + 1]);
    vt32[(long)g * HVS32 + i1] = pack2(a1 + vg[2 * i1], b1 + vg[2 * i1 + 1]);
    if (p2) vt32[(long)g * HVS32 + i2] = pack2(a2 + vg[2 * i2], b2 + vg[2 * i2 + 1]);
    else if (i2 < HVS32) vt32[(long)g * HVS32 + i2] = 0u;
}

// ---------------- FUSED node MLP v8: v7 + s_setprio around MFMA clusters (T5) ----------------
// 256 thr / 64-row strip, 2 blocks/CU. dbuf z1c (1 barrier/chunk), early phase-B weight
// issue; setprio(1) favors MFMA-entering waves over the co-resident block's load phases.
__global__ __launch_bounds__(256, 2) void fused_mlp_k(
    const u16* __restrict__ A,      // hv [kN x 320] bf16
    const u16* __restrict__ W1f,    // fragment-packed [5][4][2][10][64][8]
    const float* __restrict__ b1,   // [600]
    const u16* __restrict__ W2f,    // fragment-packed [5][4][5][4][64][8]
    const float* __restrict__ b2,   // [300]
    u16* __restrict__ outp,         // hv (in-place)
    float* __restrict__ stats) {
    __shared__ __align__(16) u16 lA[5][64 * 64];    // 40 KB persistent A strip
    __shared__ __align__(16) u16 z1c[2][64 * 128];  // 32 KB z1 chunk dbuf, XOR swizzle
    __shared__ float sred[320][2];                  // 2.5 KB BN partial sums

    const int tid = threadIdx.x;
    const int lane = tid & 63;
    const int wave = tid >> 6;      // 0..3
    const int l16 = lane & 15;
    const int quad = lane >> 4;
    const long tm = (long)blockIdx.x * 64;
    const int srow = lane >> 3;
    const int sch = (lane & 7) ^ srow;

    for (int i = tid; i < 320; i += 256) { sred[i][0] = 0.f; sred[i][1] = 0.f; }

    // stage the whole A strip once (5 k-tiles x 64 rows)
    #pragma unroll
    for (int t = 0; t < 5; t++) {
        #pragma unroll
        for (int j = 0; j < 2; j++) {
            int rb = wave * 16 + j * 8;
            gld16(A + (tm + rb + srow) * KP_H + t * 64 + sch * 8, &lA[t][rb * 64]);
        }
    }

    // preload biases (compile-time indexed after full unroll)
    float rb1[5][2];
    #pragma unroll
    for (int c = 0; c < 5; c++)
        #pragma unroll
        for (int nt = 0; nt < 2; nt++) {
            int gc = c * 128 + wave * 32 + nt * 16 + l16;
            rb1[c][nt] = (gc < kH2) ? b1[gc] : 0.f;
        }
    float rb2[5];
    #pragma unroll
    for (int nt = 0; nt < 5; nt++) {
        int col = wave * 80 + nt * 16 + l16;
        rb2[nt] = (col < kH) ? b2[col] : 0.f;
    }

    f32x4_t acc2[4][5];
    #pragma unroll
    for (int i = 0; i < 4; i++)
        #pragma unroll
        for (int j = 0; j < 5; j++) acc2[i][j] = (f32x4_t){0.f, 0.f, 0.f, 0.f};

    vwait0();
    rbar();  // A strip staged; sred zeroed

    #pragma unroll
    for (int c = 0; c < 5; c++) {
        // ---------- phase A (barrier-free): z1 chunk = A @ W1 chunk ----------
        f32x4_t acc1[4][2];
        #pragma unroll
        for (int i = 0; i < 4; i++) {
            acc1[i][0] = (f32x4_t){0.f, 0.f, 0.f, 0.f};
            acc1[i][1] = (f32x4_t){0.f, 0.f, 0.f, 0.f};
        }
        // fragment base for (c, wave): [((c*4+w)*2+nt)*10 + tk] frames of 512 u16
        const u16* w1p = W1f + ((long)((c * 4 + wave) * 2) * 10) * 512 + lane * 8;
        bf16x8_t wf[4][2];
        #pragma unroll
        for (int p = 0; p < 3; p++) {   // preload tk=0..2 (distance-3 rotation)
            wf[p][0] = *(const bf16x8_t*)(w1p + p * 512);
            wf[p][1] = *(const bf16x8_t*)(w1p + 10 * 512 + p * 512);
        }
        #pragma unroll
        for (int tk = 0; tk < 10; tk++) {
            if (tk + 3 < 10) {          // prefetch tk+3 into slot (tk+3)&3 != tk&3
                wf[(tk + 3) & 3][0] = *(const bf16x8_t*)(w1p + (tk + 3) * 512);
                wf[(tk + 3) & 3][1] = *(const bf16x8_t*)(w1p + 10 * 512 + (tk + 3) * 512);
            }
            const int t = tk >> 1, ks = tk & 1;
            bf16x8_t af[4];
            #pragma unroll
            for (int mt = 0; mt < 4; mt++) {
                int row = mt * 16 + l16;
                int phys = (ks * 4 + quad) ^ (l16 & 7);
                af[mt] = *(const bf16x8_t*)&lA[t][row * 64 + phys * 8];
            }
            __builtin_amdgcn_s_setprio(1);
            #pragma unroll
            for (int mt = 0; mt < 4; mt++) {
                acc1[mt][0] = __builtin_amdgcn_mfma_f32_16x16x32_bf16(af[mt], wf[tk & 3][0], acc1[mt][0], 0, 0, 0);
                acc1[mt][1] = __builtin_amdgcn_mfma_f32_16x16x32_bf16(af[mt], wf[tk & 3][1], acc1[mt][1], 0, 0, 0);
            }
            __builtin_amdgcn_s_setprio(0);
        }

        // issue phase-B ks=0,1 weights NOW — latency hides under handoff + barrier
        const u16* w2p = W2f + ((long)((c * 4 + wave) * 5) * 4) * 512 + lane * 8;
        bf16x8_t wg[2][5];
        #pragma unroll
        for (int nt = 0; nt < 5; nt++) {
            wg[0][nt] = *(const bf16x8_t*)(w2p + nt * 4 * 512);
            wg[1][nt] = *(const bf16x8_t*)(w2p + nt * 4 * 512 + 512);
        }

        // ---------- z1c handoff into buf[c&1] (no leading barrier needed: dbuf) ----------
        u16* zb = z1c[c & 1];
        #pragma unroll
        for (int nt = 0; nt < 2; nt++) {
            int col = wave * 32 + nt * 16 + l16;
            #pragma unroll
            for (int mt = 0; mt < 4; mt++) {
                #pragma unroll
                for (int r = 0; r < 4; r++) {
                    int row = mt * 16 + quad * 4 + r;
                    float v = fmaxf(acc1[mt][nt][r] + rb1[c][nt], 0.f);
                    int phys = (col >> 3) ^ (row & 15);
                    zb[row * 128 + phys * 8 + (col & 7)] = f2bf(v);
                }
            }
        }
        lwait0();
        rbar();  // z1c[c&1] visible to all waves (also orders next chunk's writes)

        // ---------- phase B (barrier-free): acc2 += z1c[c&1] @ W2 chunk ----------
        #pragma unroll
        for (int ks = 0; ks < 4; ks++) {
            bf16x8_t af[4];
            #pragma unroll
            for (int mt = 0; mt < 4; mt++) {
                int row = mt * 16 + l16;
                int phys = (ks * 4 + quad) ^ (row & 15);
                af[mt] = *(const bf16x8_t*)&zb[row * 128 + phys * 8];
            }
            __builtin_amdgcn_s_setprio(1);
            #pragma unroll
            for (int mt = 0; mt < 4; mt++)
                #pragma unroll
                for (int nt = 0; nt < 5; nt++)
                    acc2[mt][nt] = __builtin_amdgcn_mfma_f32_16x16x32_bf16(af[mt], wg[ks & 1][nt], acc2[mt][nt], 0, 0, 0);
            __builtin_amdgcn_s_setprio(0);
            if (ks + 2 < 4) {  // refill consumed slot with ks+2 (full-iteration latency cover)
                #pragma unroll
                for (int nt = 0; nt < 5; nt++)
                    wg[ks & 1][nt] = *(const bf16x8_t*)(w2p + nt * 4 * 512 + (ks + 2) * 512);
            }
        }
    }

    // ---------- epilogue: bias, bf16 store (in-place), BN stats ----------
    #pragma unroll
    for (int nt = 0; nt < 5; nt++) {
        int col = wave * 80 + nt * 16 + l16;
        float s = 0.f, s2 = 0.f;
        #pragma unroll
        for (int mt = 0; mt < 4; mt++) {
            #pragma unroll
            for (int r = 0; r < 4; r++) {
                long row = tm + mt * 16 + quad * 4 + r;
                float v = acc2[mt][nt][r] + rb2[nt];
                float sv = (col < kH) ? v : 0.f;
                outp[row * KP_H + col] = f2bf(sv);
                s += sv; s2 += sv * sv;
            }
        }
        atomicAdd(&sred[col][0], s);
        atomicAdd(&sred[col][1], s2);
    }
    __syncthreads();
    for (int i = tid; i < kH; i += 256) {
        atomicAdd(&stats[i], sred[i][0]);
        atomicAdd(&stats[kH + i], sred[i][1]);
    }
}

// ---------------- GEMM: 128x128 tile, BK=64, counted-vmcnt double-buffered pipeline ----------------
template<int ACT, int OUT_BF16, int BN_STATS>
__global__ __launch_bounds__(256) void gemm_k(
    const u16* __restrict__ A, const u16* __restrict__ Wt,
    const float* __restrict__ bias, void* __restrict__ out,
    float* __restrict__ stats,
    int KP, int NN, int out_stride, int store_cols) {
    __shared__ __align__(16) u16 lA[2][128 * 64];
    __shared__ __align__(16) u16 lB[2][128 * 64];
    __shared__ float sred[128][2];

    const int tid = threadIdx.x;
    const int lane = tid & 63;
    const int wave = tid >> 6;
    const int l16 = lane & 15;
    const int quad = lane >> 4;
    const int wm = (wave & 1) * 64;
    const int wn = (wave >> 1) * 64;
    int sm, sn;
    swz_tile(sm, sn);
    const long tm = (long)sm * 128;
    const int tn = sn * 128;

    const int srow = lane >> 3;
    const int sch = (lane & 7) ^ srow;

    f32x4_t acc[4][4];
    #pragma unroll
    for (int i = 0; i < 4; i++)
        #pragma unroll
        for (int j = 0; j < 4; j++) acc[i][j] = (f32x4_t){0.f, 0.f, 0.f, 0.f};

    auto stage = [&](int bb, int k0) {  // 8 VMEM per wave
        #pragma unroll
        for (int j = 0; j < 4; j++) {
            int rb = wave * 32 + j * 8;
            int r = rb + srow;
            gld16(A + (tm + r) * KP + k0 + sch * 8, &lA[bb][rb * 64]);
            gld16(Wt + (long)(tn + r) * KP + k0 + sch * 8, &lB[bb][rb * 64]);
        }
    };

    const int nk = KP >> 6;
    stage(0, 0);
    if (nk > 1) stage(1, 64);
    for (int t = 0; t < nk; t++) {
        if (t < nk - 1) vwait8(); else vwait0();
        rbar();
        const u16* la = lA[t & 1];
        const u16* lb = lB[t & 1];
        #pragma unroll
        for (int ks = 0; ks < 2; ks++) {
            bf16x8_t af[4], bfr[4];
            #pragma unroll
            for (int mt = 0; mt < 4; mt++) {
                int row = wm + mt * 16 + l16;
                int phys = (ks * 4 + quad) ^ (l16 & 7);
                af[mt] = *(const bf16x8_t*)&la[row * 64 + phys * 8];
            }
            #pragma unroll
            for (int nt = 0; nt < 4; nt++) {
                int row = wn + nt * 16 + l16;
                int phys = (ks * 4 + quad) ^ (l16 & 7);
                bfr[nt] = *(const bf16x8_t*)&lb[row * 64 + phys * 8];
            }
            #pragma unroll
            for (int mt = 0; mt < 4; mt++)
                #pragma unroll
                for (int nt = 0; nt < 4; nt++)
                    acc[mt][nt] = __builtin_amdgcn_mfma_f32_16x16x32_bf16(af[mt], bfr[nt], acc[mt][nt], 0, 0, 0);
        }
        rbar();
        if (t + 2 < nk) stage(t & 1, (t + 2) * 64);
    }

    if (BN_STATS) {
        if (tid < 128) { sred[tid][0] = 0.f; sred[tid][1] = 0.f; }
    }
    __syncthreads();

    #pragma unroll
    for (int nt = 0; nt < 4; nt++) {
        int col = tn + wn + nt * 16 + l16;
        float bv = (col < NN) ? bias[col] : 0.f;
        float s = 0.f, s2 = 0.f;
        #pragma unroll
        for (int mt = 0; mt < 4; mt++) {
            #pragma unroll
            for (int r = 0; r < 4; r++) {
                long row = tm + wm + mt * 16 + quad * 4 + r;
                float v = acc[mt][nt][r] + bv;
                if (ACT) v = fmaxf(v, 0.f);
                float sv = (col < NN) ? v : 0.f;
                if (col < store_cols) {
                    if (OUT_BF16) ((u16*)out)[row * out_stride + col] = f2bf(sv);
                    else          ((float*)out)[row * out_stride + col] = sv;
                }
                s += sv; s2 += sv * sv;
            }
        }
        if (BN_STATS) {
            atomicAdd(&sred[wn + nt * 16 + l16][0], s);
            atomicAdd(&sred[wn + nt * 16 + l16][1], s2);
        }
    }
    if (BN_STATS) {
        __syncthreads();
        if (tid < 128) {
            int col = tn + tid;
            if (col < NN) {
                atomicAdd(&stats[col], sred[tid][0]);
                atomicAdd(&stats[NN + col], sred[tid][1]);
            }
        }
    }
}

// ---------------- GEMM64: 128x64 tile; OUT_MODE: 0=f32, 1=bf16, 2=vn_nxt = vn_cur + relu(v) ----------------
template<int ACT, int OUT_MODE, int BN_STATS>
__global__ __launch_bounds__(256) void gemm64_k(
    const u16* __restrict__ A, const u16* __restrict__ Wt,
    const float* __restrict__ bias, void* __restrict__ out,
    float* __restrict__ stats, const float* __restrict__ vnacc,
    int KP, int NN, int out_stride, int store_cols) {
    __shared__ __align__(16) u16 lA[2][128 * 64];
    __shared__ __align__(16) u16 lB[2][64 * 64];
    __shared__ float sred[64][2];

    const int tid = threadIdx.x;
    const int lane = tid & 63;
    const int wave = tid >> 6;
    const int l16 = lane & 15;
    const int quad = lane >> 4;
    const int wm = (wave & 1) * 64;
    const int wn = (wave >> 1) * 32;
    int sm, sn;
    swz_tile(sm, sn);
    const long tm = (long)sm * 128;
    const int tn = sn * 64;

    const int srow = lane >> 3;
    const int sch = (lane & 7) ^ srow;

    f32x4_t acc[4][2];
    #pragma unroll
    for (int i = 0; i < 4; i++)
        #pragma unroll
        for (int j = 0; j < 2; j++) acc[i][j] = (f32x4_t){0.f, 0.f, 0.f, 0.f};

    auto stage = [&](int bb, int k0) {  // 6 VMEM per wave
        #pragma unroll
        for (int j = 0; j < 4; j++) {
            int rb = wave * 32 + j * 8;
            gld16(A + (tm + rb + srow) * KP + k0 + sch * 8, &lA[bb][rb * 64]);
        }
        #pragma unroll
        for (int j = 0; j < 2; j++) {
            int rb = wave * 16 + j * 8;
            gld16(Wt + (long)(tn + rb + srow) * KP + k0 + sch * 8, &lB[bb][rb * 64]);
        }
    };

    const int nk = KP >> 6;
    stage(0, 0);
    if (nk > 1) stage(1, 64);
    for (int t = 0; t < nk; t++) {
        if (t < nk - 1) vwait6(); else vwait0();
        rbar();
        const u16* la = lA[t & 1];
        const u16* lb = lB[t & 1];
        #pragma unroll
        for (int ks = 0; ks < 2; ks++) {
            bf16x8_t af[4], bfr[2];
            #pragma unroll
            for (int mt = 0; mt < 4; mt++) {
                int row = wm + mt * 16 + l16;
                int phys = (ks * 4 + quad) ^ (l16 & 7);
                af[mt] = *(const bf16x8_t*)&la[row * 64 + phys * 8];
            }
            #pragma unroll
            for (int nt = 0; nt < 2; nt++) {
                int row = wn + nt * 16 + l16;
                int phys = (ks * 4 + quad) ^ (l16 & 7);
                bfr[nt] = *(const bf16x8_t*)&lb[row * 64 + phys * 8];
            }
            #pragma unroll
            for (int mt = 0; mt < 4; mt++)
                #pragma unroll
                for (int nt = 0; nt < 2; nt++)
                    acc[mt][nt] = __builtin_amdgcn_mfma_f32_16x16x32_bf16(af[mt], bfr[nt], acc[mt][nt], 0, 0, 0);
        }
        rbar();
        if (t + 2 < nk) stage(t & 1, (t + 2) * 64);
    }

    if (BN_STATS) {
        if (tid < 64) { sred[tid][0] = 0.f; sred[tid][1] = 0.f; }
    }
    __syncthreads();

    #pragma unroll
    for (int nt = 0; nt < 2; nt++) {
        int col = tn + wn + nt * 16 + l16;
        float bv = (col < NN) ? bias[col] : 0.f;
        float s = 0.f, s2 = 0.f;
        #pragma unroll
        for (int mt = 0; mt < 4; mt++) {
            #pragma unroll
            for (int r = 0; r < 4; r++) {
                long row = tm + wm + mt * 16 + quad * 4 + r;
                float v = acc[mt][nt][r] + bv;
                if (ACT) v = fmaxf(v, 0.f);
                float sv = (col < NN) ? v : 0.f;
                if (col < store_cols) {
                    if (OUT_MODE == 1) ((u16*)out)[row * out_stride + col] = f2bf(sv);
                    else if (OUT_MODE == 2)
                        ((float*)out)[row * out_stride + col] =
                            vnacc[row * out_stride + col] + fmaxf(v, 0.f);
                    else ((float*)out)[row * out_stride + col] = sv;
                }
                s += sv; s2 += sv * sv;
            }
        }
        if (BN_STATS) {
            atomicAdd(&sred[wn + nt * 16 + l16][0], s);
            atomicAdd(&sred[wn + nt * 16 + l16][1], s2);
        }
    }
    if (BN_STATS) {
        __syncthreads();
        if (tid < 64) {
            int col = tn + tid;
            if (col < NN) {
                atomicAdd(&stats[col], sred[tid][0]);
                atomicAdd(&stats[NN + col], sred[tid][1]);
            }
        }
    }
}

// ---------------- BN-apply + (relu) + residual ----------------
template<int RELU>
__global__ __launch_bounds__(256) void resid_k(
    u32* __restrict__ hvb32, const u32* __restrict__ z32,
    const float* __restrict__ stats,
    const float* __restrict__ scale, const float* __restrict__ bias, int l,
    const int* __restrict__ batch,
    const float* __restrict__ vncur, const float* __restrict__ vnnxt) {
    int tid = threadIdx.x;
    int wave = tid >> 6, lane = tid & 63;
    int n = blockIdx.x * 4 + wave;
    int g = batch[n];
    #pragma unroll
    for (int p = 0; p < 3; p++) {
        int ii = lane + p * 64;
        if (ii >= 150) break;
        int c0 = 2 * ii;
        float m0 = stats[c0] * (1.f / (float)kN), m1 = stats[c0 + 1] * (1.f / (float)kN);
        float v0 = fmaxf(stats[kH + c0] * (1.f / (float)kN) - m0 * m0, 0.f);
        float v1 = fmaxf(stats[kH + c0 + 1] * (1.f / (float)kN) - m1 * m1, 0.f);
        float a0 = scale[l * kH + c0] * rsqrtf(v0 + 1e-5f);
        float a1 = scale[l * kH + c0 + 1] * rsqrtf(v1 + 1e-5f);
        float d0 = bias[l * kH + c0] - m0 * a0;
        float d1 = bias[l * kH + c0 + 1] - m1 * a1;
        u32 zz = z32[(long)n * HVS32 + ii];
        u32 ho = hvb32[(long)n * HVS32 + ii];
        float2 vc = *(const float2*)(vncur + g * kH + c0);
        float2 vx = *(const float2*)(vnnxt + g * kH + c0);
        float t0 = blo(zz) * a0 + d0;
        float t1 = bhi(zz) * a1 + d1;
        if (RELU) { t0 = fmaxf(t0, 0.f); t1 = fmaxf(t1, 0.f); }
        float h0 = (blo(ho) - vc.x) + t0;
        float h1 = (bhi(ho) - vc.y) + t1;
        hvb32[(long)n * HVS32 + ii] = pack2(h0 + vx.x, h1 + vx.y);
    }
}

// ---------------- pooled mean (wave per graph) ----------------
__global__ __launch_bounds__(256) void pooled_k(
    const u32* __restrict__ hv32, const float* __restrict__ vnlast,
    const int* __restrict__ counts, const int* __restrict__ starts,
    u32* __restrict__ hrep32) {
    int tid = threadIdx.x, wave = tid >> 6, lane = tid & 63;
    int g = blockIdx.x * 4 + wave;
    int cnt = counts[g], st = starts[g];
    int i0 = lane, i1 = lane + 64, i2 = lane + 128;
    bool p2 = (i2 < 150);
    float a0 = 0.f, b0 = 0.f, a1 = 0.f, b1 = 0.f, a2 = 0.f, b2 = 0.f;
    int i = 0;
    for (; i + 4 <= cnt; i += 4) {
        const u32* rA = hv32 + (long)(st + i) * HVS32;
        const u32* rB = hv32 + (long)(st + i + 1) * HVS32;
        const u32* rC = hv32 + (long)(st + i + 2) * HVS32;
        const u32* rD = hv32 + (long)(st + i + 3) * HVS32;
        u32 vA0 = rA[i0], vA1 = rA[i1], vA2 = p2 ? rA[i2] : 0u;
        u32 vB0 = rB[i0], vB1 = rB[i1], vB2 = p2 ? rB[i2] : 0u;
        u32 vC0 = rC[i0], vC1 = rC[i1], vC2 = p2 ? rC[i2] : 0u;
        u32 vD0 = rD[i0], vD1 = rD[i1], vD2 = p2 ? rD[i2] : 0u;
        a0 += (blo(vA0) + blo(vB0)) + (blo(vC0) + blo(vD0));
        b0 += (bhi(vA0) + bhi(vB0)) + (bhi(vC0) + bhi(vD0));
        a1 += (blo(vA1) + blo(vB1)) + (blo(vC1) + blo(vD1));
        b1 += (bhi(vA1) + bhi(vB1)) + (bhi(vC1) + bhi(vD1));
        a2 += (blo(vA2) + blo(vB2)) + (blo(vC2) + blo(vD2));
        b2 += (bhi(vA2) + bhi(vB2)) + (bhi(vC2) + bhi(vD2));
    }
    for (; i < cnt; i++) {
        const u32* rA = hv32 + (long)(st + i) * HVS32;
        u32 vA0 = rA[i0], vA1 = rA[i1], vA2 = p2 ? rA[i2] : 0u;
        a0 += blo(vA0); b0 += bhi(vA0);
        a1 += blo(vA1); b1 += bhi(vA1);
        a2 += blo(vA2); b2 += bhi(vA2);
    }
    float fc = (float)cnt;
    float inv = 1.f / (float)(cnt > 0 ? cnt : 1);
    const float* vg = vnlast + g * kH;
    hrep32[(long)g * 768 + i0] = pack2((a0 - fc * vg[2 * i0]) * inv, (b0 - fc * vg[2 * i0 + 1]) * inv);
    hrep32[(long)g * 768 + i1] = pack2((a1 - fc * vg[2 * i1]) * inv, (b1 - fc * vg[2 * i1 + 1]) * inv);
    if (p2)
        hrep32[(long)g * 768 + i2] = pack2((a2 - fc * vg[2 * i2]) * inv, (b2 - fc * vg[2 * i2 + 1]) * inv);
}

// ---------------- h_rep cols [300,1536) ----------------
__global__ void hrep_rest_k(const float* __restrict__ morgan, const float* __restrict__ maccs,
                            const int* __restrict__ counts, u16* __restrict__ hrep) {
    long idx = (long)blockIdx.x * 256 + threadIdx.x;
    if (idx >= (long)kG * (KP_DG - kH)) return;
    int g = (int)(idx / (KP_DG - kH));
    int j = (int)(idx % (KP_DG - kH));
    int col = kH + j;
    u16 v;
    if (j < kF) {
        int c = counts[g];
        int q = (j < c) ? ((c - 1 - j) / kF + 1) : 0;
        v = f2bf((float)q / (float)(c > 0 ? c : 1));
    } else if (j < kF + 1024) {
        v = f2bf(morgan[(long)g * 1024 + (j - kF)]);
    } else if (j < kF + 1024 + 167) {
        v = f2bf(maccs[(long)g * 167 + (j - kF - 1024)]);
    } else {
        v = 0;
    }
    hrep[(long)g * KP_DG + col] = v;
}

// ---------------- final ----------------
__global__ void final_k(const u16* __restrict__ zp, const float* __restrict__ Wp2,
                        const float* __restrict__ bp2, float* __restrict__ out) {
    int wave = threadIdx.x >> 6, lane = threadIdx.x & 63;
    int g = blockIdx.x * 4 + wave;
    float acc = 0.f;
    for (int c = lane; c < kH2; c += 64) acc += bf2f(zp[(long)g * KP_H2 + c]) * Wp2[c];
    #pragma unroll
    for (int off = 32; off; off >>= 1) acc += __shfl_down(acc, off);
    if (lane == 0) out[g] = acc + bp2[0];
}

extern "C" void kernel_launch(void* const* d_in, const int* in_sizes, int n_in,
                              void* d_out, int out_size, void* d_ws, size_t ws_size,
                              hipStream_t stream) {
    const float* x      = (const float*)d_in[0];
    const float* morgan = (const float*)d_in[1];
    const float* maccs  = (const float*)d_in[2];
    const int*   ei     = (const int*)d_in[3];
    const int*   batch  = (const int*)d_in[4];
    const float* W_emb  = (const float*)d_in[5];
    const float* b_emb  = (const float*)d_in[6];
    const float* gin_W1 = (const float*)d_in[7];
    const float* gin_b1 = (const float*)d_in[8];
    const float* gin_W2 = (const float*)d_in[9];
    const float* gin_b2 = (const float*)d_in[10];
    const float* bn_scale = (const float*)d_in[11];
    const float* bn_bias  = (const float*)d_in[12];
    const float* eps    = (const float*)d_in[13];
    const float* vn0    = (const float*)d_in[14];
    const float* vn_W1  = (const float*)d_in[15];
    const float* vn_b1  = (const float*)d_in[16];
    const float* vn_W2  = (const float*)d_in[17];
    const float* vn_b2  = (const float*)d_in[18];
    const float* Wp1    = (const float*)d_in[19];
    const float* bp1    = (const float*)d_in[20];
    const float* Wp2    = (const float*)d_in[21];
    const float* bp2    = (const float*)d_in[22];
    float* out = (float*)d_out;

    char* ws = (char*)d_ws;
    size_t off = 0;
    auto alloc = [&](size_t bytes) -> char* {
        char* p = ws + off;
        off += (bytes + 255) & ~(size_t)255;
        return p;
    };
    u16*   hvbf = (u16*)alloc((size_t)kN * HVS * 2);        // 41.9 MB
    u16*   hv   = (u16*)alloc((size_t)kN * KP_H * 2);       // 41.9 MB
    u16*   z1   = (u16*)alloc((size_t)kN * KP_H2 * 2);      // 83.9 MB (vn/pred overlays)
    float* vnA  = (float*)alloc((size_t)kG * kH * 4);
    float* vnB  = (float*)alloc((size_t)kG * kH * 4);
    int* counts = (int*)alloc(kG * 4);
    int* starts = (int*)alloc(kG * 4);
    float* stats = (float*)alloc(2 * kH * 4);
    int* cnt_n  = (int*)alloc((size_t)kN * 4);
    int* start_n = (int*)alloc((size_t)(kN + 1) * 4);
    int* fill_n = (int*)alloc((size_t)kN * 4);
    int* bsum   = (int*)alloc((kN / 1024) * 4);
    int* perm   = (int*)alloc((size_t)kE * 4);
    u16* W1f   = (u16*)alloc((size_t)kL * WFRAG_PER_L * 2);   // 2.05 MB fragment-packed gin_W1
    u16* W2f   = (u16*)alloc((size_t)kL * WFRAG_PER_L * 2);   // 2.05 MB fragment-packed gin_W2
    u16* Wt_v1 = (u16*)alloc((size_t)(kL - 1) * NP_H2 * KP_H * 2);
    u16* Wt_v2 = (u16*)alloc((size_t)(kL - 1) * NP_H * KP_H2 * 2);
    u16* Wt_p1 = (u16*)alloc((size_t)NP_H2 * KP_DG * 2);
    if (off > ws_size) return;

    // z1-region overlays (disjoint lifetimes):
    u16* vt_in = z1;                                   // [2048,320] bf16 (pre vn-G1)
    u16* z1v   = z1 + (size_t)4 * 1024 * 1024;         // [2048,640] bf16 (pre vn-G1)
    u16* hrep  = z1;                                   // [2048,1536] bf16 (post layers)
    u16* zp    = z1 + (size_t)8 * 1024 * 1024;         // [2048,640] bf16 (post layers)
    float* vnb[2] = {vnA, vnB};

    // weight packing / transposes
    {
        long tf = (long)kL * WFRAG_PER_L;
        pack_w1_k<<<dim3((unsigned)((tf + 255) / 256)), 256, 0, stream>>>(gin_W1, W1f, tf);
        pack_w2_k<<<dim3((unsigned)((tf + 255) / 256)), 256, 0, stream>>>(gin_W2, W2f, tf);
        long t3 = (long)(kL - 1) * NP_H2 * KP_H;
        transpose_k<<<dim3((unsigned)((t3 + 255) / 256)), 256, 0, stream>>>(vn_W1, Wt_v1, kH, kH2, NP_H2, KP_H, t3);
        long t4 = (long)(kL - 1) * NP_H * KP_H2;
        transpose_k<<<dim3((unsigned)((t4 + 255) / 256)), 256, 0, stream>>>(vn_W2, Wt_v2, kH2, kH, NP_H, KP_H2, t4);
        long t5 = (long)NP_H2 * KP_DG;
        transpose_k<<<dim3((unsigned)((t5 + 255) / 256)), 256, 0, stream>>>(Wp1, Wt_p1, kDG, kH2, NP_H2, KP_DG, t5);
    }

    // graph ranges + node CSR
    hipMemsetAsync(counts, 0, kG * 4, stream);
    hipMemsetAsync(cnt_n, 0, (size_t)kN * 4, stream);
    hipMemsetAsync(fill_n, 0, (size_t)kN * 4, stream);
    hist_g_k<<<kN / 256, 256, 0, stream>>>(batch, counts);
    scan_g_k<<<1, 1024, 0, stream>>>(counts, starts);
    hist_n_k<<<kE / 256, 256, 0, stream>>>(ei, cnt_n);
    scanA_k<<<kN / 1024, 1024, 0, stream>>>(cnt_n, start_n, bsum);
    scanB_k<<<1, 64, 0, stream>>>(bsum);
    scanC_k<<<kN / 1024, 1024, 0, stream>>>(start_n, bsum);
    fill_n_k<<<kE / 256, 256, 0, stream>>>(ei, start_n, fill_n, perm);

    embed_k<<<kN / 4, 256, 0, stream>>>(x, W_emb, b_emb, vn0, (u32*)hvbf);
    vninit_k<<<kG, 320, 0, stream>>>(vn0, vnA);

    for (int l = 0; l < kL; l++) {
        float* vcur = vnb[l & 1];
        float* vnxt = vnb[(l + 1) & 1];
        gather_combine_k<<<kN / 4, 256, 0, stream>>>(
            (const u32*)hvbf, start_n, perm, eps, l, (u32*)hv, stats);
        if (l < kL - 1) {
            vt_fin_k<<<kG / 4, 256, 0, stream>>>(
                (const u32*)hvbf, vcur, counts, starts, (u32*)vt_in);
            gemm_k<1, 1, 0><<<dim3(16, NP_H2 / 128), 256, 0, stream>>>(
                vt_in, Wt_v1 + (size_t)l * NP_H2 * KP_H, vn_b1 + l * kH2,
                z1v, nullptr, KP_H, kH2, KP_H2, KP_H2);
            gemm64_k<0, 2, 0><<<dim3(16, NP_H / 64), 256, 0, stream>>>(
                z1v, Wt_v2 + (size_t)l * NP_H * KP_H2, vn_b2 + l * kH,
                vnxt, nullptr, vcur, KP_H2, kH, kH, kH);
        }
        // fused node MLP v8: dbuf z1c + early W2 issue + setprio MFMA clusters
        fused_mlp_k<<<kN / 64, 256, 0, stream>>>(
            hv, W1f + (size_t)l * WFRAG_PER_L, gin_b1 + l * kH2,
            W2f + (size_t)l * WFRAG_PER_L, gin_b2 + l * kH,
            hv, stats);
        if (l < kL - 1)
            resid_k<1><<<kN / 4, 256, 0, stream>>>(
                (u32*)hvbf, (const u32*)hv, stats, bn_scale, bn_bias, l, batch, vcur, vnxt);
        else
            resid_k<0><<<kN / 4, 256, 0, stream>>>(
                (u32*)hvbf, (const u32*)hv, stats, bn_scale, bn_bias, l, batch, vcur, vcur);
    }

    float* vnlast = vnb[(kL - 1) & 1];
    pooled_k<<<kG / 4, 256, 0, stream>>>(
        (const u32*)hvbf, vnlast, counts, starts, (u32*)hrep);
    {
        long tr = (long)kG * (KP_DG - kH);
        hrep_rest_k<<<dim3((unsigned)((tr + 255) / 256)), 256, 0, stream>>>(morgan, maccs, counts, hrep);
    }
    gemm_k<1, 1, 0><<<dim3(16, NP_H2 / 128), 256, 0, stream>>>(
        hrep, Wt_p1, bp1, zp, nullptr, KP_DG, kH2, KP_H2, KP_H2);
    final_k<<<kG / 4, 256, 0, stream>>>(zp, Wp2, bp2, out);
}

// Round 15
// 1128.357 us; speedup vs baseline: 1.9489x; 1.0198x over previous
//
#include <hip/hip_runtime.h>

typedef unsigned short u16;
typedef unsigned int u32;
typedef __attribute__((ext_vector_type(8))) short bf16x8_t;
typedef __attribute__((ext_vector_type(4))) float f32x4_t;

// problem constants
#define kN 65536
#define kE 262144
#define kG 2048
#define kH 300
#define kH2 600
#define kL 5
#define kF 32
#define kDG 1523
// padded dims
#define KP_H 320     // K pad of H
#define KP_H2 640    // K pad of 2H
#define KP_DG 1536   // K pad of DG
#define NP_H2 640    // N pad of 2H (128-tiled)
#define NP_H 320     // N pad of H (64-tiled)
// hvbf row stride (u16 / u32)
#define HVS 320
#define HVS32 160
// fragment-packed weight size per layer: 5*4*2*10*64*8 == 5*4*5*4*64*8 == 204800 u16
#define WFRAG_PER_L 204800

__device__ __forceinline__ float bf2f(u16 x) {
    union { u32 u; float f; } v; v.u = ((u32)x) << 16; return v.f;
}
__device__ __forceinline__ u16 f2bf(float f) {
    union { float f; u32 u; } v; v.f = f;
    u32 u = v.u;
    u32 r = (u + 0x7fffu + ((u >> 16) & 1u)) >> 16;  // RNE
    return (u16)r;
}
__device__ __forceinline__ float blo(u32 v) { return bf2f((u16)(v & 0xffffu)); }
__device__ __forceinline__ float bhi(u32 v) { return bf2f((u16)(v >> 16)); }
__device__ __forceinline__ u32 pack2(float lo, float hi) {
    return (u32)f2bf(lo) | ((u32)f2bf(hi) << 16);
}

// async 16B global -> LDS
__device__ __forceinline__ void gld16(const u16* g, u16* l) {
    __builtin_amdgcn_global_load_lds(
        (const __attribute__((address_space(1))) u32*)g,
        (__attribute__((address_space(3))) u32*)l, 16, 0, 0);
}

// counted vmcnt waits + raw barrier
__device__ __forceinline__ void vwait8() { asm volatile("s_waitcnt vmcnt(8)" ::: "memory"); }
__device__ __forceinline__ void vwait0() { asm volatile("s_waitcnt vmcnt(0)" ::: "memory"); }
__device__ __forceinline__ void lwait0() { asm volatile("s_waitcnt lgkmcnt(0)" ::: "memory"); }
__device__ __forceinline__ void rbar() {
    __builtin_amdgcn_sched_barrier(0);
    __builtin_amdgcn_s_barrier();
    __builtin_amdgcn_sched_barrier(0);
}

// XCD-bijective tile swizzle (requires gridDim.x % 8 == 0; holds: 16).
__device__ __forceinline__ void swz_tile(int& m, int& n) {
    int p = blockIdx.x + gridDim.x * blockIdx.y;
    int xcd = p & 7;
    int q = p >> 3;
    int NB = gridDim.y;
    int mb8 = gridDim.x >> 3;
    m = xcd * mb8 + q / NB;
    n = q % NB;
}

// ---------------- weight transpose: W[b][k][n] (f32) -> Wt[b][n][k] (bf16), zero-padded ----------------
__global__ void transpose_k(const float* __restrict__ W, u16* __restrict__ Wt,
                            int K, int NN, int NP, int KP, long total) {
    long idx = (long)blockIdx.x * 256 + threadIdx.x;
    if (idx >= total) return;
    int per = NP * KP;
    int b = (int)(idx / per);
    int r = (int)(idx % per);
    int n = r / KP;
    int k = r % KP;
    u16 v = 0;
    if (n < NN && k < K) v = f2bf(W[(long)b * K * NN + (long)k * NN + n]);
    Wt[idx] = v;
}

// ---------------- fragment-pack W1 (W [L][300][600]) -> W1f [L][c][w][nt][tk][lane][8] ----------------
__global__ void pack_w1_k(const float* __restrict__ W, u16* __restrict__ Wf, long total) {
    long idx = (long)blockIdx.x * 256 + threadIdx.x;
    if (idx >= total) return;
    int l = (int)(idx / WFRAG_PER_L);
    long r = idx % WFRAG_PER_L;
    int e = (int)(r & 7);
    long r1 = r >> 3;
    int ln = (int)(r1 & 63);
    int l16 = ln & 15, quad = ln >> 4;
    long s = r1 >> 6;
    int tk = (int)(s % 10);
    long s2 = s / 10;
    int nt = (int)(s2 & 1);
    long s3 = s2 >> 1;
    int w = (int)(s3 & 3);
    int c = (int)(s3 >> 2);
    int n = c * 128 + w * 32 + nt * 16 + l16;
    int k = tk * 32 + quad * 8 + e;
    u16 v = 0;
    if (n < kH2 && k < kH) v = f2bf(W[(long)l * kH * kH2 + (long)k * kH2 + n]);
    Wf[idx] = v;
}

// ---------------- fragment-pack W2 (W [L][600][300]) -> W2f [L][c][w][nt][ks][lane][8] ----------------
__global__ void pack_w2_k(const float* __restrict__ W, u16* __restrict__ Wf, long total) {
    long idx = (long)blockIdx.x * 256 + threadIdx.x;
    if (idx >= total) return;
    int l = (int)(idx / WFRAG_PER_L);
    long r = idx % WFRAG_PER_L;
    int e = (int)(r & 7);
    long r1 = r >> 3;
    int ln = (int)(r1 & 63);
    int l16 = ln & 15, quad = ln >> 4;
    long s = r1 >> 6;
    int ks = (int)(s & 3);
    long s2 = s >> 2;
    int nt = (int)(s2 % 5);
    long s3 = s2 / 5;
    int w = (int)(s3 & 3);
    int c = (int)(s3 >> 2);
    int n = w * 80 + nt * 16 + l16;
    int k = c * 128 + ks * 32 + quad * 8 + e;
    u16 v = 0;
    if (n < kH && k < kH2) v = f2bf(W[(long)l * kH2 * kH + (long)k * kH + n]);
    Wf[idx] = v;
}

// ---------------- graph histogram + scan ----------------
__global__ void hist_g_k(const int* __restrict__ batch, int* __restrict__ counts) {
    int n = blockIdx.x * 256 + threadIdx.x;
    if (n < kN) atomicAdd(&counts[batch[n]], 1);
}

__global__ void scan_g_k(const int* __restrict__ counts, int* __restrict__ starts) {
    __shared__ int s[1024];
    int t = threadIdx.x;
    int c0 = counts[2 * t], c1 = counts[2 * t + 1];
    s[t] = c0 + c1;
    __syncthreads();
    for (int off = 1; off < 1024; off <<= 1) {
        int v = (t >= off) ? s[t - off] : 0;
        __syncthreads();
        s[t] += v;
        __syncthreads();
    }
    int excl = (t > 0) ? s[t - 1] : 0;
    starts[2 * t] = excl;
    starts[2 * t + 1] = excl + c0;
}

// ---------------- node CSR build ----------------
__global__ void hist_n_k(const int* __restrict__ ei, int* __restrict__ cnt) {
    int e = blockIdx.x * 256 + threadIdx.x;
    if (e < kE) atomicAdd(&cnt[ei[kE + e]], 1);
}

__global__ void scanA_k(const int* __restrict__ cnt, int* __restrict__ start, int* __restrict__ bsum) {
    __shared__ int s[1024];
    int b = blockIdx.x, t = threadIdx.x;
    int v = cnt[b * 1024 + t];
    s[t] = v;
    __syncthreads();
    for (int off = 1; off < 1024; off <<= 1) {
        int u = (t >= off) ? s[t - off] : 0;
        __syncthreads();
        s[t] += u;
        __syncthreads();
    }
    start[b * 1024 + t] = s[t] - v;
    if (t == 1023) bsum[b] = s[1023];
}

__global__ void scanB_k(int* __restrict__ bsum) {
    if (threadIdx.x == 0) {
        int s = 0;
        for (int i = 0; i < kN / 1024; i++) { s += bsum[i]; bsum[i] = s; }
    }
}

__global__ void scanC_k(int* __restrict__ start, const int* __restrict__ bsum) {
    int b = blockIdx.x, t = threadIdx.x;
    int add = (b > 0) ? bsum[b - 1] : 0;
    start[b * 1024 + t] += add;
    if (b == kN / 1024 - 1 && t == 1023) start[kN] = bsum[kN / 1024 - 1];
}

__global__ void fill_n_k(const int* __restrict__ ei, const int* __restrict__ start,
                         int* __restrict__ fill, int* __restrict__ perm) {
    int e = blockIdx.x * 256 + threadIdx.x;
    if (e >= kE) return;
    int s = ei[e], d = ei[kE + e];
    int pos = start[d] + atomicAdd(&fill[d], 1);
    perm[pos] = s;
}

// ---------------- node embedding: hvbf = bf16(x@W+b + vn0) ----------------
__global__ __launch_bounds__(256) void embed_k(
    const float* __restrict__ x, const float* __restrict__ W,
    const float* __restrict__ b, const float* __restrict__ vn0,
    u32* __restrict__ hv32) {
    __shared__ float sW[9 * kH];
    __shared__ float sBV[kH];
    int tid = threadIdx.x;
    for (int i = tid; i < 9 * kH; i += 256) sW[i] = W[i];
    for (int i = tid; i < kH; i += 256) sBV[i] = b[i] + vn0[i];
    __syncthreads();
    int wave = tid >> 6, lane = tid & 63;
    int n = blockIdx.x * 4 + wave;
    float xv[9];
    #pragma unroll
    for (int d = 0; d < 9; d++) xv[d] = x[n * 9 + d];
    #pragma unroll
    for (int p = 0; p < 3; p++) {
        int ii = lane + p * 64;
        if (ii < 150) {
            int c0 = 2 * ii;
            float a0 = sBV[c0], a1 = sBV[c0 + 1];
            #pragma unroll
            for (int d = 0; d < 9; d++) {
                a0 += xv[d] * sW[d * kH + c0];
                a1 += xv[d] * sW[d * kH + c0 + 1];
            }
            hv32[(long)n * HVS32 + ii] = pack2(a0, a1);
        } else if (ii < HVS32) {
            hv32[(long)n * HVS32 + ii] = 0u;
        }
    }
}

__global__ void vninit_k(const float* __restrict__ vn0, float* __restrict__ vn) {
    int g = blockIdx.x, c = threadIdx.x;
    if (c < kH) vn[g * kH + c] = vn0[c];
}

// ---------------- gather + combine ----------------
__global__ __launch_bounds__(256) void gather_combine_k(
    const u32* __restrict__ hv32, const int* __restrict__ start_n,
    const int* __restrict__ perm, const float* __restrict__ eps, int l,
    u32* __restrict__ out32, float* __restrict__ stats) {
    int tid = threadIdx.x;
    int wave = tid >> 6, lane = tid & 63;
    int n = blockIdx.x * 4 + wave;
    int st = start_n[n], en = start_n[n + 1];
    int i0 = lane, i1 = lane + 64, i2 = lane + 128;
    bool p2 = (i2 < 150);
    float a0 = 0.f, b0 = 0.f, a1 = 0.f, b1 = 0.f, a2 = 0.f, b2 = 0.f;
    int e = st;
    for (; e + 4 <= en; e += 4) {
        const u32* rA = hv32 + (long)perm[e] * HVS32;
        const u32* rB = hv32 + (long)perm[e + 1] * HVS32;
        const u32* rC = hv32 + (long)perm[e + 2] * HVS32;
        const u32* rD = hv32 + (long)perm[e + 3] * HVS32;
        u32 vA0 = rA[i0], vA1 = rA[i1], vA2 = p2 ? rA[i2] : 0u;
        u32 vB0 = rB[i0], vB1 = rB[i1], vB2 = p2 ? rB[i2] : 0u;
        u32 vC0 = rC[i0], vC1 = rC[i1], vC2 = p2 ? rC[i2] : 0u;
        u32 vD0 = rD[i0], vD1 = rD[i1], vD2 = p2 ? rD[i2] : 0u;
        a0 += (blo(vA0) + blo(vB0)) + (blo(vC0) + blo(vD0));
        b0 += (bhi(vA0) + bhi(vB0)) + (bhi(vC0) + bhi(vD0));
        a1 += (blo(vA1) + blo(vB1)) + (blo(vC1) + blo(vD1));
        b1 += (bhi(vA1) + bhi(vB1)) + (bhi(vC1) + bhi(vD1));
        a2 += (blo(vA2) + blo(vB2)) + (blo(vC2) + blo(vD2));
        b2 += (bhi(vA2) + bhi(vB2)) + (bhi(vC2) + bhi(vD2));
    }
    for (; e + 2 <= en; e += 2) {
        const u32* rA = hv32 + (long)perm[e] * HVS32;
        const u32* rB = hv32 + (long)perm[e + 1] * HVS32;
        u32 vA0 = rA[i0], vA1 = rA[i1], vA2 = p2 ? rA[i2] : 0u;
        u32 vB0 = rB[i0], vB1 = rB[i1], vB2 = p2 ? rB[i2] : 0u;
        a0 += blo(vA0) + blo(vB0); b0 += bhi(vA0) + bhi(vB0);
        a1 += blo(vA1) + blo(vB1); b1 += bhi(vA1) + bhi(vB1);
        a2 += blo(vA2) + blo(vB2); b2 += bhi(vA2) + bhi(vB2);
    }
    if (e < en) {
        const u32* rA = hv32 + (long)perm[e] * HVS32;
        u32 vA0 = rA[i0], vA1 = rA[i1], vA2 = p2 ? rA[i2] : 0u;
        a0 += blo(vA0); b0 += bhi(vA0);
        a1 += blo(vA1); b1 += bhi(vA1);
        a2 += blo(vA2); b2 += bhi(vA2);
    }
    const u32* self = hv32 + (long)n * HVS32;
    float ep = 1.f + eps[l];
    u32 s0 = self[i0], s1 = self[i1];
    u32* o = out32 + (long)n * HVS32;
    o[i0] = pack2(ep * blo(s0) + a0, ep * bhi(s0) + b0);
    o[i1] = pack2(ep * blo(s1) + a1, ep * bhi(s1) + b1);
    if (p2) {
        u32 s2 = self[i2];
        o[i2] = pack2(ep * blo(s2) + a2, ep * bhi(s2) + b2);
    } else if (i2 < HVS32) {
        o[i2] = 0u;
    }
    int gz = blockIdx.x * 256 + tid;
    if (gz < 2 * kH) stats[gz] = 0.f;
}

// ---------------- vt (wave per graph): vt[g] = sum_rows hvbf + vn_cur[g] ----------------
__global__ __launch_bounds__(256) void vt_fin_k(
    const u32* __restrict__ hv32, const float* __restrict__ vncur,
    const int* __restrict__ counts, const int* __restrict__ starts,
    u32* __restrict__ vt32) {
    int tid = threadIdx.x, wave = tid >> 6, lane = tid & 63;
    int g = blockIdx.x * 4 + wave;
    int cnt = counts[g], st = starts[g];
    int i0 = lane, i1 = lane + 64, i2 = lane + 128;
    bool p2 = (i2 < 150);
    float a0 = 0.f, b0 = 0.f, a1 = 0.f, b1 = 0.f, a2 = 0.f, b2 = 0.f;
    int i = 0;
    for (; i + 4 <= cnt; i += 4) {
        const u32* rA = hv32 + (long)(st + i) * HVS32;
        const u32* rB = hv32 + (long)(st + i + 1) * HVS32;
        const u32* rC = hv32 + (long)(st + i + 2) * HVS32;
        const u32* rD = hv32 + (long)(st + i + 3) * HVS32;
        u32 vA0 = rA[i0], vA1 = rA[i1], vA2 = p2 ? rA[i2] : 0u;
        u32 vB0 = rB[i0], vB1 = rB[i1], vB2 = p2 ? rB[i2] : 0u;
        u32 vC0 = rC[i0], vC1 = rC[i1], vC2 = p2 ? rC[i2] : 0u;
        u32 vD0 = rD[i0], vD1 = rD[i1], vD2 = p2 ? rD[i2] : 0u;
        a0 += (blo(vA0) + blo(vB0)) + (blo(vC0) + blo(vD0));
        b0 += (bhi(vA0) + bhi(vB0)) + (bhi(vC0) + bhi(vD0));
        a1 += (blo(vA1) + blo(vB1)) + (blo(vC1) + blo(vD1));
        b1 += (bhi(vA1) + bhi(vB1)) + (bhi(vC1) + bhi(vD1));
        a2 += (blo(vA2) + blo(vB2)) + (blo(vC2) + blo(vD2));
        b2 += (bhi(vA2) + bhi(vB2)) + (bhi(vC2) + bhi(vD2));
    }
    for (; i < cnt; i++) {
        const u32* rA = hv32 + (long)(st + i) * HVS32;
        u32 vA0 = rA[i0], vA1 = rA[i1], vA2 = p2 ? rA[i2] : 0u;
        a0 += blo(vA0); b0 += bhi(vA0);
        a1 += blo(vA1); b1 += bhi(vA1);
        a2 += blo(vA2); b2 += bhi(vA2);
    }
    const float* vg = vncur + g * kH;
    vt32[(long)g * HVS32 + i0] = pack2(a0 + vg[2 * i0], b0 + vg[2 * i0 + 1]);
    vt32[(long)g * HVS32 + i1] = pack2(a1 + vg[2 * i1], b1 + vg[2 * i1 + 1]);
    if (p2) vt32[(long)g * HVS32 + i2] = pack2(a2 + vg[2 * i2], b2 + vg[2 * i2 + 1]);
    else if (i2 < HVS32) vt32[(long)g * HVS32 + i2] = 0u;
}

// ---------------- FUSED node MLP v8: dbuf z1c + early W2 issue + setprio (r13/r14 verified) ----------------
__global__ __launch_bounds__(256, 2) void fused_mlp_k(
    const u16* __restrict__ A,      // hv [kN x 320] bf16
    const u16* __restrict__ W1f,    // fragment-packed [5][4][2][10][64][8]
    const float* __restrict__ b1,   // [600]
    const u16* __restrict__ W2f,    // fragment-packed [5][4][5][4][64][8]
    const float* __restrict__ b2,   // [300]
    u16* __restrict__ outp,         // hv (in-place)
    float* __restrict__ stats) {
    __shared__ __align__(16) u16 lA[5][64 * 64];    // 40 KB persistent A strip
    __shared__ __align__(16) u16 z1c[2][64 * 128];  // 32 KB z1 chunk dbuf, XOR swizzle
    __shared__ float sred[320][2];                  // 2.5 KB BN partial sums

    const int tid = threadIdx.x;
    const int lane = tid & 63;
    const int wave = tid >> 6;      // 0..3
    const int l16 = lane & 15;
    const int quad = lane >> 4;
    const long tm = (long)blockIdx.x * 64;
    const int srow = lane >> 3;
    const int sch = (lane & 7) ^ srow;

    for (int i = tid; i < 320; i += 256) { sred[i][0] = 0.f; sred[i][1] = 0.f; }

    #pragma unroll
    for (int t = 0; t < 5; t++) {
        #pragma unroll
        for (int j = 0; j < 2; j++) {
            int rb = wave * 16 + j * 8;
            gld16(A + (tm + rb + srow) * KP_H + t * 64 + sch * 8, &lA[t][rb * 64]);
        }
    }

    float rb1[5][2];
    #pragma unroll
    for (int c = 0; c < 5; c++)
        #pragma unroll
        for (int nt = 0; nt < 2; nt++) {
            int gc = c * 128 + wave * 32 + nt * 16 + l16;
            rb1[c][nt] = (gc < kH2) ? b1[gc] : 0.f;
        }
    float rb2[5];
    #pragma unroll
    for (int nt = 0; nt < 5; nt++) {
        int col = wave * 80 + nt * 16 + l16;
        rb2[nt] = (col < kH) ? b2[col] : 0.f;
    }

    f32x4_t acc2[4][5];
    #pragma unroll
    for (int i = 0; i < 4; i++)
        #pragma unroll
        for (int j = 0; j < 5; j++) acc2[i][j] = (f32x4_t){0.f, 0.f, 0.f, 0.f};

    vwait0();
    rbar();

    #pragma unroll
    for (int c = 0; c < 5; c++) {
        f32x4_t acc1[4][2];
        #pragma unroll
        for (int i = 0; i < 4; i++) {
            acc1[i][0] = (f32x4_t){0.f, 0.f, 0.f, 0.f};
            acc1[i][1] = (f32x4_t){0.f, 0.f, 0.f, 0.f};
        }
        const u16* w1p = W1f + ((long)((c * 4 + wave) * 2) * 10) * 512 + lane * 8;
        bf16x8_t wf[4][2];
        #pragma unroll
        for (int p = 0; p < 3; p++) {
            wf[p][0] = *(const bf16x8_t*)(w1p + p * 512);
            wf[p][1] = *(const bf16x8_t*)(w1p + 10 * 512 + p * 512);
        }
        #pragma unroll
        for (int tk = 0; tk < 10; tk++) {
            if (tk + 3 < 10) {
                wf[(tk + 3) & 3][0] = *(const bf16x8_t*)(w1p + (tk + 3) * 512);
                wf[(tk + 3) & 3][1] = *(const bf16x8_t*)(w1p + 10 * 512 + (tk + 3) * 512);
            }
            const int t = tk >> 1, ks = tk & 1;
            bf16x8_t af[4];
            #pragma unroll
            for (int mt = 0; mt < 4; mt++) {
                int row = mt * 16 + l16;
                int phys = (ks * 4 + quad) ^ (l16 & 7);
                af[mt] = *(const bf16x8_t*)&lA[t][row * 64 + phys * 8];
            }
            __builtin_amdgcn_s_setprio(1);
            #pragma unroll
            for (int mt = 0; mt < 4; mt++) {
                acc1[mt][0] = __builtin_amdgcn_mfma_f32_16x16x32_bf16(af[mt], wf[tk & 3][0], acc1[mt][0], 0, 0, 0);
                acc1[mt][1] = __builtin_amdgcn_mfma_f32_16x16x32_bf16(af[mt], wf[tk & 3][1], acc1[mt][1], 0, 0, 0);
            }
            __builtin_amdgcn_s_setprio(0);
        }

        const u16* w2p = W2f + ((long)((c * 4 + wave) * 5) * 4) * 512 + lane * 8;
        bf16x8_t wg[2][5];
        #pragma unroll
        for (int nt = 0; nt < 5; nt++) {
            wg[0][nt] = *(const bf16x8_t*)(w2p + nt * 4 * 512);
            wg[1][nt] = *(const bf16x8_t*)(w2p + nt * 4 * 512 + 512);
        }

        u16* zb = z1c[c & 1];
        #pragma unroll
        for (int nt = 0; nt < 2; nt++) {
            int col = wave * 32 + nt * 16 + l16;
            #pragma unroll
            for (int mt = 0; mt < 4; mt++) {
                #pragma unroll
                for (int r = 0; r < 4; r++) {
                    int row = mt * 16 + quad * 4 + r;
                    float v = fmaxf(acc1[mt][nt][r] + rb1[c][nt], 0.f);
                    int phys = (col >> 3) ^ (row & 15);
                    zb[row * 128 + phys * 8 + (col & 7)] = f2bf(v);
                }
            }
        }
        lwait0();
        rbar();

        #pragma unroll
        for (int ks = 0; ks < 4; ks++) {
            bf16x8_t af[4];
            #pragma unroll
            for (int mt = 0; mt < 4; mt++) {
                int row = mt * 16 + l16;
                int phys = (ks * 4 + quad) ^ (row & 15);
                af[mt] = *(const bf16x8_t*)&zb[row * 128 + phys * 8];
            }
            __builtin_amdgcn_s_setprio(1);
            #pragma unroll
            for (int mt = 0; mt < 4; mt++)
                #pragma unroll
                for (int nt = 0; nt < 5; nt++)
                    acc2[mt][nt] = __builtin_amdgcn_mfma_f32_16x16x32_bf16(af[mt], wg[ks & 1][nt], acc2[mt][nt], 0, 0, 0);
            __builtin_amdgcn_s_setprio(0);
            if (ks + 2 < 4) {
                #pragma unroll
                for (int nt = 0; nt < 5; nt++)
                    wg[ks & 1][nt] = *(const bf16x8_t*)(w2p + nt * 4 * 512 + (ks + 2) * 512);
            }
        }
    }

    #pragma unroll
    for (int nt = 0; nt < 5; nt++) {
        int col = wave * 80 + nt * 16 + l16;
        float s = 0.f, s2 = 0.f;
        #pragma unroll
        for (int mt = 0; mt < 4; mt++) {
            #pragma unroll
            for (int r = 0; r < 4; r++) {
                long row = tm + mt * 16 + quad * 4 + r;
                float v = acc2[mt][nt][r] + rb2[nt];
                float sv = (col < kH) ? v : 0.f;
                outp[row * KP_H + col] = f2bf(sv);
                s += sv; s2 += sv * sv;
            }
        }
        atomicAdd(&sred[col][0], s);
        atomicAdd(&sred[col][1], s2);
    }
    __syncthreads();
    for (int i = tid; i < kH; i += 256) {
        atomicAdd(&stats[i], sred[i][0]);
        atomicAdd(&stats[kH + i], sred[i][1]);
    }
}

// ---------------- FUSED vn MLP: vn_nxt = vn_cur + relu(relu(vt@W1+b1)@W2+b2) ----------------
// Same structure as fused_mlp_k (dims identical: 320->640->320); 2048 rows -> 32 blocks.
// No BN stats; f32 output with vn_cur accumulate. Replaces gemm_k + gemm64_k vn launches.
__global__ __launch_bounds__(256, 2) void fused_vn_k(
    const u16* __restrict__ A,      // vt [kG x 320] bf16
    const u16* __restrict__ W1f,    // fragment-packed vn_W1 (per-layer base)
    const float* __restrict__ b1,   // [600]
    const u16* __restrict__ W2f,    // fragment-packed vn_W2 (per-layer base)
    const float* __restrict__ b2,   // [300]
    const float* __restrict__ vncur,// [kG x 300] f32
    float* __restrict__ vnnxt) {    // [kG x 300] f32
    __shared__ __align__(16) u16 lA[5][64 * 64];
    __shared__ __align__(16) u16 z1c[2][64 * 128];

    const int tid = threadIdx.x;
    const int lane = tid & 63;
    const int wave = tid >> 6;
    const int l16 = lane & 15;
    const int quad = lane >> 4;
    const long tm = (long)blockIdx.x * 64;
    const int srow = lane >> 3;
    const int sch = (lane & 7) ^ srow;

    #pragma unroll
    for (int t = 0; t < 5; t++) {
        #pragma unroll
        for (int j = 0; j < 2; j++) {
            int rb = wave * 16 + j * 8;
            gld16(A + (tm + rb + srow) * KP_H + t * 64 + sch * 8, &lA[t][rb * 64]);
        }
    }

    float rb1[5][2];
    #pragma unroll
    for (int c = 0; c < 5; c++)
        #pragma unroll
        for (int nt = 0; nt < 2; nt++) {
            int gc = c * 128 + wave * 32 + nt * 16 + l16;
            rb1[c][nt] = (gc < kH2) ? b1[gc] : 0.f;
        }
    float rb2[5];
    #pragma unroll
    for (int nt = 0; nt < 5; nt++) {
        int col = wave * 80 + nt * 16 + l16;
        rb2[nt] = (col < kH) ? b2[col] : 0.f;
    }

    f32x4_t acc2[4][5];
    #pragma unroll
    for (int i = 0; i < 4; i++)
        #pragma unroll
        for (int j = 0; j < 5; j++) acc2[i][j] = (f32x4_t){0.f, 0.f, 0.f, 0.f};

    vwait0();
    rbar();

    #pragma unroll
    for (int c = 0; c < 5; c++) {
        f32x4_t acc1[4][2];
        #pragma unroll
        for (int i = 0; i < 4; i++) {
            acc1[i][0] = (f32x4_t){0.f, 0.f, 0.f, 0.f};
            acc1[i][1] = (f32x4_t){0.f, 0.f, 0.f, 0.f};
        }
        const u16* w1p = W1f + ((long)((c * 4 + wave) * 2) * 10) * 512 + lane * 8;
        bf16x8_t wf[4][2];
        #pragma unroll
        for (int p = 0; p < 3; p++) {
            wf[p][0] = *(const bf16x8_t*)(w1p + p * 512);
            wf[p][1] = *(const bf16x8_t*)(w1p + 10 * 512 + p * 512);
        }
        #pragma unroll
        for (int tk = 0; tk < 10; tk++) {
            if (tk + 3 < 10) {
                wf[(tk + 3) & 3][0] = *(const bf16x8_t*)(w1p + (tk + 3) * 512);
                wf[(tk + 3) & 3][1] = *(const bf16x8_t*)(w1p + 10 * 512 + (tk + 3) * 512);
            }
            const int t = tk >> 1, ks = tk & 1;
            bf16x8_t af[4];
            #pragma unroll
            for (int mt = 0; mt < 4; mt++) {
                int row = mt * 16 + l16;
                int phys = (ks * 4 + quad) ^ (l16 & 7);
                af[mt] = *(const bf16x8_t*)&lA[t][row * 64 + phys * 8];
            }
            __builtin_amdgcn_s_setprio(1);
            #pragma unroll
            for (int mt = 0; mt < 4; mt++) {
                acc1[mt][0] = __builtin_amdgcn_mfma_f32_16x16x32_bf16(af[mt], wf[tk & 3][0], acc1[mt][0], 0, 0, 0);
                acc1[mt][1] = __builtin_amdgcn_mfma_f32_16x16x32_bf16(af[mt], wf[tk & 3][1], acc1[mt][1], 0, 0, 0);
            }
            __builtin_amdgcn_s_setprio(0);
        }

        const u16* w2p = W2f + ((long)((c * 4 + wave) * 5) * 4) * 512 + lane * 8;
        bf16x8_t wg[2][5];
        #pragma unroll
        for (int nt = 0; nt < 5; nt++) {
            wg[0][nt] = *(const bf16x8_t*)(w2p + nt * 4 * 512);
            wg[1][nt] = *(const bf16x8_t*)(w2p + nt * 4 * 512 + 512);
        }

        u16* zb = z1c[c & 1];
        #pragma unroll
        for (int nt = 0; nt < 2; nt++) {
            int col = wave * 32 + nt * 16 + l16;
            #pragma unroll
            for (int mt = 0; mt < 4; mt++) {
                #pragma unroll
                for (int r = 0; r < 4; r++) {
                    int row = mt * 16 + quad * 4 + r;
                    float v = fmaxf(acc1[mt][nt][r] + rb1[c][nt], 0.f);
                    int phys = (col >> 3) ^ (row & 15);
                    zb[row * 128 + phys * 8 + (col & 7)] = f2bf(v);
                }
            }
        }
        lwait0();
        rbar();

        #pragma unroll
        for (int ks = 0; ks < 4; ks++) {
            bf16x8_t af[4];
            #pragma unroll
            for (int mt = 0; mt < 4; mt++) {
                int row = mt * 16 + l16;
                int phys = (ks * 4 + quad) ^ (row & 15);
                af[mt] = *(const bf16x8_t*)&zb[row * 128 + phys * 8];
            }
            __builtin_amdgcn_s_setprio(1);
            #pragma unroll
            for (int mt = 0; mt < 4; mt++)
                #pragma unroll
                for (int nt = 0; nt < 5; nt++)
                    acc2[mt][nt] = __builtin_amdgcn_mfma_f32_16x16x32_bf16(af[mt], wg[ks & 1][nt], acc2[mt][nt], 0, 0, 0);
            __builtin_amdgcn_s_setprio(0);
            if (ks + 2 < 4) {
                #pragma unroll
                for (int nt = 0; nt < 5; nt++)
                    wg[ks & 1][nt] = *(const bf16x8_t*)(w2p + nt * 4 * 512 + (ks + 2) * 512);
            }
        }
    }

    // epilogue: vn_nxt = vn_cur + relu(z2 + b2), f32, cols < kH only
    #pragma unroll
    for (int nt = 0; nt < 5; nt++) {
        int col = wave * 80 + nt * 16 + l16;
        if (col < kH) {
            #pragma unroll
            for (int mt = 0; mt < 4; mt++) {
                #pragma unroll
                for (int r = 0; r < 4; r++) {
                    long row = tm + mt * 16 + quad * 4 + r;
                    float v = fmaxf(acc2[mt][nt][r] + rb2[nt], 0.f);
                    vnnxt[row * kH + col] = vncur[row * kH + col] + v;
                }
            }
        }
    }
}

// ---------------- GEMM: 128x128 tile, BK=64, counted-vmcnt double-buffered pipeline ----------------
template<int ACT, int OUT_BF16, int BN_STATS>
__global__ __launch_bounds__(256) void gemm_k(
    const u16* __restrict__ A, const u16* __restrict__ Wt,
    const float* __restrict__ bias, void* __restrict__ out,
    float* __restrict__ stats,
    int KP, int NN, int out_stride, int store_cols) {
    __shared__ __align__(16) u16 lA[2][128 * 64];
    __shared__ __align__(16) u16 lB[2][128 * 64];
    __shared__ float sred[128][2];

    const int tid = threadIdx.x;
    const int lane = tid & 63;
    const int wave = tid >> 6;
    const int l16 = lane & 15;
    const int quad = lane >> 4;
    const int wm = (wave & 1) * 64;
    const int wn = (wave >> 1) * 64;
    int sm, sn;
    swz_tile(sm, sn);
    const long tm = (long)sm * 128;
    const int tn = sn * 128;

    const int srow = lane >> 3;
    const int sch = (lane & 7) ^ srow;

    f32x4_t acc[4][4];
    #pragma unroll
    for (int i = 0; i < 4; i++)
        #pragma unroll
        for (int j = 0; j < 4; j++) acc[i][j] = (f32x4_t){0.f, 0.f, 0.f, 0.f};

    auto stage = [&](int bb, int k0) {  // 8 VMEM per wave
        #pragma unroll
        for (int j = 0; j < 4; j++) {
            int rb = wave * 32 + j * 8;
            int r = rb + srow;
            gld16(A + (tm + r) * KP + k0 + sch * 8, &lA[bb][rb * 64]);
            gld16(Wt + (long)(tn + r) * KP + k0 + sch * 8, &lB[bb][rb * 64]);
        }
    };

    const int nk = KP >> 6;
    stage(0, 0);
    if (nk > 1) stage(1, 64);
    for (int t = 0; t < nk; t++) {
        if (t < nk - 1) vwait8(); else vwait0();
        rbar();
        const u16* la = lA[t & 1];
        const u16* lb = lB[t & 1];
        #pragma unroll
        for (int ks = 0; ks < 2; ks++) {
            bf16x8_t af[4], bfr[4];
            #pragma unroll
            for (int mt = 0; mt < 4; mt++) {
                int row = wm + mt * 16 + l16;
                int phys = (ks * 4 + quad) ^ (l16 & 7);
                af[mt] = *(const bf16x8_t*)&la[row * 64 + phys * 8];
            }
            #pragma unroll
            for (int nt = 0; nt < 4; nt++) {
                int row = wn + nt * 16 + l16;
                int phys = (ks * 4 + quad) ^ (l16 & 7);
                bfr[nt] = *(const bf16x8_t*)&lb[row * 64 + phys * 8];
            }
            #pragma unroll
            for (int mt = 0; mt < 4; mt++)
                #pragma unroll
                for (int nt = 0; nt < 4; nt++)
                    acc[mt][nt] = __builtin_amdgcn_mfma_f32_16x16x32_bf16(af[mt], bfr[nt], acc[mt][nt], 0, 0, 0);
        }
        rbar();
        if (t + 2 < nk) stage(t & 1, (t + 2) * 64);
    }

    if (BN_STATS) {
        if (tid < 128) { sred[tid][0] = 0.f; sred[tid][1] = 0.f; }
    }
    __syncthreads();

    #pragma unroll
    for (int nt = 0; nt < 4; nt++) {
        int col = tn + wn + nt * 16 + l16;
        float bv = (col < NN) ? bias[col] : 0.f;
        float s = 0.f, s2 = 0.f;
        #pragma unroll
        for (int mt = 0; mt < 4; mt++) {
            #pragma unroll
            for (int r = 0; r < 4; r++) {
                long row = tm + wm + mt * 16 + quad * 4 + r;
                float v = acc[mt][nt][r] + bv;
                if (ACT) v = fmaxf(v, 0.f);
                float sv = (col < NN) ? v : 0.f;
                if (col < store_cols) {
                    if (OUT_BF16) ((u16*)out)[row * out_stride + col] = f2bf(sv);
                    else          ((float*)out)[row * out_stride + col] = sv;
                }
                s += sv; s2 += sv * sv;
            }
        }
        if (BN_STATS) {
            atomicAdd(&sred[wn + nt * 16 + l16][0], s);
            atomicAdd(&sred[wn + nt * 16 + l16][1], s2);
        }
    }
    if (BN_STATS) {
        __syncthreads();
        if (tid < 128) {
            int col = tn + tid;
            if (col < NN) {
                atomicAdd(&stats[col], sred[tid][0]);
                atomicAdd(&stats[NN + col], sred[tid][1]);
            }
        }
    }
}

// ---------------- BN-apply + (relu) + residual ----------------
template<int RELU>
__global__ __launch_bounds__(256) void resid_k(
    u32* __restrict__ hvb32, const u32* __restrict__ z32,
    const float* __restrict__ stats,
    const float* __restrict__ scale, const float* __restrict__ bias, int l,
    const int* __restrict__ batch,
    const float* __restrict__ vncur, const float* __restrict__ vnnxt) {
    int tid = threadIdx.x;
    int wave = tid >> 6, lane = tid & 63;
    int n = blockIdx.x * 4 + wave;
    int g = batch[n];
    #pragma unroll
    for (int p = 0; p < 3; p++) {
        int ii = lane + p * 64;
        if (ii >= 150) break;
        int c0 = 2 * ii;
        float m0 = stats[c0] * (1.f / (float)kN), m1 = stats[c0 + 1] * (1.f / (float)kN);
        float v0 = fmaxf(stats[kH + c0] * (1.f / (float)kN) - m0 * m0, 0.f);
        float v1 = fmaxf(stats[kH + c0 + 1] * (1.f / (float)kN) - m1 * m1, 0.f);
        float a0 = scale[l * kH + c0] * rsqrtf(v0 + 1e-5f);
        float a1 = scale[l * kH + c0 + 1] * rsqrtf(v1 + 1e-5f);
        float d0 = bias[l * kH + c0] - m0 * a0;
        float d1 = bias[l * kH + c0 + 1] - m1 * a1;
        u32 zz = z32[(long)n * HVS32 + ii];
        u32 ho = hvb32[(long)n * HVS32 + ii];
        float2 vc = *(const float2*)(vncur + g * kH + c0);
        float2 vx = *(const float2*)(vnnxt + g * kH + c0);
        float t0 = blo(zz) * a0 + d0;
        float t1 = bhi(zz) * a1 + d1;
        if (RELU) { t0 = fmaxf(t0, 0.f); t1 = fmaxf(t1, 0.f); }
        float h0 = (blo(ho) - vc.x) + t0;
        float h1 = (bhi(ho) - vc.y) + t1;
        hvb32[(long)n * HVS32 + ii] = pack2(h0 + vx.x, h1 + vx.y);
    }
}

// ---------------- pooled mean (wave per graph) ----------------
__global__ __launch_bounds__(256) void pooled_k(
    const u32* __restrict__ hv32, const float* __restrict__ vnlast,
    const int* __restrict__ counts, const int* __restrict__ starts,
    u32* __restrict__ hrep32) {
    int tid = threadIdx.x, wave = tid >> 6, lane = tid & 63;
    int g = blockIdx.x * 4 + wave;
    int cnt = counts[g], st = starts[g];
    int i0 = lane, i1 = lane + 64, i2 = lane + 128;
    bool p2 = (i2 < 150);
    float a0 = 0.f, b0 = 0.f, a1 = 0.f, b1 = 0.f, a2 = 0.f, b2 = 0.f;
    int i = 0;
    for (; i + 4 <= cnt; i += 4) {
        const u32* rA = hv32 + (long)(st + i) * HVS32;
        const u32* rB = hv32 + (long)(st + i + 1) * HVS32;
        const u32* rC = hv32 + (long)(st + i + 2) * HVS32;
        const u32* rD = hv32 + (long)(st + i + 3) * HVS32;
        u32 vA0 = rA[i0], vA1 = rA[i1], vA2 = p2 ? rA[i2] : 0u;
        u32 vB0 = rB[i0], vB1 = rB[i1], vB2 = p2 ? rB[i2] : 0u;
        u32 vC0 = rC[i0], vC1 = rC[i1], vC2 = p2 ? rC[i2] : 0u;
        u32 vD0 = rD[i0], vD1 = rD[i1], vD2 = p2 ? rD[i2] : 0u;
        a0 += (blo(vA0) + blo(vB0)) + (blo(vC0) + blo(vD0));
        b0 += (bhi(vA0) + bhi(vB0)) + (bhi(vC0) + bhi(vD0));
        a1 += (blo(vA1) + blo(vB1)) + (blo(vC1) + blo(vD1));
        b1 += (bhi(vA1) + bhi(vB1)) + (bhi(vC1) + bhi(vD1));
        a2 += (blo(vA2) + blo(vB2)) + (blo(vC2) + blo(vD2));
        b2 += (bhi(vA2) + bhi(vB2)) + (bhi(vC2) + bhi(vD2));
    }
    for (; i < cnt; i++) {
        const u32* rA = hv32 + (long)(st + i) * HVS32;
        u32 vA0 = rA[i0], vA1 = rA[i1], vA2 = p2 ? rA[i2] : 0u;
        a0 += blo(vA0); b0 += bhi(vA0);
        a1 += blo(vA1); b1 += bhi(vA1);
        a2 += blo(vA2); b2 += bhi(vA2);
    }
    float fc = (float)cnt;
    float inv = 1.f / (float)(cnt > 0 ? cnt : 1);
    const float* vg = vnlast + g * kH;
    hrep32[(long)g * 768 + i0] = pack2((a0 - fc * vg[2 * i0]) * inv, (b0 - fc * vg[2 * i0 + 1]) * inv);
    hrep32[(long)g * 768 + i1] = pack2((a1 - fc * vg[2 * i1]) * inv, (b1 - fc * vg[2 * i1 + 1]) * inv);
    if (p2)
        hrep32[(long)g * 768 + i2] = pack2((a2 - fc * vg[2 * i2]) * inv, (b2 - fc * vg[2 * i2 + 1]) * inv);
}

// ---------------- h_rep cols [300,1536) ----------------
__global__ void hrep_rest_k(const float* __restrict__ morgan, const float* __restrict__ maccs,
                            const int* __restrict__ counts, u16* __restrict__ hrep) {
    long idx = (long)blockIdx.x * 256 + threadIdx.x;
    if (idx >= (long)kG * (KP_DG - kH)) return;
    int g = (int)(idx / (KP_DG - kH));
    int j = (int)(idx % (KP_DG - kH));
    int col = kH + j;
    u16 v;
    if (j < kF) {
        int c = counts[g];
        int q = (j < c) ? ((c - 1 - j) / kF + 1) : 0;
        v = f2bf((float)q / (float)(c > 0 ? c : 1));
    } else if (j < kF + 1024) {
        v = f2bf(morgan[(long)g * 1024 + (j - kF)]);
    } else if (j < kF + 1024 + 167) {
        v = f2bf(maccs[(long)g * 167 + (j - kF - 1024)]);
    } else {
        v = 0;
    }
    hrep[(long)g * KP_DG + col] = v;
}

// ---------------- final ----------------
__global__ void final_k(const u16* __restrict__ zp, const float* __restrict__ Wp2,
                        const float* __restrict__ bp2, float* __restrict__ out) {
    int wave = threadIdx.x >> 6, lane = threadIdx.x & 63;
    int g = blockIdx.x * 4 + wave;
    float acc = 0.f;
    for (int c = lane; c < kH2; c += 64) acc += bf2f(zp[(long)g * KP_H2 + c]) * Wp2[c];
    #pragma unroll
    for (int off = 32; off; off >>= 1) acc += __shfl_down(acc, off);
    if (lane == 0) out[g] = acc + bp2[0];
}

extern "C" void kernel_launch(void* const* d_in, const int* in_sizes, int n_in,
                              void* d_out, int out_size, void* d_ws, size_t ws_size,
                              hipStream_t stream) {
    const float* x      = (const float*)d_in[0];
    const float* morgan = (const float*)d_in[1];
    const float* maccs  = (const float*)d_in[2];
    const int*   ei     = (const int*)d_in[3];
    const int*   batch  = (const int*)d_in[4];
    const float* W_emb  = (const float*)d_in[5];
    const float* b_emb  = (const float*)d_in[6];
    const float* gin_W1 = (const float*)d_in[7];
    const float* gin_b1 = (const float*)d_in[8];
    const float* gin_W2 = (const float*)d_in[9];
    const float* gin_b2 = (const float*)d_in[10];
    const float* bn_scale = (const float*)d_in[11];
    const float* bn_bias  = (const float*)d_in[12];
    const float* eps    = (const float*)d_in[13];
    const float* vn0    = (const float*)d_in[14];
    const float* vn_W1  = (const float*)d_in[15];
    const float* vn_b1  = (const float*)d_in[16];
    const float* vn_W2  = (const float*)d_in[17];
    const float* vn_b2  = (const float*)d_in[18];
    const float* Wp1    = (const float*)d_in[19];
    const float* bp1    = (const float*)d_in[20];
    const float* Wp2    = (const float*)d_in[21];
    const float* bp2    = (const float*)d_in[22];
    float* out = (float*)d_out;

    char* ws = (char*)d_ws;
    size_t off = 0;
    auto alloc = [&](size_t bytes) -> char* {
        char* p = ws + off;
        off += (bytes + 255) & ~(size_t)255;
        return p;
    };
    u16*   hvbf = (u16*)alloc((size_t)kN * HVS * 2);        // 41.9 MB
    u16*   hv   = (u16*)alloc((size_t)kN * KP_H * 2);       // 41.9 MB
    u16*   z1   = (u16*)alloc((size_t)kN * KP_H2 * 2);      // 83.9 MB (pred overlays)
    float* vnA  = (float*)alloc((size_t)kG * kH * 4);
    float* vnB  = (float*)alloc((size_t)kG * kH * 4);
    int* counts = (int*)alloc(kG * 4);
    int* starts = (int*)alloc(kG * 4);
    float* stats = (float*)alloc(2 * kH * 4);
    int* cnt_n  = (int*)alloc((size_t)kN * 4);
    int* start_n = (int*)alloc((size_t)(kN + 1) * 4);
    int* fill_n = (int*)alloc((size_t)kN * 4);
    int* bsum   = (int*)alloc((kN / 1024) * 4);
    int* perm   = (int*)alloc((size_t)kE * 4);
    u16* W1f   = (u16*)alloc((size_t)kL * WFRAG_PER_L * 2);       // fragment-packed gin_W1
    u16* W2f   = (u16*)alloc((size_t)kL * WFRAG_PER_L * 2);       // fragment-packed gin_W2
    u16* Wv1f  = (u16*)alloc((size_t)(kL - 1) * WFRAG_PER_L * 2); // fragment-packed vn_W1
    u16* Wv2f  = (u16*)alloc((size_t)(kL - 1) * WFRAG_PER_L * 2); // fragment-packed vn_W2
    u16* Wt_p1 = (u16*)alloc((size_t)NP_H2 * KP_DG * 2);
    if (off > ws_size) return;

    // z1-region overlays (disjoint lifetimes):
    u16* vt_in = z1;                                   // [2048,320] bf16 (pre vn MLP)
    u16* hrep  = z1;                                   // [2048,1536] bf16 (post layers)
    u16* zp    = z1 + (size_t)8 * 1024 * 1024;         // [2048,640] bf16 (post layers)
    float* vnb[2] = {vnA, vnB};

    // weight packing / transposes
    {
        long tf = (long)kL * WFRAG_PER_L;
        pack_w1_k<<<dim3((unsigned)((tf + 255) / 256)), 256, 0, stream>>>(gin_W1, W1f, tf);
        pack_w2_k<<<dim3((unsigned)((tf + 255) / 256)), 256, 0, stream>>>(gin_W2, W2f, tf);
        long tv = (long)(kL - 1) * WFRAG_PER_L;
        pack_w1_k<<<dim3((unsigned)((tv + 255) / 256)), 256, 0, stream>>>(vn_W1, Wv1f, tv);
        pack_w2_k<<<dim3((unsigned)((tv + 255) / 256)), 256, 0, stream>>>(vn_W2, Wv2f, tv);
        long t5 = (long)NP_H2 * KP_DG;
        transpose_k<<<dim3((unsigned)((t5 + 255) / 256)), 256, 0, stream>>>(Wp1, Wt_p1, kDG, kH2, NP_H2, KP_DG, t5);
    }

    // graph ranges + node CSR
    hipMemsetAsync(counts, 0, kG * 4, stream);
    hipMemsetAsync(cnt_n, 0, (size_t)kN * 4, stream);
    hipMemsetAsync(fill_n, 0, (size_t)kN * 4, stream);
    hist_g_k<<<kN / 256, 256, 0, stream>>>(batch, counts);
    scan_g_k<<<1, 1024, 0, stream>>>(counts, starts);
    hist_n_k<<<kE / 256, 256, 0, stream>>>(ei, cnt_n);
    scanA_k<<<kN / 1024, 1024, 0, stream>>>(cnt_n, start_n, bsum);
    scanB_k<<<1, 64, 0, stream>>>(bsum);
    scanC_k<<<kN / 1024, 1024, 0, stream>>>(start_n, bsum);
    fill_n_k<<<kE / 256, 256, 0, stream>>>(ei, start_n, fill_n, perm);

    embed_k<<<kN / 4, 256, 0, stream>>>(x, W_emb, b_emb, vn0, (u32*)hvbf);
    vninit_k<<<kG, 320, 0, stream>>>(vn0, vnA);

    for (int l = 0; l < kL; l++) {
        float* vcur = vnb[l & 1];
        float* vnxt = vnb[(l + 1) & 1];
        gather_combine_k<<<kN / 4, 256, 0, stream>>>(
            (const u32*)hvbf, start_n, perm, eps, l, (u32*)hv, stats);
        if (l < kL - 1) {
            vt_fin_k<<<kG / 4, 256, 0, stream>>>(
                (const u32*)hvbf, vcur, counts, starts, (u32*)vt_in);
            // fused vn MLP: vt -> vnnxt = vncur + relu(MLP(vt)) (replaces 2 GEMM launches)
            fused_vn_k<<<kG / 64, 256, 0, stream>>>(
                vt_in, Wv1f + (size_t)l * WFRAG_PER_L, vn_b1 + l * kH2,
                Wv2f + (size_t)l * WFRAG_PER_L, vn_b2 + l * kH,
                vcur, vnxt);
        }
        // fused node MLP v8: dbuf z1c + early W2 issue + setprio MFMA clusters
        fused_mlp_k<<<kN / 64, 256, 0, stream>>>(
            hv, W1f + (size_t)l * WFRAG_PER_L, gin_b1 + l * kH2,
            W2f + (size_t)l * WFRAG_PER_L, gin_b2 + l * kH,
            hv, stats);
        if (l < kL - 1)
            resid_k<1><<<kN / 4, 256, 0, stream>>>(
                (u32*)hvbf, (const u32*)hv, stats, bn_scale, bn_bias, l, batch, vcur, vnxt);
        else
            resid_k<0><<<kN / 4, 256, 0, stream>>>(
                (u32*)hvbf, (const u32*)hv, stats, bn_scale, bn_bias, l, batch, vcur, vcur);
    }

    float* vnlast = vnb[(kL - 1) & 1];
    pooled_k<<<kG / 4, 256, 0, stream>>>(
        (const u32*)hvbf, vnlast, counts, starts, (u32*)hrep);
    {
        long tr = (long)kG * (KP_DG - kH);
        hrep_rest_k<<<dim3((unsigned)((tr + 255) / 256)), 256, 0, stream>>>(morgan, maccs, counts, hrep);
    }
    gemm_k<1, 1, 0><<<dim3(16, NP_H2 / 128), 256, 0, stream>>>(
        hrep, Wt_p1, bp1, zp, nullptr, KP_DG, kH2, KP_H2, KP_H2);
    final_k<<<kG / 4, 256, 0, stream>>>(zp, Wp2, bp2, out);
}